// Round 11
// baseline (374.976 us; speedup 1.0000x reference)
//
#include <hip/hip_runtime.h>
#include <math.h>

// FlashMultiHeadAttention: B=32 S=500 H=1024 NH=16 HD=64, rope + rel-pos-bias + key-pad mask.
// Pipeline: [mask->bytes] [gather-list scan] [rope table] [f32->bf16 cvt]
//           [QKV proj GEMM 256x256 8-PHASE m201-style; Q-gemm fuses rope+transpose]
//           [rope+gather+swizzle K tiles] [gather+transpose+swizzle V tiles]
//           [flash attn: masked-k compressed, swapped QK^T, in-reg softmax] [out proj GEMM]

typedef unsigned short u16;
typedef unsigned int   u32;
typedef unsigned char  u8;
using bf16x8 = __attribute__((ext_vector_type(8))) short;
using f32x4  = __attribute__((ext_vector_type(4))) float;
using f32x2  = __attribute__((ext_vector_type(2))) float;
using u16x4  = __attribute__((ext_vector_type(4))) unsigned short;

#define DEV __device__ __forceinline__

#if __has_builtin(__builtin_amdgcn_exp2f)
#define EXP2(x) __builtin_amdgcn_exp2f(x)
#else
#define EXP2(x) exp2f(x)
#endif

DEV u16 f2bf(float f) {                 // RNE f32 -> bf16
  union { float f; u32 u; } c; c.f = f;
  u32 u = c.u;
  return (u16)((u + 0x7FFFu + ((u >> 16) & 1u)) >> 16);
}
DEV float bf2f(u16 h) {
  union { u32 u; float f; } c; c.u = ((u32)h) << 16;
  return c.f;
}
DEV u32 cvtpk(float a, float b) {       // packed pair via HW cvt (T12)
  u32 r;
  asm("v_cvt_pk_bf16_f32 %0, %1, %2" : "=v"(r) : "v"(a), "v"(b));
  return r;
}

// async global->LDS, 16B/lane; LDS dest = wave-uniform base + lane*16 (linear).
DEV void async16(void* l, const void* g) {
  __builtin_amdgcn_global_load_lds(
      (__attribute__((address_space(1))) unsigned int*)g,
      (__attribute__((address_space(3))) unsigned int*)l, 16, 0, 0);
}

// ---------------- mask prep: detect bool storage (i32/f32/u8), emit bytes ----------------
__global__ __launch_bounds__(256) void mask_prep(const void* __restrict__ mraw,
                                                 u8* __restrict__ maskb) {
  __shared__ int bad_i32, bad_f32;
  if (threadIdx.x == 0) { bad_i32 = 0; bad_f32 = 0; }
  __syncthreads();
  const u32* w = (const u32*)mraw;
  int li = 0, lf = 0;
  for (int g = threadIdx.x; g < 4000; g += 256) {
    u32 v = w[g];
    li |= !(v == 0u || v == 1u);
    lf |= !(v == 0u || v == 0x3F800000u);
  }
  if (li) atomicOr(&bad_i32, 1);
  if (lf) atomicOr(&bad_f32, 1);
  __syncthreads();
  int mode = (!bad_i32) ? 0 : ((!bad_f32) ? 1 : 2);   // 0=int32, 1=float32, 2=uint8
  for (int i = threadIdx.x; i < 16000; i += 256) {
    int v;
    if (mode == 0)      v = ((const int*)mraw)[i] != 0;
    else if (mode == 1) v = (((const float*)mraw)[i] != 0.0f);
    else                v = ((const u8*)mraw)[i] != 0;
    maskb[i] = (u8)v;
  }
}

// ---------------- per-batch gather list: karr[b][512] = kept token or 0xFFFF ----------------
__global__ __launch_bounds__(512) void build_gather(const u8* __restrict__ maskb,
                                                    u16* __restrict__ karr,
                                                    int* __restrict__ kept) {
  const int b = blockIdx.x;
  const int t = threadIdx.x;
  const int lane = t & 63, wave = t >> 6;
  __shared__ int wbase[8];
  __shared__ int wpop[8];
  int v = (t < 500) ? (int)maskb[b * 500 + t] : 0;
  unsigned long long bal = __ballot(v != 0);
  karr[b * 512 + t] = 0xFFFF;
  if (lane == 0) wpop[wave] = __popcll(bal);
  __syncthreads();
  if (t == 0) {
    int s = 0;
    for (int w = 0; w < 8; ++w) { wbase[w] = s; s += wpop[w]; }
    kept[b] = s;
  }
  __syncthreads();
  if (v) {
    int rank = wbase[wave] + __popcll(bal & ((1ull << lane) - 1ull));
    karr[b * 512 + rank] = (u16)t;
  }
}

// ---------------- rope cos/sin table: tab[(s*32+j)*2] = cos, +1 = sin ----------------
__global__ __launch_bounds__(256) void rope_table(float* __restrict__ tab) {
  int idx = blockIdx.x * 256 + threadIdx.x;
  if (idx >= 16000) return;
  int s = idx >> 5, j = idx & 31;
  float ang = (float)s * exp2f(-(float)j * 0.41524100f);  // 10000^(-j/32)
  float sn, cs;
  sincosf(ang, &sn, &cs);
  tab[idx * 2] = cs;
  tab[idx * 2 + 1] = sn;
}

// ---------------- f32 -> bf16 convert (vectorized) ----------------
__global__ __launch_bounds__(256) void cvt_f32_bf16(const float* __restrict__ src,
                                                    u16* __restrict__ dst, int n4) {
  int i = blockIdx.x * 256 + threadIdx.x;
  int stride = gridDim.x * 256;
  for (; i < n4; i += stride) {
    f32x4 f = *(const f32x4*)(src + (size_t)i * 4);
    u16x4 o;
    o[0] = f2bf(f[0]); o[1] = f2bf(f[1]); o[2] = f2bf(f[2]); o[3] = f2bf(f[3]);
    *(u16x4*)(dst + (size_t)i * 4) = o;
  }
}

// ---------------- GEMM: C[m][n] = sum_k A[m][k]*Bw[n][k] + bias[n] ----------------
// m201-style 8-phase: BM=BN=256, BK=64, 2 K-tiles/iter, 8 waves (2Mx4N), per-wave 128x64.
// LDS 128KB = 2dbuf x {A,B} x 2 halves x [128 rows][64 k] (rows 128B, XOR slot swizzle).
// Per phase: {ds_read frags || stage 1 half (2 gload_lds) -> barrier -> lgkm(0) ->
//             setprio(1) 16 MFMA setprio(0) -> [vmcnt(4) @P3,P7] -> barrier}.
// Ring proof: each half-slot staged >=2 barriers after its last ds_read; vmcnt(4)
// at P3/P7 drains exactly the halves the next read-phase consumes (see derivation).
// MODE: 0 = f32 out; 1 = bf16 out; 2 = bf16 + rope + transpose to [b][h][s][64].
template <int MODE>
__global__ __launch_bounds__(512, 2) void gemm_bt(const u16* __restrict__ A,
                                                  const u16* __restrict__ Bw,
                                                  const float* __restrict__ bias,
                                                  void* __restrict__ Cout, int M,
                                                  const float* __restrict__ tabg) {
  const int bid = blockIdx.x;
  const int xcd = bid & 7, idx = bid >> 3;
  const int swz = (xcd < 4 ? xcd * 32 : 128 + (xcd - 4) * 31) + idx;  // 252 = 4*32+4*31
  const int m0 = (swz >> 2) * 256;
  const int n0 = (swz & 3) * 256;
  const int tid = threadIdx.x;
  const int wave = tid >> 6;
  const int wr = wave >> 2, wc = wave & 3;
  const int fr = tid & 15, fo = (tid >> 4) & 3;
  const int f7 = fr & 7;
  const int sl0 = (fo ^ f7) * 8;            // kk0 16B-slot (u16 offset)
  const int sl1 = ((4 + fo) ^ f7) * 8;      // kk1

  __shared__ __attribute__((aligned(16))) u16 AS[4 * 8192];   // [dbuf*2+half][128*64] 64KB
  __shared__ __attribute__((aligned(16))) u16 BS[4 * 8192];   // 64KB

  f32x4 acc[8][4];
#pragma unroll
  for (int mi = 0; mi < 8; ++mi)
#pragma unroll
    for (int ni = 0; ni < 4; ++ni)
#pragma unroll
      for (int j = 0; j < 4; ++j) acc[mi][ni][j] = 0.f;

  // stage one 16KB half-tile (2 gload/thread); inverse-swizzled source, linear dest
  auto STG_A = [&](int kt2, int half, int dbuf) {
    kt2 = min(kt2, 15);
    u16* dst = &AS[(dbuf * 2 + half) * 8192];
#pragma unroll
    for (int i2 = 0; i2 < 2; ++i2) {
      int c = i2 * 512 + tid;
      int r = c >> 3, v = (c & 7) ^ (r & 7);
      int ar = min(m0 + half * 128 + r, M - 1);
      async16(&dst[c * 8], A + (size_t)ar * 1024 + kt2 * 64 + v * 8);
    }
  };
  auto STG_B = [&](int kt2, int half, int dbuf) {
    kt2 = min(kt2, 15);
    u16* dst = &BS[(dbuf * 2 + half) * 8192];
#pragma unroll
    for (int i2 = 0; i2 < 2; ++i2) {
      int c = i2 * 512 + tid;
      int r = c >> 3, v = (c & 7) ^ (r & 7);
      async16(&dst[c * 8], Bw + (size_t)(n0 + half * 128 + r) * 1024 + kt2 * 64 + v * 8);
    }
  };

  const u16* Ad0 = &AS[(0 + wr) * 8192];            // dbuf0, A-half = wr
  const u16* Ad1 = &AS[(2 + wr) * 8192];
  const u16* Bd0 = &BS[(0 + (wc >> 1)) * 8192 + (wc & 1) * 4096];
  const u16* Bd1 = &BS[(2 + (wc >> 1)) * 8192 + (wc & 1) * 4096];

  bf16x8 afr[8][2], bfr[4][2];

#define RD_A(BASE, MI0)                                                   \
  _Pragma("unroll")                                                       \
  for (int q = 0; q < 4; ++q) {                                           \
    afr[MI0 + q][0] = *(const bf16x8*)&(BASE)[((MI0 + q) * 16 + fr) * 64 + sl0]; \
    afr[MI0 + q][1] = *(const bf16x8*)&(BASE)[((MI0 + q) * 16 + fr) * 64 + sl1]; \
  }
#define RD_B(BASE, KK, SL)                                                \
  _Pragma("unroll")                                                       \
  for (int q = 0; q < 4; ++q)                                             \
    bfr[q][KK] = *(const bf16x8*)&(BASE)[(q * 16 + fr) * 64 + SL];
#define MFMA16(MI0, KK)                                                   \
  __builtin_amdgcn_s_setprio(1);                                          \
  _Pragma("unroll")                                                       \
  for (int q = 0; q < 4; ++q)                                             \
    _Pragma("unroll")                                                     \
    for (int ni = 0; ni < 4; ++ni)                                        \
      acc[MI0 + q][ni] = __builtin_amdgcn_mfma_f32_16x16x32_bf16(         \
          afr[MI0 + q][KK], bfr[ni][KK], acc[MI0 + q][ni], 0, 0, 0);      \
  __builtin_amdgcn_s_setprio(0);
#define BAR() __builtin_amdgcn_s_barrier()
#define LGKM0() do { asm volatile("s_waitcnt lgkmcnt(0)" ::: "memory"); \
                     __builtin_amdgcn_sched_barrier(0); } while (0)
#define VM4() do { asm volatile("s_waitcnt vmcnt(4)" ::: "memory");     \
                   __builtin_amdgcn_sched_barrier(0); } while (0)

  // prologue: tile0 full + A(1); leaves <=4 outstanding (A(1)) after VM4
  STG_A(0, 0, 0); STG_A(0, 1, 0); STG_B(0, 0, 0); STG_B(0, 1, 0);
  STG_A(1, 0, 1); STG_A(1, 1, 1);
  VM4();
  BAR();

  for (int i = 0; i < 8; ++i) {
    const int ta = 2 * i, tb = 2 * i + 1;
    // P0: rd A(ta)m0-3 kk01 + B(ta)kk0; stage B-lo(tb)->d1
    RD_A(Ad0, 0); RD_B(Bd0, 0, sl0);
    STG_B(tb, 0, 1);
    BAR(); LGKM0();
    MFMA16(0, 0);
    BAR();
    // P1: rd A(ta)m4-7 + B(ta)kk1; stage B-hi(tb)->d1
    RD_A(Ad0, 4); RD_B(Bd0, 1, sl1);
    STG_B(tb, 1, 1);
    BAR(); LGKM0();
    MFMA16(0, 1);
    BAR();
    // P2: stage A-lo(ta+2)->d0 (freed after P1); MFMA m4-7 kk0 (pure reg)
    STG_A(ta + 2, 0, 0);
    BAR(); LGKM0();
    MFMA16(4, 0);
    BAR();
    // P3: stage A-hi(ta+2)->d0; MFMA m4-7 kk1; vmcnt(4) covers A(tb)+B(tb)
    STG_A(ta + 2, 1, 0);
    BAR(); LGKM0();
    MFMA16(4, 1);
    VM4();
    BAR();
    // P4: rd A(tb)m0-3 + B(tb)kk0; stage B-lo(ta+2)->d0
    RD_A(Ad1, 0); RD_B(Bd1, 0, sl0);
    STG_B(ta + 2, 0, 0);
    BAR(); LGKM0();
    MFMA16(0, 0);
    BAR();
    // P5: rd A(tb)m4-7 + B(tb)kk1; stage B-hi(ta+2)->d0
    RD_A(Ad1, 4); RD_B(Bd1, 1, sl1);
    STG_B(ta + 2, 1, 0);
    BAR(); LGKM0();
    MFMA16(0, 1);
    BAR();
    // P6: stage A-lo(tb+2)->d1 (freed after P5); MFMA m4-7 kk0
    STG_A(tb + 2, 0, 1);
    BAR(); LGKM0();
    MFMA16(4, 0);
    BAR();
    // P7: stage A-hi(tb+2)->d1; MFMA m4-7 kk1; vmcnt(4) covers next A(ta')+B(ta')
    STG_A(tb + 2, 1, 1);
    BAR(); LGKM0();
    MFMA16(4, 1);
    VM4();
    BAR();
  }
#undef RD_A
#undef RD_B
#undef MFMA16
#undef BAR
#undef LGKM0
#undef VM4

  // ---- epilogue: per-wave LDS bounce for contiguous stores ----
  __syncthreads();                                    // drains vmcnt; all LDS reads done
  if (MODE == 2) {
    // rope + transpose: wave strip = head; bounce f32, rope from tab, write [bh][s][d]
    float* fw = (float*)&AS[0] + wave * 1024;         // 4KB per wave
    const int hh = (n0 >> 6) + wc;
    const int lane = tid & 63;
    const int row = lane >> 2;
    const int jb = (lane & 3) * 8;
    float bvv[4];
#pragma unroll
    for (int ni = 0; ni < 4; ++ni) bvv[ni] = bias[n0 + wc * 64 + ni * 16 + fr];
#pragma unroll
    for (int mi = 0; mi < 8; ++mi) {
#pragma unroll
      for (int ni = 0; ni < 4; ++ni)
#pragma unroll
        for (int r = 0; r < 4; ++r)
          fw[(fo * 4 + r) * 64 + ni * 16 + fr] = acc[mi][ni][r] + bvv[ni];
      int m = m0 + wr * 128 + mi * 16 + row;
      if (m < M) {
        int bb = (u32)m / 500u;
        int ss = m - bb * 500;
        u16* dst = (u16*)Cout + (((size_t)(bb * 16 + hh)) * 500 + ss) * 64;
        bf16x8 va, vb;
#pragma unroll
        for (int p = 0; p < 8; ++p) {
          int j = jb + p;
          float x0 = fw[row * 64 + j];
          float x1 = fw[row * 64 + 32 + j];
          float xe = fw[row * 64 + 2 * j];
          float xo = fw[row * 64 + 2 * j + 1];
          f32x2 cn = *(const f32x2*)(tabg + (ss * 32 + j) * 2);
          va[p] = (short)f2bf(x0 * cn[0] - xo * cn[1]);
          vb[p] = (short)f2bf(x1 * cn[0] + xe * cn[1]);
        }
        *(bf16x8*)(dst + jb) = va;
        *(bf16x8*)(dst + 32 + jb) = vb;
      }
      __builtin_amdgcn_s_barrier();
    }
  } else if (MODE == 1) {
    u16* bw = (u16*)&AS[0] + wave * 2048;             // 4KB per wave
#pragma unroll
    for (int mi = 0; mi < 8; ++mi) {
#pragma unroll
      for (int ni = 0; ni < 4; ++ni) {
        float bv = bias[n0 + wc * 64 + ni * 16 + fr];
#pragma unroll
        for (int r = 0; r < 4; ++r)
          bw[(fo * 4 + r) * 64 + ni * 16 + fr] = f2bf(acc[mi][ni][r] + bv);
      }
      int lane = tid & 63;
      int ro = lane >> 2, ch = lane & 3;
      int m = m0 + wr * 128 + mi * 16 + ro;
      bf16x8 v0 = *(const bf16x8*)&bw[ro * 64 + ch * 16];
      bf16x8 v1 = *(const bf16x8*)&bw[ro * 64 + ch * 16 + 8];
      if (m < M) {
        u16* dst = (u16*)Cout + (size_t)m * 1024 + n0 + wc * 64 + ch * 16;
        *(bf16x8*)dst = v0;
        *(bf16x8*)(dst + 8) = v1;
      }
    }
  } else {
    float* fw = (float*)&AS[0] + wave * 1024;         // 4KB per wave
#pragma unroll
    for (int mi = 0; mi < 8; ++mi) {
#pragma unroll
      for (int ni = 0; ni < 4; ++ni) {
        float bv = bias[n0 + wc * 64 + ni * 16 + fr];
#pragma unroll
        for (int r = 0; r < 4; ++r)
          fw[(fo * 4 + r) * 64 + ni * 16 + fr] = acc[mi][ni][r] + bv;
      }
      int lane = tid & 63;
      int ro = lane >> 2, ch = lane & 3;
      int m = m0 + wr * 128 + mi * 16 + ro;
      f32x4 v0 = *(const f32x4*)&fw[ro * 64 + ch * 16];
      f32x4 v1 = *(const f32x4*)&fw[ro * 64 + ch * 16 + 4];
      f32x4 v2 = *(const f32x4*)&fw[ro * 64 + ch * 16 + 8];
      f32x4 v3 = *(const f32x4*)&fw[ro * 64 + ch * 16 + 12];
      if (m < M) {
        float* dst = (float*)Cout + (size_t)m * 1024 + n0 + wc * 64 + ch * 16;
        *(f32x4*)dst = v0;
        *(f32x4*)(dst + 4) = v1;
        *(f32x4*)(dst + 8) = v2;
        *(f32x4*)(dst + 12) = v3;
      }
    }
  }
}

// ---------------- K: rope + gather kept tokens -> pre-swizzled tiles [bh][tile][64][128B] ------
__global__ __launch_bounds__(256) void gather_k(const u16* __restrict__ Pk,
                                                const float* __restrict__ tab,
                                                const u16* __restrict__ karr,
                                                const int* __restrict__ kept,
                                                u16* __restrict__ Ktg) {
  const int tile = blockIdx.x;
  const int bh = blockIdx.y;
  const int h = bh & 15, b = bh >> 4;
  if (tile * 64 >= kept[b]) return;
  char* out = (char*)(Ktg + ((size_t)bh * 8 + tile) * 4096);
  const int tid = threadIdx.x;
#pragma unroll
  for (int i = 0; i < 8; ++i) {
    int item = i * 256 + tid;            // 2048 = 64 rows * 32 j
    int row = item >> 5, j = item & 31;
    int tok = karr[b * 512 + tile * 64 + row];
    int sw = (row & 7) << 4;
    u16 o0 = 0, o1 = 0;
    if (tok != 0xFFFF) {
      const u16* src = Pk + ((size_t)b * 500 + tok) * 1024 + h * 64;
      float x0 = bf2f(src[j]);
      float x1 = bf2f(src[32 + j]);
      float xe = bf2f(src[2 * j]);
      float xo = bf2f(src[2 * j + 1]);
      f32x2 cn = *(const f32x2*)(tab + (tok * 32 + j) * 2);
      o0 = f2bf(x0 * cn[0] - xo * cn[1]);
      o1 = f2bf(x1 * cn[0] + xe * cn[1]);
    }
    *(u16*)(out + row * 128 + ((2 * j) ^ sw)) = o0;
    *(u16*)(out + row * 128 + ((64 + 2 * j) ^ sw)) = o1;
  }
}

// ---------------- V: gather + transpose -> pre-swizzled V^T tiles [bh][tile][64 d][128B] ------
__global__ __launch_bounds__(256) void gather_v(const u16* __restrict__ Pv,
                                                const u16* __restrict__ karr,
                                                const int* __restrict__ kept,
                                                u16* __restrict__ Vtg) {
  const int tile = blockIdx.x;
  const int bh = blockIdx.y;
  const int h = bh & 15, b = bh >> 4;
  if (tile * 64 >= kept[b]) return;
  const int tid = threadIdx.x;
  __shared__ __attribute__((aligned(16))) u16 Vl[64 * 64];
#pragma unroll
  for (int i = 0; i < 2; ++i) {
    int chunk = i * 256 + tid;           // 512: slot(64) x seg(8)
    int slot = chunk >> 3, seg = chunk & 7;
    int tok = karr[b * 512 + tile * 64 + slot];
    bf16x8 v;
#pragma unroll
    for (int p = 0; p < 8; ++p) v[p] = 0;
    if (tok != 0xFFFF)
      v = *(const bf16x8*)(Pv + ((size_t)b * 500 + tok) * 1024 + h * 64 + seg * 8);
    *(bf16x8*)&Vl[slot * 64 + seg * 8] = v;
  }
  __syncthreads();
  u16* out = Vtg + ((size_t)bh * 8 + tile) * 4096;
#pragma unroll
  for (int i = 0; i < 2; ++i) {
    int chunk = i * 256 + tid;           // d(64) x c16(8)
    int d = chunk >> 3, c16 = chunk & 7;
    int k0 = ((c16 * 16) ^ ((d & 7) << 4)) >> 1;
    bf16x8 v;
#pragma unroll
    for (int p = 0; p < 8; ++p) v[p] = (short)Vl[(k0 + p) * 64 + d];
    *(bf16x8*)(out + chunk * 8) = v;
  }
}

// ---------------- flash attention: compressed k, swapped QK^T, in-reg softmax ----------------
__global__ __launch_bounds__(512) void attn_kernel(const u16* __restrict__ Qr,
                                                   const u16* __restrict__ Ktg,
                                                   const u16* __restrict__ Vtg,
                                                   const float* __restrict__ rel_emb,
                                                   const u16* __restrict__ karr,
                                                   const int* __restrict__ kept,
                                                   u16* __restrict__ AO) {
  const int bid = blockIdx.x;
  const int bh = ((bid >> 5) << 3) | (bid & 7);
  const int qb = (bid >> 3) & 3;
  const int h = bh & 15, b = bh >> 4;
  const int q0 = qb * 128;
  const int tid = threadIdx.x;
  const int wave = tid >> 6;
  const int fr = tid & 15, fo = (tid >> 4) & 3;

  __shared__ __attribute__((aligned(16))) u16 Ks[2][4096];
  __shared__ __attribute__((aligned(16))) u16 Vs[2][4096];
  __shared__ __attribute__((aligned(16))) u16 Pl[8][1024];
  __shared__ float rel2[640];
  __shared__ u16 okk[512];

  const int nt = (kept[b] + 63) >> 6;
  const float LOG2E = 1.44269504f;
  for (int i = tid; i < 640; i += 512) {
    int g = min(max(q0 - 12 + i, 0), 998);
    rel2[i] = (i == 0) ? -1e30f : rel_emb[g * 16 + h] * LOG2E;   // rel2[0] = pad sentinel
  }
  okk[tid] = karr[b * 512 + tid];

  const int qloc = wave * 16 + fr;
  const int qc = qloc + 511;             // pad slot (ok=0xFFFF) -> idx<0 -> clamp 0 -> -1e30
  const u16* Qb = Qr + ((size_t)bh * 500 + min(q0 + qloc, 499)) * 64;
  bf16x8 qf0 = *(const bf16x8*)(Qb + fo * 8);
  bf16x8 qf1 = *(const bf16x8*)(Qb + 32 + fo * 8);

  f32x4 o[4];
#pragma unroll
  for (int nf = 0; nf < 4; ++nf)
#pragma unroll
    for (int j = 0; j < 4; ++j) o[nf][j] = 0.f;
  float mrun = -1e30f, lrun = 0.f;

  const u16* Kb = Ktg + (size_t)bh * 32768;
  const u16* Vb = Vtg + (size_t)bh * 32768;
  const int sw = (fr & 7) << 4;
  const float SC = 0.18033688f;          // 0.125 * log2(e)

  if (nt > 0) {
    async16(&Ks[0][tid * 8], Kb + tid * 8);
    async16(&Vs[0][tid * 8], Vb + tid * 8);
  }
  __syncthreads();

  for (int t = 0; t < nt; ++t) {
    const int cur = t & 1;
    if (t + 1 < nt) {
      async16(&Ks[cur ^ 1][tid * 8], Kb + (t + 1) * 4096 + tid * 8);
      async16(&Vs[cur ^ 1][tid * 8], Vb + (t + 1) * 4096 + tid * 8);
    }
    const char* Kt = (const char*)(cur ? &Ks[1][0] : &Ks[0][0]);
    const char* Vt = (const char*)(cur ? &Vs[1][0] : &Vs[0][0]);

    f32x4 sacc[4];
    __builtin_amdgcn_s_setprio(1);
#pragma unroll
    for (int nf = 0; nf < 4; ++nf) {
#pragma unroll
      for (int jj = 0; jj < 4; ++jj) sacc[nf][jj] = 0.f;
      int rb = (nf * 16 + fr) * 128;
      bf16x8 kb0 = *(const bf16x8*)(Kt + rb + ((fo * 16) ^ sw));
      bf16x8 kb1 = *(const bf16x8*)(Kt + rb + ((64 + fo * 16) ^ sw));
      sacc[nf] = __builtin_amdgcn_mfma_f32_16x16x32_bf16(kb0, qf0, sacc[nf], 0, 0, 0);
      sacc[nf] = __builtin_amdgcn_mfma_f32_16x16x32_bf16(kb1, qf1, sacc[nf], 0, 0, 0);
    }
    __builtin_amdgcn_s_setprio(0);

    float p2[4][4];
    float pmax = -3e30f;
#pragma unroll
    for (int nf = 0; nf < 4; ++nf) {
      u16x4 ok4 = *(const u16x4*)&okk[t * 64 + nf * 16 + fo * 4];
#pragma unroll
      for (int r = 0; r < 4; ++r) {
        int idx2 = max(qc - (int)ok4[r], 0);
        float s2 = fmaf(sacc[nf][r], SC, rel2[idx2]);
        p2[nf][r] = s2;
        pmax = fmaxf(pmax, s2);
      }
    }
    pmax = fmaxf(pmax, __shfl_xor(pmax, 16, 64));
    pmax = fmaxf(pmax, __shfl_xor(pmax, 32, 64));

    if (!__all(pmax <= mrun + 8.0f)) {   // defer-max (T13)
      float mnew = fmaxf(mrun, pmax);
      float scl = EXP2(mrun - mnew);
      lrun *= scl;
#pragma unroll
      for (int nf = 0; nf < 4; ++nf)
#pragma unroll
        for (int r = 0; r < 4; ++r) o[nf][r] *= scl;
      mrun = mnew;
    }

    float lsum = 0.f;
#pragma unroll
    for (int nf = 0; nf < 4; ++nf) {
      float e0 = EXP2(p2[nf][0] - mrun);
      float e1 = EXP2(p2[nf][1] - mrun);
      float e2 = EXP2(p2[nf][2] - mrun);
      float e3 = EXP2(p2[nf][3] - mrun);
      lsum += (e0 + e1) + (e2 + e3);
      uint2 w; w.x = cvtpk(e0, e1); w.y = cvtpk(e2, e3);
      *(uint2*)((char*)&Pl[wave][0] + fr * 128 + ((nf * 32 + fo * 8) ^ sw)) = w;
    }
    lsum += __shfl_xor(lsum, 16, 64);
    lsum += __shfl_xor(lsum, 32, 64);
    lrun += lsum;

    bf16x8 pa0 = *(const bf16x8*)((char*)&Pl[wave][0] + fr * 128 + ((fo * 16) ^ sw));
    bf16x8 pa1 = *(const bf16x8*)((char*)&Pl[wave][0] + fr * 128 + ((64 + fo * 16) ^ sw));
    __builtin_amdgcn_s_setprio(1);
#pragma unroll
    for (int nf = 0; nf < 4; ++nf) {
      int rb = (nf * 16 + fr) * 128;
      bf16x8 vb0 = *(const bf16x8*)(Vt + rb + ((fo * 16) ^ sw));
      bf16x8 vb1 = *(const bf16x8*)(Vt + rb + ((64 + fo * 16) ^ sw));
      o[nf] = __builtin_amdgcn_mfma_f32_16x16x32_bf16(vb0, pa0, o[nf], 0, 0, 0);
      o[nf] = __builtin_amdgcn_mfma_f32_16x16x32_bf16(vb1, pa1, o[nf], 0, 0, 0);
    }
    __builtin_amdgcn_s_setprio(0);
    __syncthreads();
  }

  float inv = (lrun > 0.f) ? 1.f / lrun : 0.f;
#pragma unroll
  for (int nf = 0; nf < 4; ++nf) {
    float v0 = fminf(fmaxf(o[nf][0] * inv, -30.f), 30.f);
    float v1 = fminf(fmaxf(o[nf][1] * inv, -30.f), 30.f);
    float v2 = fminf(fmaxf(o[nf][2] * inv, -30.f), 30.f);
    float v3 = fminf(fmaxf(o[nf][3] * inv, -30.f), 30.f);
    uint2 w; w.x = cvtpk(v0, v1); w.y = cvtpk(v2, v3);
    *(uint2*)((char*)&Pl[wave][0] + fr * 128 + ((nf * 32 + fo * 8) ^ sw)) = w;
  }
  {
    int lane = tid & 63;
    int ro = lane >> 2, c = lane & 3;
    int swr = (ro & 7) << 4;
    const char* Pw = (const char*)&Pl[wave][0];
    bf16x8 v0 = *(const bf16x8*)(Pw + ro * 128 + ((c * 32) ^ swr));
    bf16x8 v1 = *(const bf16x8*)(Pw + ro * 128 + ((c * 32 + 16) ^ swr));
    int token = q0 + wave * 16 + ro;
    if (token < 500) {
      u16* dst = AO + (size_t)(b * 500 + token) * 1024 + h * 64 + c * 16;
      *(bf16x8*)dst = v0;
      *(bf16x8*)(dst + 8) = v1;
    }
  }
}

// ---------------- launch ----------------
extern "C" void kernel_launch(void* const* d_in, const int* in_sizes, int n_in,
                              void* d_out, int out_size, void* d_ws, size_t ws_size,
                              hipStream_t stream) {
  const float* query = (const float*)d_in[0];
  const float* key_  = (const float*)d_in[1];
  const float* value = (const float*)d_in[2];
  const void*  mask  = d_in[3];
  const float* Wq = (const float*)d_in[4];
  const float* bq = (const float*)d_in[5];
  const float* Wk = (const float*)d_in[6];
  const float* bk = (const float*)d_in[7];
  const float* Wv = (const float*)d_in[8];
  const float* bv = (const float*)d_in[9];
  const float* Wo = (const float*)d_in[10];
  const float* bo = (const float*)d_in[11];
  const float* rel = (const float*)d_in[12];

  // ws map: Wb 8.39MB | 4 slots x 32MiB | misc ~0.26MB
  char* ws = (char*)d_ws;
  const size_t SLOT = 33554432;
  u16* Wb = (u16*)ws;
  char* Aq = ws + 8388608;
  char* Bq = Aq + SLOT;
  char* Cq = Bq + SLOT;
  char* Dq = Cq + SLOT;
  char* MISC = Dq + SLOT;
  u8*  maskb = (u8*)MISC;
  u16* karr  = (u16*)(MISC + 65536);
  int* kept  = (int*)(MISC + 131072);
  float* tab = (float*)(MISC + 131584);

  mask_prep<<<1, 256, 0, stream>>>(mask, maskb);
  build_gather<<<32, 512, 0, stream>>>(maskb, karr, kept);
  rope_table<<<63, 256, 0, stream>>>(tab);

  cvt_f32_bf16<<<512, 256, 0, stream>>>(Wq, Wb + 0 * 1048576, 262144);
  cvt_f32_bf16<<<512, 256, 0, stream>>>(Wk, Wb + 1 * 1048576, 262144);
  cvt_f32_bf16<<<512, 256, 0, stream>>>(Wv, Wb + 2 * 1048576, 262144);
  cvt_f32_bf16<<<512, 256, 0, stream>>>(Wo, Wb + 3 * 1048576, 262144);
  cvt_f32_bf16<<<2048, 256, 0, stream>>>(query, (u16*)Aq, 4096000);
  cvt_f32_bf16<<<2048, 256, 0, stream>>>(key_,  (u16*)Bq, 4096000);
  cvt_f32_bf16<<<2048, 256, 0, stream>>>(value, (u16*)Cq, 4096000);

  gemm_bt<1><<<252, 512, 0, stream>>>((u16*)Cq, Wb + 2 * 1048576, bv, Dq, 16000, tab);  // Pv=D
  gemm_bt<2><<<252, 512, 0, stream>>>((u16*)Aq, Wb + 0 * 1048576, bq, Cq, 16000, tab);  // Qro=C
  gemm_bt<1><<<252, 512, 0, stream>>>((u16*)Bq, Wb + 1 * 1048576, bk, Aq, 16000, tab);  // Pk=A

  gather_k<<<dim3(8, 512), 256, 0, stream>>>((u16*)Aq, tab, karr, kept, (u16*)Bq);  // Ktg=B
  gather_v<<<dim3(8, 512), 256, 0, stream>>>((u16*)Dq, karr, kept, (u16*)Aq);       // Vtg=A

  attn_kernel<<<2048, 512, 0, stream>>>((u16*)Cq, (u16*)Bq, (u16*)Aq, rel,
                                        karr, kept, (u16*)Dq);                  // AO=D

  gemm_bt<0><<<252, 512, 0, stream>>>((u16*)Dq, Wb + 3 * 1048576, bo, (float*)d_out, 16000, tab);
}

// Round 12
// 327.852 us; speedup vs baseline: 1.1437x; 1.1437x over previous
//
#include <hip/hip_runtime.h>
#include <math.h>

// FlashMultiHeadAttention: B=32 S=500 H=1024 NH=16 HD=64, rope + rel-pos-bias + key-pad mask.
// Pipeline: [mask->bytes] [gather-list scan] [rope table] [cvt Q full] [gather+cvt K/V kept rows]
//           [K/V proj GEMM over COMPACT kept rows] [Q proj GEMM fusing rope+transpose]
//           [rope+gather+swizzle K tiles] [gather+transpose+swizzle V tiles]
//           [flash attn: masked-k compressed, swapped QK^T, in-reg softmax] [out proj GEMM]

typedef unsigned short u16;
typedef unsigned int   u32;
typedef unsigned char  u8;
using bf16x8 = __attribute__((ext_vector_type(8))) short;
using f32x4  = __attribute__((ext_vector_type(4))) float;
using f32x2  = __attribute__((ext_vector_type(2))) float;
using u16x4  = __attribute__((ext_vector_type(4))) unsigned short;

#define DEV __device__ __forceinline__

#if __has_builtin(__builtin_amdgcn_exp2f)
#define EXP2(x) __builtin_amdgcn_exp2f(x)
#else
#define EXP2(x) exp2f(x)
#endif

DEV u16 f2bf(float f) {                 // RNE f32 -> bf16
  union { float f; u32 u; } c; c.f = f;
  u32 u = c.u;
  return (u16)((u + 0x7FFFu + ((u >> 16) & 1u)) >> 16);
}
DEV float bf2f(u16 h) {
  union { u32 u; float f; } c; c.u = ((u32)h) << 16;
  return c.f;
}
DEV u32 cvtpk(float a, float b) {       // packed pair via HW cvt (T12)
  u32 r;
  asm("v_cvt_pk_bf16_f32 %0, %1, %2" : "=v"(r) : "v"(a), "v"(b));
  return r;
}

// async global->LDS, 16B/lane; LDS dest = wave-uniform base + lane*16 (linear).
DEV void async16(void* l, const void* g) {
  __builtin_amdgcn_global_load_lds(
      (__attribute__((address_space(1))) unsigned int*)g,
      (__attribute__((address_space(3))) unsigned int*)l, 16, 0, 0);
}

// ---------------- mask prep: detect bool storage (i32/f32/u8), emit bytes ----------------
__global__ __launch_bounds__(256) void mask_prep(const void* __restrict__ mraw,
                                                 u8* __restrict__ maskb) {
  __shared__ int bad_i32, bad_f32;
  if (threadIdx.x == 0) { bad_i32 = 0; bad_f32 = 0; }
  __syncthreads();
  const u32* w = (const u32*)mraw;
  int li = 0, lf = 0;
  for (int g = threadIdx.x; g < 4000; g += 256) {
    u32 v = w[g];
    li |= !(v == 0u || v == 1u);
    lf |= !(v == 0u || v == 0x3F800000u);
  }
  if (li) atomicOr(&bad_i32, 1);
  if (lf) atomicOr(&bad_f32, 1);
  __syncthreads();
  int mode = (!bad_i32) ? 0 : ((!bad_f32) ? 1 : 2);   // 0=int32, 1=float32, 2=uint8
  for (int i = threadIdx.x; i < 16000; i += 256) {
    int v;
    if (mode == 0)      v = ((const int*)mraw)[i] != 0;
    else if (mode == 1) v = (((const float*)mraw)[i] != 0.0f);
    else                v = ((const u8*)mraw)[i] != 0;
    maskb[i] = (u8)v;
  }
}

// ---------------- per-batch gather list: karr[b][512] = kept token or 0xFFFF ----------------
__global__ __launch_bounds__(512) void build_gather(const u8* __restrict__ maskb,
                                                    u16* __restrict__ karr,
                                                    int* __restrict__ kept) {
  const int b = blockIdx.x;
  const int t = threadIdx.x;
  const int lane = t & 63, wave = t >> 6;
  __shared__ int wbase[8];
  __shared__ int wpop[8];
  int v = (t < 500) ? (int)maskb[b * 500 + t] : 0;
  unsigned long long bal = __ballot(v != 0);
  karr[b * 512 + t] = 0xFFFF;
  if (lane == 0) wpop[wave] = __popcll(bal);
  __syncthreads();
  if (t == 0) {
    int s = 0;
    for (int w = 0; w < 8; ++w) { wbase[w] = s; s += wpop[w]; }
    kept[b] = s;
  }
  __syncthreads();
  if (v) {
    int rank = wbase[wave] + __popcll(bal & ((1ull << lane) - 1ull));
    karr[b * 512 + rank] = (u16)t;
  }
}

// ---------------- rope cos/sin table: tab[(s*32+j)*2] = cos, +1 = sin ----------------
__global__ __launch_bounds__(256) void rope_table(float* __restrict__ tab) {
  int idx = blockIdx.x * 256 + threadIdx.x;
  if (idx >= 16000) return;
  int s = idx >> 5, j = idx & 31;
  float ang = (float)s * exp2f(-(float)j * 0.41524100f);  // 10000^(-j/32)
  float sn, cs;
  sincosf(ang, &sn, &cs);
  tab[idx * 2] = cs;
  tab[idx * 2 + 1] = sn;
}

// ---------------- f32 -> bf16 convert (vectorized) ----------------
__global__ __launch_bounds__(256) void cvt_f32_bf16(const float* __restrict__ src,
                                                    u16* __restrict__ dst, int n4) {
  int i = blockIdx.x * 256 + threadIdx.x;
  int stride = gridDim.x * 256;
  for (; i < n4; i += stride) {
    f32x4 f = *(const f32x4*)(src + (size_t)i * 4);
    u16x4 o;
    o[0] = f2bf(f[0]); o[1] = f2bf(f[1]); o[2] = f2bf(f[2]); o[3] = f2bf(f[3]);
    *(u16x4*)(dst + (size_t)i * 4) = o;
  }
}

// ---------------- gather kept rows + f32->bf16: dst[b*512 + rank] = src[b*500 + tok] --------
__global__ __launch_bounds__(256) void gathercvt(const float* __restrict__ src,
                                                 const u16* __restrict__ karr,
                                                 const int* __restrict__ kept,
                                                 u16* __restrict__ dst) {
  const int b = blockIdx.y;
  const int r = blockIdx.x * 2 + (threadIdx.x >> 7);   // 512 rows/batch
  if (r >= kept[b]) return;
  const int c = (threadIdx.x & 127) * 8;
  const int tok = karr[b * 512 + r];
  const float* s = src + ((size_t)b * 500 + tok) * 1024 + c;
  f32x4 f0 = *(const f32x4*)s;
  f32x4 f1 = *(const f32x4*)(s + 4);
  u16 o[8];
  o[0] = f2bf(f0[0]); o[1] = f2bf(f0[1]); o[2] = f2bf(f0[2]); o[3] = f2bf(f0[3]);
  o[4] = f2bf(f1[0]); o[5] = f2bf(f1[1]); o[6] = f2bf(f1[2]); o[7] = f2bf(f1[3]);
  *(bf16x8*)(dst + ((size_t)b * 512 + r) * 1024 + c) = *(bf16x8*)o;
}

// ---------------- GEMM: C[m][n] = sum_k A[m][k]*Bw[n][k] + bias[n] ----------------
// Round-10 proven structure: 256x256 tile, BK=32, 512 thr / 8 waves (2x4), per-wave 128x64;
// XOR-swizzled LDS; fine-phase counted-vmcnt schedule; 3 buffers (96KB).
// MODE: 0 = f32 out [m][1024]; 1 = bf16 out [m][1024]; 2 = bf16 + rope + transpose to
//       [b][h][s][64] (Q proj); 3 = COMPACT bf16: A/C rows are [b][512] kept-rank layout,
//       per-block early-exit on kept[b] (grid 256 = 32b x 2rb x 4n, XCD-chunked).
template <int MODE>
__global__ __launch_bounds__(512, 2) void gemm_bt(const u16* __restrict__ A,
                                                  const u16* __restrict__ Bw,
                                                  const float* __restrict__ bias,
                                                  void* __restrict__ Cout, int M,
                                                  const float* __restrict__ tabg,
                                                  const int* __restrict__ keptp) {
  const int bid = blockIdx.x;
  int m0, n0, Mloc;
  size_t abase, crowbase;
  if (MODE == 3) {
    const int swz = (bid & 7) * 32 + (bid >> 3);      // bijective: 256 = 8*32
    const int mb = swz >> 2;
    n0 = (swz & 3) * 256;
    const int b = mb >> 1, rb = mb & 1;
    const int kb = keptp[b];
    if (rb * 256 >= kb) return;
    m0 = rb * 256;
    Mloc = kb;
    abase = (size_t)b * 512 * 1024;
    crowbase = (size_t)b * 512;
  } else {
    const int xcd = bid & 7, idx = bid >> 3;
    const int swz = (xcd < 4 ? xcd * 32 : 128 + (xcd - 4) * 31) + idx;  // 252 = 4*32+4*31
    m0 = (swz >> 2) * 256;
    n0 = (swz & 3) * 256;
    Mloc = M;
    abase = 0;
    crowbase = 0;
  }
  const int tid = threadIdx.x;
  const int wave = tid >> 6;
  const int wr = wave >> 2, wc = wave & 3;
  const int fr = tid & 15, fo = (tid >> 4) & 3;
  const int fr2 = fr >> 1;
  const int aslot = ((4 * (fr & 1) + fo) ^ fr2) * 8;  // u16 offset within 64-u16 LDS row

  const int TILE = 256 * 32;                          // u16 elems per buffer (16KB)
  __shared__ __attribute__((aligned(16))) u16 As[3 * 256 * 32];   // 48KB
  __shared__ __attribute__((aligned(16))) u16 Bs[3 * 256 * 32];   // 48KB

  f32x4 acc[8][4];
#pragma unroll
  for (int mi = 0; mi < 8; ++mi)
#pragma unroll
    for (int ni = 0; ni < 4; ++ni)
#pragma unroll
      for (int j = 0; j < 4; ++j) acc[mi][ni][j] = 0.f;

  auto STAGE_A = [&](int kt2, u16* sA) {
#pragma unroll
    for (int i = 0; i < 2; ++i) {
      int c = i * 512 + tid;
      int r = c >> 3, v = (c & 7) ^ (r & 7);
      int ar = min(m0 + 2 * r + (v >> 2), Mloc - 1);
      async16(&sA[c * 8], A + abase + (size_t)ar * 1024 + kt2 * 32 + (v & 3) * 8);
    }
  };
  auto STAGE_B = [&](int kt2, u16* sB) {
#pragma unroll
    for (int i = 0; i < 2; ++i) {
      int c = i * 512 + tid;
      int r = c >> 3, v = (c & 7) ^ (r & 7);
      int nr = n0 + 2 * r + (v >> 2);
      async16(&sB[c * 8], Bw + (size_t)nr * 1024 + kt2 * 32 + (v & 3) * 8);
    }
  };

  u16 *a0 = &As[0], *a1 = &As[TILE], *a2 = &As[2 * TILE];
  u16 *b0 = &Bs[0], *b1 = &Bs[TILE], *b2 = &Bs[2 * TILE];
  STAGE_A(0, a0); STAGE_B(0, b0);                     // 4 vmem instrs (tile 0)
  STAGE_A(1, a1); STAGE_B(1, b1);                     // 4 more (tile 1)
  asm volatile("s_waitcnt vmcnt(4)" ::: "memory");    // tile 0 landed; tile 1 in flight
  __builtin_amdgcn_sched_barrier(0);
  __builtin_amdgcn_s_barrier();

  for (int kt = 0; kt < 32; ++kt) {
    const bool st = (kt + 2 < 32);
    // ---- phase 0: frags m0-3 + all b; stage A of kt+2 ----
    bf16x8 a[8], b[4];
#pragma unroll
    for (int mi = 0; mi < 4; ++mi)
      a[mi] = *(const bf16x8*)&a0[(wr * 64 + mi * 8 + fr2) * 64 + aslot];
#pragma unroll
    for (int ni = 0; ni < 4; ++ni)
      b[ni] = *(const bf16x8*)&b0[(wc * 32 + ni * 8 + fr2) * 64 + aslot];
    if (st) STAGE_A(kt + 2, a2);
    __builtin_amdgcn_s_barrier();
    asm volatile("s_waitcnt lgkmcnt(0)" ::: "memory");
    __builtin_amdgcn_sched_barrier(0);
    __builtin_amdgcn_s_setprio(1);
#pragma unroll
    for (int mi = 0; mi < 4; ++mi)
#pragma unroll
      for (int ni = 0; ni < 4; ++ni)
        acc[mi][ni] = __builtin_amdgcn_mfma_f32_16x16x32_bf16(a[mi], b[ni], acc[mi][ni], 0, 0, 0);
    __builtin_amdgcn_s_setprio(0);
    __builtin_amdgcn_s_barrier();

    // ---- phase 1: frags m4-7; stage B of kt+2 ----
#pragma unroll
    for (int mi = 4; mi < 8; ++mi)
      a[mi] = *(const bf16x8*)&a0[(wr * 64 + mi * 8 + fr2) * 64 + aslot];
    if (st) STAGE_B(kt + 2, b2);
    __builtin_amdgcn_s_barrier();
    asm volatile("s_waitcnt lgkmcnt(0)" ::: "memory");
    __builtin_amdgcn_sched_barrier(0);
    __builtin_amdgcn_s_setprio(1);
#pragma unroll
    for (int mi = 4; mi < 8; ++mi)
#pragma unroll
      for (int ni = 0; ni < 4; ++ni)
        acc[mi][ni] = __builtin_amdgcn_mfma_f32_16x16x32_bf16(a[mi], b[ni], acc[mi][ni], 0, 0, 0);
    __builtin_amdgcn_s_setprio(0);
    if (kt < 31) {
      if (st) asm volatile("s_waitcnt vmcnt(4)" ::: "memory");
      else    asm volatile("s_waitcnt vmcnt(0)" ::: "memory");
      __builtin_amdgcn_sched_barrier(0);
    }
    __builtin_amdgcn_s_barrier();

    u16* t;
    t = a0; a0 = a1; a1 = a2; a2 = t;
    t = b0; b0 = b1; b1 = b2; b2 = t;
  }

  // ---- epilogue ----
  __syncthreads();
  if (MODE == 2) {
    // rope + transpose: wave strip = head; bounce f32, rope from tab, write [bh][s][d]
    float* fw = (float*)&As[0] + wave * 1024;
    const int hh = (n0 >> 6) + wc;
    const int lane = tid & 63;
    const int row = lane >> 2;
    const int jb = (lane & 3) * 8;
    float bvv[4];
#pragma unroll
    for (int ni = 0; ni < 4; ++ni) bvv[ni] = bias[n0 + wc * 64 + ni * 16 + fr];
#pragma unroll
    for (int mi = 0; mi < 8; ++mi) {
#pragma unroll
      for (int ni = 0; ni < 4; ++ni)
#pragma unroll
        for (int r = 0; r < 4; ++r)
          fw[(fo * 4 + r) * 64 + ni * 16 + fr] = acc[mi][ni][r] + bvv[ni];
      int m = m0 + wr * 128 + mi * 16 + row;
      if (m < Mloc) {
        int bb = (u32)m / 500u;
        int ss = m - bb * 500;
        u16* dst = (u16*)Cout + (((size_t)(bb * 16 + hh)) * 500 + ss) * 64;
        bf16x8 va, vb;
#pragma unroll
        for (int p = 0; p < 8; ++p) {
          int j = jb + p;
          float x0 = fw[row * 64 + j];
          float x1 = fw[row * 64 + 32 + j];
          float xe = fw[row * 64 + 2 * j];
          float xo = fw[row * 64 + 2 * j + 1];
          f32x2 cn = *(const f32x2*)(tabg + (ss * 32 + j) * 2);
          va[p] = (short)f2bf(x0 * cn[0] - xo * cn[1]);
          vb[p] = (short)f2bf(x1 * cn[0] + xe * cn[1]);
        }
        *(bf16x8*)(dst + jb) = va;
        *(bf16x8*)(dst + 32 + jb) = vb;
      }
      __builtin_amdgcn_s_barrier();
    }
  } else if (MODE == 1 || MODE == 3) {
    u16* bw = (u16*)&As[0] + wave * 2048;
#pragma unroll
    for (int mi = 0; mi < 8; ++mi) {
#pragma unroll
      for (int ni = 0; ni < 4; ++ni) {
        float bv = bias[n0 + wc * 64 + ni * 16 + fr];
#pragma unroll
        for (int r = 0; r < 4; ++r)
          bw[(fo * 4 + r) * 64 + ni * 16 + fr] = f2bf(acc[mi][ni][r] + bv);
      }
      int lane = tid & 63;
      int ro = lane >> 2, ch = lane & 3;
      int m = m0 + wr * 128 + mi * 16 + ro;
      bf16x8 v0 = *(const bf16x8*)&bw[ro * 64 + ch * 16];
      bf16x8 v1 = *(const bf16x8*)&bw[ro * 64 + ch * 16 + 8];
      if (m < Mloc) {
        u16* dst = (u16*)Cout + (crowbase + m) * 1024 + n0 + wc * 64 + ch * 16;
        *(bf16x8*)dst = v0;
        *(bf16x8*)(dst + 8) = v1;
      }
    }
  } else {
    float* fw = (float*)&As[0] + wave * 1024;
#pragma unroll
    for (int mi = 0; mi < 8; ++mi) {
#pragma unroll
      for (int ni = 0; ni < 4; ++ni) {
        float bv = bias[n0 + wc * 64 + ni * 16 + fr];
#pragma unroll
        for (int r = 0; r < 4; ++r)
          fw[(fo * 4 + r) * 64 + ni * 16 + fr] = acc[mi][ni][r] + bv;
      }
      int lane = tid & 63;
      int ro = lane >> 2, ch = lane & 3;
      int m = m0 + wr * 128 + mi * 16 + ro;
      f32x4 v0 = *(const f32x4*)&fw[ro * 64 + ch * 16];
      f32x4 v1 = *(const f32x4*)&fw[ro * 64 + ch * 16 + 4];
      f32x4 v2 = *(const f32x4*)&fw[ro * 64 + ch * 16 + 8];
      f32x4 v3 = *(const f32x4*)&fw[ro * 64 + ch * 16 + 12];
      if (m < Mloc) {
        float* dst = (float*)Cout + (size_t)m * 1024 + n0 + wc * 64 + ch * 16;
        *(f32x4*)dst = v0;
        *(f32x4*)(dst + 4) = v1;
        *(f32x4*)(dst + 8) = v2;
        *(f32x4*)(dst + 12) = v3;
      }
    }
  }
}

// ---------------- K: rope + compact-source gather -> pre-swizzled tiles [bh][tile][64][128B] ---
__global__ __launch_bounds__(256) void gather_k(const u16* __restrict__ PkC,
                                                const float* __restrict__ tab,
                                                const u16* __restrict__ karr,
                                                const int* __restrict__ kept,
                                                u16* __restrict__ Ktg) {
  const int tile = blockIdx.x;
  const int bh = blockIdx.y;
  const int h = bh & 15, b = bh >> 4;
  if (tile * 64 >= kept[b]) return;
  char* out = (char*)(Ktg + ((size_t)bh * 8 + tile) * 4096);
  const int tid = threadIdx.x;
#pragma unroll
  for (int i = 0; i < 8; ++i) {
    int item = i * 256 + tid;            // 2048 = 64 rows * 32 j
    int row = item >> 5, j = item & 31;
    int rk = tile * 64 + row;
    int tok = karr[b * 512 + rk];
    int sw = (row & 7) << 4;
    u16 o0 = 0, o1 = 0;
    if (tok != 0xFFFF) {
      const u16* src = PkC + ((size_t)b * 512 + rk) * 1024 + h * 64;   // compact rank row
      float x0 = bf2f(src[j]);
      float x1 = bf2f(src[32 + j]);
      float xe = bf2f(src[2 * j]);
      float xo = bf2f(src[2 * j + 1]);
      f32x2 cn = *(const f32x2*)(tab + (tok * 32 + j) * 2);
      o0 = f2bf(x0 * cn[0] - xo * cn[1]);
      o1 = f2bf(x1 * cn[0] + xe * cn[1]);
    }
    *(u16*)(out + row * 128 + ((2 * j) ^ sw)) = o0;
    *(u16*)(out + row * 128 + ((64 + 2 * j) ^ sw)) = o1;
  }
}

// ---------------- V: compact-source gather + transpose -> pre-swizzled V^T tiles --------------
__global__ __launch_bounds__(256) void gather_v(const u16* __restrict__ PvC,
                                                const u16* __restrict__ karr,
                                                const int* __restrict__ kept,
                                                u16* __restrict__ Vtg) {
  const int tile = blockIdx.x;
  const int bh = blockIdx.y;
  const int h = bh & 15, b = bh >> 4;
  if (tile * 64 >= kept[b]) return;
  const int tid = threadIdx.x;
  __shared__ __attribute__((aligned(16))) u16 Vl[64 * 64];
#pragma unroll
  for (int i = 0; i < 2; ++i) {
    int chunk = i * 256 + tid;           // 512: slot(64) x seg(8)
    int slot = chunk >> 3, seg = chunk & 7;
    int rk = tile * 64 + slot;
    int tok = karr[b * 512 + rk];
    bf16x8 v;
#pragma unroll
    for (int p = 0; p < 8; ++p) v[p] = 0;
    if (tok != 0xFFFF)
      v = *(const bf16x8*)(PvC + ((size_t)b * 512 + rk) * 1024 + h * 64 + seg * 8);
    *(bf16x8*)&Vl[slot * 64 + seg * 8] = v;
  }
  __syncthreads();
  u16* out = Vtg + ((size_t)bh * 8 + tile) * 4096;
#pragma unroll
  for (int i = 0; i < 2; ++i) {
    int chunk = i * 256 + tid;           // d(64) x c16(8)
    int d = chunk >> 3, c16 = chunk & 7;
    int k0 = ((c16 * 16) ^ ((d & 7) << 4)) >> 1;
    bf16x8 v;
#pragma unroll
    for (int p = 0; p < 8; ++p) v[p] = (short)Vl[(k0 + p) * 64 + d];
    *(bf16x8*)(out + chunk * 8) = v;
  }
}

// ---------------- flash attention: compressed k, swapped QK^T, in-reg softmax ----------------
__global__ __launch_bounds__(512) void attn_kernel(const u16* __restrict__ Qr,
                                                   const u16* __restrict__ Ktg,
                                                   const u16* __restrict__ Vtg,
                                                   const float* __restrict__ rel_emb,
                                                   const u16* __restrict__ karr,
                                                   const int* __restrict__ kept,
                                                   u16* __restrict__ AO) {
  const int bid = blockIdx.x;
  const int bh = ((bid >> 5) << 3) | (bid & 7);
  const int qb = (bid >> 3) & 3;
  const int h = bh & 15, b = bh >> 4;
  const int q0 = qb * 128;
  const int tid = threadIdx.x;
  const int wave = tid >> 6;
  const int fr = tid & 15, fo = (tid >> 4) & 3;

  __shared__ __attribute__((aligned(16))) u16 Ks[2][4096];
  __shared__ __attribute__((aligned(16))) u16 Vs[2][4096];
  __shared__ __attribute__((aligned(16))) u16 Pl[8][1024];
  __shared__ float rel2[640];
  __shared__ u16 okk[512];

  const int nt = (kept[b] + 63) >> 6;
  const float LOG2E = 1.44269504f;
  for (int i = tid; i < 640; i += 512) {
    int g = min(max(q0 - 12 + i, 0), 998);
    rel2[i] = (i == 0) ? -1e30f : rel_emb[g * 16 + h] * LOG2E;   // rel2[0] = pad sentinel
  }
  okk[tid] = karr[b * 512 + tid];

  const int qloc = wave * 16 + fr;
  const int qc = qloc + 511;             // pad slot (ok=0xFFFF) -> idx<0 -> clamp 0 -> -1e30
  const u16* Qb = Qr + ((size_t)bh * 500 + min(q0 + qloc, 499)) * 64;
  bf16x8 qf0 = *(const bf16x8*)(Qb + fo * 8);
  bf16x8 qf1 = *(const bf16x8*)(Qb + 32 + fo * 8);

  f32x4 o[4];
#pragma unroll
  for (int nf = 0; nf < 4; ++nf)
#pragma unroll
    for (int j = 0; j < 4; ++j) o[nf][j] = 0.f;
  float mrun = -1e30f, lrun = 0.f;

  const u16* Kb = Ktg + (size_t)bh * 32768;
  const u16* Vb = Vtg + (size_t)bh * 32768;
  const int sw = (fr & 7) << 4;
  const float SC = 0.18033688f;          // 0.125 * log2(e)

  if (nt > 0) {
    async16(&Ks[0][tid * 8], Kb + tid * 8);
    async16(&Vs[0][tid * 8], Vb + tid * 8);
  }
  __syncthreads();

  for (int t = 0; t < nt; ++t) {
    const int cur = t & 1;
    if (t + 1 < nt) {
      async16(&Ks[cur ^ 1][tid * 8], Kb + (t + 1) * 4096 + tid * 8);
      async16(&Vs[cur ^ 1][tid * 8], Vb + (t + 1) * 4096 + tid * 8);
    }
    const char* Kt = (const char*)(cur ? &Ks[1][0] : &Ks[0][0]);
    const char* Vt = (const char*)(cur ? &Vs[1][0] : &Vs[0][0]);

    f32x4 sacc[4];
    __builtin_amdgcn_s_setprio(1);
#pragma unroll
    for (int nf = 0; nf < 4; ++nf) {
#pragma unroll
      for (int jj = 0; jj < 4; ++jj) sacc[nf][jj] = 0.f;
      int rb = (nf * 16 + fr) * 128;
      bf16x8 kb0 = *(const bf16x8*)(Kt + rb + ((fo * 16) ^ sw));
      bf16x8 kb1 = *(const bf16x8*)(Kt + rb + ((64 + fo * 16) ^ sw));
      sacc[nf] = __builtin_amdgcn_mfma_f32_16x16x32_bf16(kb0, qf0, sacc[nf], 0, 0, 0);
      sacc[nf] = __builtin_amdgcn_mfma_f32_16x16x32_bf16(kb1, qf1, sacc[nf], 0, 0, 0);
    }
    __builtin_amdgcn_s_setprio(0);

    float p2[4][4];
    float pmax = -3e30f;
#pragma unroll
    for (int nf = 0; nf < 4; ++nf) {
      u16x4 ok4 = *(const u16x4*)&okk[t * 64 + nf * 16 + fo * 4];
#pragma unroll
      for (int r = 0; r < 4; ++r) {
        int idx2 = max(qc - (int)ok4[r], 0);
        float s2 = fmaf(sacc[nf][r], SC, rel2[idx2]);
        p2[nf][r] = s2;
        pmax = fmaxf(pmax, s2);
      }
    }
    pmax = fmaxf(pmax, __shfl_xor(pmax, 16, 64));
    pmax = fmaxf(pmax, __shfl_xor(pmax, 32, 64));

    if (!__all(pmax <= mrun + 8.0f)) {   // defer-max (T13)
      float mnew = fmaxf(mrun, pmax);
      float scl = EXP2(mrun - mnew);
      lrun *= scl;
#pragma unroll
      for (int nf = 0; nf < 4; ++nf)
#pragma unroll
        for (int r = 0; r < 4; ++r) o[nf][r] *= scl;
      mrun = mnew;
    }

    float lsum = 0.f;
#pragma unroll
    for (int nf = 0; nf < 4; ++nf) {
      float e0 = EXP2(p2[nf][0] - mrun);
      float e1 = EXP2(p2[nf][1] - mrun);
      float e2 = EXP2(p2[nf][2] - mrun);
      float e3 = EXP2(p2[nf][3] - mrun);
      lsum += (e0 + e1) + (e2 + e3);
      uint2 w; w.x = cvtpk(e0, e1); w.y = cvtpk(e2, e3);
      *(uint2*)((char*)&Pl[wave][0] + fr * 128 + ((nf * 32 + fo * 8) ^ sw)) = w;
    }
    lsum += __shfl_xor(lsum, 16, 64);
    lsum += __shfl_xor(lsum, 32, 64);
    lrun += lsum;

    bf16x8 pa0 = *(const bf16x8*)((char*)&Pl[wave][0] + fr * 128 + ((fo * 16) ^ sw));
    bf16x8 pa1 = *(const bf16x8*)((char*)&Pl[wave][0] + fr * 128 + ((64 + fo * 16) ^ sw));
    __builtin_amdgcn_s_setprio(1);
#pragma unroll
    for (int nf = 0; nf < 4; ++nf) {
      int rb = (nf * 16 + fr) * 128;
      bf16x8 vb0 = *(const bf16x8*)(Vt + rb + ((fo * 16) ^ sw));
      bf16x8 vb1 = *(const bf16x8*)(Vt + rb + ((64 + fo * 16) ^ sw));
      o[nf] = __builtin_amdgcn_mfma_f32_16x16x32_bf16(vb0, pa0, o[nf], 0, 0, 0);
      o[nf] = __builtin_amdgcn_mfma_f32_16x16x32_bf16(vb1, pa1, o[nf], 0, 0, 0);
    }
    __builtin_amdgcn_s_setprio(0);
    __syncthreads();
  }

  float inv = (lrun > 0.f) ? 1.f / lrun : 0.f;
#pragma unroll
  for (int nf = 0; nf < 4; ++nf) {
    float v0 = fminf(fmaxf(o[nf][0] * inv, -30.f), 30.f);
    float v1 = fminf(fmaxf(o[nf][1] * inv, -30.f), 30.f);
    float v2 = fminf(fmaxf(o[nf][2] * inv, -30.f), 30.f);
    float v3 = fminf(fmaxf(o[nf][3] * inv, -30.f), 30.f);
    uint2 w; w.x = cvtpk(v0, v1); w.y = cvtpk(v2, v3);
    *(uint2*)((char*)&Pl[wave][0] + fr * 128 + ((nf * 32 + fo * 8) ^ sw)) = w;
  }
  {
    int lane = tid & 63;
    int ro = lane >> 2, c = lane & 3;
    int swr = (ro & 7) << 4;
    const char* Pw = (const char*)&Pl[wave][0];
    bf16x8 v0 = *(const bf16x8*)(Pw + ro * 128 + ((c * 32) ^ swr));
    bf16x8 v1 = *(const bf16x8*)(Pw + ro * 128 + ((c * 32 + 16) ^ swr));
    int token = q0 + wave * 16 + ro;
    if (token < 500) {
      u16* dst = AO + (size_t)(b * 500 + token) * 1024 + h * 64 + c * 16;
      *(bf16x8*)dst = v0;
      *(bf16x8*)(dst + 8) = v1;
    }
  }
}

// ---------------- launch ----------------
extern "C" void kernel_launch(void* const* d_in, const int* in_sizes, int n_in,
                              void* d_out, int out_size, void* d_ws, size_t ws_size,
                              hipStream_t stream) {
  const float* query = (const float*)d_in[0];
  const float* key_  = (const float*)d_in[1];
  const float* value = (const float*)d_in[2];
  const void*  mask  = d_in[3];
  const float* Wq = (const float*)d_in[4];
  const float* bq = (const float*)d_in[5];
  const float* Wk = (const float*)d_in[6];
  const float* bk = (const float*)d_in[7];
  const float* Wv = (const float*)d_in[8];
  const float* bv = (const float*)d_in[9];
  const float* Wo = (const float*)d_in[10];
  const float* bo = (const float*)d_in[11];
  const float* rel = (const float*)d_in[12];

  // ws map: Wb 8.39MB | 4 slots x 32MiB | misc ~0.26MB
  // slot liveness: A: Xq(full)->PkC->Vtg | B: XkC->Ktg | C: XvC->Qro | D: PvC->AO
  char* ws = (char*)d_ws;
  const size_t SLOT = 33554432;
  u16* Wb = (u16*)ws;
  char* Aq = ws + 8388608;
  char* Bq = Aq + SLOT;
  char* Cq = Bq + SLOT;
  char* Dq = Cq + SLOT;
  char* MISC = Dq + SLOT;
  u8*  maskb = (u8*)MISC;
  u16* karr  = (u16*)(MISC + 65536);
  int* kept  = (int*)(MISC + 131072);
  float* tab = (float*)(MISC + 131584);

  mask_prep<<<1, 256, 0, stream>>>(mask, maskb);
  build_gather<<<32, 512, 0, stream>>>(maskb, karr, kept);
  rope_table<<<63, 256, 0, stream>>>(tab);

  cvt_f32_bf16<<<512, 256, 0, stream>>>(Wq, Wb + 0 * 1048576, 262144);
  cvt_f32_bf16<<<512, 256, 0, stream>>>(Wk, Wb + 1 * 1048576, 262144);
  cvt_f32_bf16<<<512, 256, 0, stream>>>(Wv, Wb + 2 * 1048576, 262144);
  cvt_f32_bf16<<<512, 256, 0, stream>>>(Wo, Wb + 3 * 1048576, 262144);
  cvt_f32_bf16<<<2048, 256, 0, stream>>>(query, (u16*)Aq, 4096000);                 // Xq full
  gathercvt<<<dim3(256, 32), 256, 0, stream>>>(key_,   karr, kept, (u16*)Bq);       // XkC compact
  gathercvt<<<dim3(256, 32), 256, 0, stream>>>(value,  karr, kept, (u16*)Cq);       // XvC compact

  gemm_bt<3><<<256, 512, 0, stream>>>((u16*)Cq, Wb + 2 * 1048576, bv, Dq, 0, tab, kept);   // PvC=D
  gemm_bt<2><<<252, 512, 0, stream>>>((u16*)Aq, Wb + 0 * 1048576, bq, Cq, 16000, tab, nullptr); // Qro=C
  gemm_bt<3><<<256, 512, 0, stream>>>((u16*)Bq, Wb + 1 * 1048576, bk, Aq, 0, tab, kept);   // PkC=A

  gather_k<<<dim3(8, 512), 256, 0, stream>>>((u16*)Aq, tab, karr, kept, (u16*)Bq);  // Ktg=B
  gather_v<<<dim3(8, 512), 256, 0, stream>>>((u16*)Dq, karr, kept, (u16*)Aq);       // Vtg=A

  attn_kernel<<<2048, 512, 0, stream>>>((u16*)Cq, (u16*)Bq, (u16*)Aq, rel,
                                        karr, kept, (u16*)Dq);                  // AO=D

  gemm_bt<0><<<252, 512, 0, stream>>>((u16*)Dq, Wb + 3 * 1048576, bo, (float*)d_out, 16000, tab, nullptr);
}

// Round 13
// 297.294 us; speedup vs baseline: 1.2613x; 1.1028x over previous
//
#include <hip/hip_runtime.h>
#include <math.h>

// FlashMultiHeadAttention: B=32 S=500 H=1024 NH=16 HD=64, rope + rel-pos-bias + key-pad mask.
// Pipeline: [gather-list scan w/ inline mask-mode detect] [rope table] [cvt W x4 fused]
//           [cvt Q] [gather+cvt K/V kept rows fused] [K/V proj GEMM COMPACT]
//           [Q proj GEMM fusing rope+transpose] [rope+gather+swizzle K tiles]
//           [gather+transpose+swizzle V tiles] [flash attn] [out proj GEMM]
// GEMM core: BK=64, 2 LDS buffers (128KB), T3-minimum single-barrier loop
//            {STAGE(t+1) -> ds_read -> lgkm(0) -> MFMA -> vmcnt(0) -> barrier}.

typedef unsigned short u16;
typedef unsigned int   u32;
typedef unsigned char  u8;
using bf16x8 = __attribute__((ext_vector_type(8))) short;
using f32x4  = __attribute__((ext_vector_type(4))) float;
using f32x2  = __attribute__((ext_vector_type(2))) float;
using u16x4  = __attribute__((ext_vector_type(4))) unsigned short;

#define DEV __device__ __forceinline__

#if __has_builtin(__builtin_amdgcn_exp2f)
#define EXP2(x) __builtin_amdgcn_exp2f(x)
#else
#define EXP2(x) exp2f(x)
#endif

DEV u16 f2bf(float f) {                 // RNE f32 -> bf16
  union { float f; u32 u; } c; c.f = f;
  u32 u = c.u;
  return (u16)((u + 0x7FFFu + ((u >> 16) & 1u)) >> 16);
}
DEV float bf2f(u16 h) {
  union { u32 u; float f; } c; c.u = ((u32)h) << 16;
  return c.f;
}
DEV u32 cvtpk(float a, float b) {       // packed pair via HW cvt (T12)
  u32 r;
  asm("v_cvt_pk_bf16_f32 %0, %1, %2" : "=v"(r) : "v"(a), "v"(b));
  return r;
}

// async global->LDS, 16B/lane; LDS dest = wave-uniform base + lane*16 (linear).
DEV void async16(void* l, const void* g) {
  __builtin_amdgcn_global_load_lds(
      (__attribute__((address_space(1))) unsigned int*)g,
      (__attribute__((address_space(3))) unsigned int*)l, 16, 0, 0);
}

// ---------------- gather list + inline mask-mode detection ----------------
__global__ __launch_bounds__(512) void build_gather(const void* __restrict__ mraw,
                                                    u16* __restrict__ karr,
                                                    int* __restrict__ kept) {
  const int b = blockIdx.x;
  const int t = threadIdx.x;
  const int lane = t & 63, wave = t >> 6;
  __shared__ int s_li, s_lf;
  __shared__ int wbase[8];
  __shared__ int wpop[8];
  if (t == 0) { s_li = 0; s_lf = 0; }
  __syncthreads();
  const u32* w = (const u32*)mraw;
  int li = 0, lf = 0;
  for (int g = t; g < 4000; g += 512) {      // same 4000 words in every block -> same mode
    u32 v = w[g];
    li |= !(v == 0u || v == 1u);
    lf |= !(v == 0u || v == 0x3F800000u);
  }
  if (li) atomicOr(&s_li, 1);
  if (lf) atomicOr(&s_lf, 1);
  __syncthreads();
  const int mode = (!s_li) ? 0 : ((!s_lf) ? 1 : 2);   // 0=int32, 1=float32, 2=uint8
  int v = 0;
  if (t < 500) {
    if (mode == 0)      v = ((const int*)mraw)[b * 500 + t] != 0;
    else if (mode == 1) v = (((const float*)mraw)[b * 500 + t] != 0.0f);
    else                v = ((const u8*)mraw)[b * 500 + t] != 0;
  }
  unsigned long long bal = __ballot(v != 0);
  karr[b * 512 + t] = 0xFFFF;
  if (lane == 0) wpop[wave] = __popcll(bal);
  __syncthreads();
  if (t == 0) {
    int s = 0;
    for (int ww = 0; ww < 8; ++ww) { wbase[ww] = s; s += wpop[ww]; }
    kept[b] = s;
  }
  __syncthreads();
  if (v) {
    int rank = wbase[wave] + __popcll(bal & ((1ull << lane) - 1ull));
    karr[b * 512 + rank] = (u16)t;
  }
}

// ---------------- rope cos/sin table: tab[(s*32+j)*2] = cos, +1 = sin ----------------
__global__ __launch_bounds__(256) void rope_table(float* __restrict__ tab) {
  int idx = blockIdx.x * 256 + threadIdx.x;
  if (idx >= 16000) return;
  int s = idx >> 5, j = idx & 31;
  float ang = (float)s * exp2f(-(float)j * 0.41524100f);  // 10000^(-j/32)
  float sn, cs;
  sincosf(ang, &sn, &cs);
  tab[idx * 2] = cs;
  tab[idx * 2 + 1] = sn;
}

// ---------------- weights f32 -> bf16, 4 matrices in one launch ----------------
__global__ __launch_bounds__(256) void cvt_w4(const float* __restrict__ w0,
                                              const float* __restrict__ w1,
                                              const float* __restrict__ w2,
                                              const float* __restrict__ w3,
                                              u16* __restrict__ dst) {
  const float* src = (blockIdx.y == 0) ? w0 : (blockIdx.y == 1) ? w1
                    : (blockIdx.y == 2) ? w2 : w3;
  int i = blockIdx.x * 256 + threadIdx.x;            // 262144 groups of 4
  f32x4 f = *(const f32x4*)(src + (size_t)i * 4);
  u16x4 o;
  o[0] = f2bf(f[0]); o[1] = f2bf(f[1]); o[2] = f2bf(f[2]); o[3] = f2bf(f[3]);
  *(u16x4*)(dst + (size_t)blockIdx.y * 1048576 + (size_t)i * 4) = o;
}

// ---------------- f32 -> bf16 convert (vectorized) ----------------
__global__ __launch_bounds__(256) void cvt_f32_bf16(const float* __restrict__ src,
                                                    u16* __restrict__ dst, int n4) {
  int i = blockIdx.x * 256 + threadIdx.x;
  int stride = gridDim.x * 256;
  for (; i < n4; i += stride) {
    f32x4 f = *(const f32x4*)(src + (size_t)i * 4);
    u16x4 o;
    o[0] = f2bf(f[0]); o[1] = f2bf(f[1]); o[2] = f2bf(f[2]); o[3] = f2bf(f[3]);
    *(u16x4*)(dst + (size_t)i * 4) = o;
  }
}

// ---------------- gather kept rows + cvt for K and V in one launch ----------------
__global__ __launch_bounds__(256) void gathercvt2(const float* __restrict__ srcK,
                                                  const float* __restrict__ srcV,
                                                  const u16* __restrict__ karr,
                                                  const int* __restrict__ kept,
                                                  u16* __restrict__ dstK,
                                                  u16* __restrict__ dstV) {
  const int b = blockIdx.y;
  const int r = blockIdx.x * 2 + (threadIdx.x >> 7);   // 512 rows/batch
  if (r >= kept[b]) return;
  const float* src = blockIdx.z ? srcV : srcK;
  u16* dst = blockIdx.z ? dstV : dstK;
  const int c = (threadIdx.x & 127) * 8;
  const int tok = karr[b * 512 + r];
  const float* s = src + ((size_t)b * 500 + tok) * 1024 + c;
  f32x4 f0 = *(const f32x4*)s;
  f32x4 f1 = *(const f32x4*)(s + 4);
  u16 o[8];
  o[0] = f2bf(f0[0]); o[1] = f2bf(f0[1]); o[2] = f2bf(f0[2]); o[3] = f2bf(f0[3]);
  o[4] = f2bf(f1[0]); o[5] = f2bf(f1[1]); o[6] = f2bf(f1[2]); o[7] = f2bf(f1[3]);
  *(bf16x8*)(dst + ((size_t)b * 512 + r) * 1024 + c) = *(bf16x8*)o;
}

// ---------------- GEMM: C[m][n] = sum_k A[m][k]*Bw[n][k] + bias[n] ----------------
// 256x256 tile, BK=64, 512 thr / 8 waves (2x4), per-wave 128x64. 2 LDS buffers [256][64]
// (128B rows, XOR slot swizzle; staged via inverse-swizzled global src, linear dest).
// T3-minimum loop: STAGE(t+1,buf^1) -> ds_read(kk0) lgkm MFMA -> ds_read(kk1) lgkm MFMA
//                  -> vmcnt(0) -> barrier. One barrier per 64-K.
// MODE: 0 f32 out; 1 bf16 out; 2 bf16+rope+transpose (Q); 3 compact kept-rank rows.
template <int MODE>
__global__ __launch_bounds__(512, 2) void gemm_bt(const u16* __restrict__ A,
                                                  const u16* __restrict__ Bw,
                                                  const float* __restrict__ bias,
                                                  void* __restrict__ Cout, int M,
                                                  const float* __restrict__ tabg,
                                                  const int* __restrict__ keptp) {
  const int bid = blockIdx.x;
  int m0, n0, Mloc;
  size_t abase, crowbase;
  if (MODE == 3) {
    const int swz = (bid & 7) * 32 + (bid >> 3);      // bijective: 256 = 8*32
    const int mb = swz >> 2;
    n0 = (swz & 3) * 256;
    const int b = mb >> 1, rb = mb & 1;
    const int kb = keptp[b];
    if (rb * 256 >= kb) return;
    m0 = rb * 256;
    Mloc = kb;
    abase = (size_t)b * 512 * 1024;
    crowbase = (size_t)b * 512;
  } else {
    const int xcd = bid & 7, idx = bid >> 3;
    const int swz = (xcd < 4 ? xcd * 32 : 128 + (xcd - 4) * 31) + idx;  // 252 = 4*32+4*31
    m0 = (swz >> 2) * 256;
    n0 = (swz & 3) * 256;
    Mloc = M;
    abase = 0;
    crowbase = 0;
  }
  const int tid = threadIdx.x;
  const int wave = tid >> 6;
  const int wr = wave >> 2, wc = wave & 3;
  const int fr = tid & 15, fo = (tid >> 4) & 3;
  const int sl0 = (fo ^ (fr & 7)) * 8;        // kk0 16B-slot (u16 offset in 64-u16 row)
  const int sl1 = ((4 + fo) ^ (fr & 7)) * 8;  // kk1

  __shared__ __attribute__((aligned(16))) u16 AS[2 * 16384];   // 64KB
  __shared__ __attribute__((aligned(16))) u16 BS[2 * 16384];   // 64KB

  f32x4 acc[8][4];
#pragma unroll
  for (int mi = 0; mi < 8; ++mi)
#pragma unroll
    for (int ni = 0; ni < 4; ++ni)
#pragma unroll
      for (int j = 0; j < 4; ++j) acc[mi][ni][j] = 0.f;

  // stage tile t (256 rows x 64 u16 per matrix): 2048 16B-chunks each, 4+4 per thread.
  // LDS row r slot s holds source k-chunk (s ^ (r&7)) -> reader finds chunk c at slot c^(r&7).
  auto STG = [&](int t, int buf) {
    u16* sA = &AS[buf * 16384];
    u16* sB = &BS[buf * 16384];
#pragma unroll
    for (int i = 0; i < 4; ++i) {
      int c = i * 512 + tid;
      int r = c >> 3, v = (c & 7) ^ (r & 7);
      int ar = min(m0 + r, Mloc - 1);
      async16(&sA[c * 8], A + abase + (size_t)ar * 1024 + t * 64 + v * 8);
    }
#pragma unroll
    for (int i = 0; i < 4; ++i) {
      int c = i * 512 + tid;
      int r = c >> 3, v = (c & 7) ^ (r & 7);
      async16(&sB[c * 8], Bw + (size_t)(n0 + r) * 1024 + t * 64 + v * 8);
    }
  };

  STG(0, 0);
  asm volatile("s_waitcnt vmcnt(0)" ::: "memory");
  __builtin_amdgcn_sched_barrier(0);
  __builtin_amdgcn_s_barrier();

  int cur = 0;
  for (int t = 0; t < 16; ++t) {
    if (t + 1 < 16) STG(t + 1, cur ^ 1);
    const u16* a0 = &AS[cur * 16384];
    const u16* b0 = &BS[cur * 16384];
    bf16x8 a[8], b[4];
    // ---- kk0 ----
#pragma unroll
    for (int mi = 0; mi < 8; ++mi)
      a[mi] = *(const bf16x8*)&a0[(wr * 128 + mi * 16 + fr) * 64 + sl0];
#pragma unroll
    for (int ni = 0; ni < 4; ++ni)
      b[ni] = *(const bf16x8*)&b0[(wc * 64 + ni * 16 + fr) * 64 + sl0];
    asm volatile("s_waitcnt lgkmcnt(0)" ::: "memory");
    __builtin_amdgcn_sched_barrier(0);
    __builtin_amdgcn_s_setprio(1);
#pragma unroll
    for (int mi = 0; mi < 8; ++mi)
#pragma unroll
      for (int ni = 0; ni < 4; ++ni)
        acc[mi][ni] = __builtin_amdgcn_mfma_f32_16x16x32_bf16(a[mi], b[ni], acc[mi][ni], 0, 0, 0);
    __builtin_amdgcn_s_setprio(0);
    // ---- kk1 ----
#pragma unroll
    for (int mi = 0; mi < 8; ++mi)
      a[mi] = *(const bf16x8*)&a0[(wr * 128 + mi * 16 + fr) * 64 + sl1];
#pragma unroll
    for (int ni = 0; ni < 4; ++ni)
      b[ni] = *(const bf16x8*)&b0[(wc * 64 + ni * 16 + fr) * 64 + sl1];
    asm volatile("s_waitcnt lgkmcnt(0)" ::: "memory");
    __builtin_amdgcn_sched_barrier(0);
    __builtin_amdgcn_s_setprio(1);
#pragma unroll
    for (int mi = 0; mi < 8; ++mi)
#pragma unroll
      for (int ni = 0; ni < 4; ++ni)
        acc[mi][ni] = __builtin_amdgcn_mfma_f32_16x16x32_bf16(a[mi], b[ni], acc[mi][ni], 0, 0, 0);
    __builtin_amdgcn_s_setprio(0);
    // next tile fully landed; all waves' reads of cur done (regs) -> single barrier
    asm volatile("s_waitcnt vmcnt(0)" ::: "memory");
    __builtin_amdgcn_sched_barrier(0);
    __builtin_amdgcn_s_barrier();
    cur ^= 1;
  }

  // ---- epilogue ----
  __syncthreads();
  if (MODE == 2) {
    // rope + transpose: wave strip = head; bounce f32, rope from tab, write [bh][s][d]
    float* fw = (float*)&AS[0] + wave * 1024;
    const int hh = (n0 >> 6) + wc;
    const int lane = tid & 63;
    const int row = lane >> 2;
    const int jb = (lane & 3) * 8;
    float bvv[4];
#pragma unroll
    for (int ni = 0; ni < 4; ++ni) bvv[ni] = bias[n0 + wc * 64 + ni * 16 + fr];
#pragma unroll
    for (int mi = 0; mi < 8; ++mi) {
#pragma unroll
      for (int ni = 0; ni < 4; ++ni)
#pragma unroll
        for (int r = 0; r < 4; ++r)
          fw[(fo * 4 + r) * 64 + ni * 16 + fr] = acc[mi][ni][r] + bvv[ni];
      int m = m0 + wr * 128 + mi * 16 + row;
      if (m < Mloc) {
        int bb = (u32)m / 500u;
        int ss = m - bb * 500;
        u16* dst = (u16*)Cout + (((size_t)(bb * 16 + hh)) * 500 + ss) * 64;
        bf16x8 va, vb;
#pragma unroll
        for (int p = 0; p < 8; ++p) {
          int j = jb + p;
          float x0 = fw[row * 64 + j];
          float x1 = fw[row * 64 + 32 + j];
          float xe = fw[row * 64 + 2 * j];
          float xo = fw[row * 64 + 2 * j + 1];
          f32x2 cn = *(const f32x2*)(tabg + (ss * 32 + j) * 2);
          va[p] = (short)f2bf(x0 * cn[0] - xo * cn[1]);
          vb[p] = (short)f2bf(x1 * cn[0] + xe * cn[1]);
        }
        *(bf16x8*)(dst + jb) = va;
        *(bf16x8*)(dst + 32 + jb) = vb;
      }
      __builtin_amdgcn_s_barrier();
    }
  } else if (MODE == 1 || MODE == 3) {
    u16* bw = (u16*)&AS[0] + wave * 2048;
#pragma unroll
    for (int mi = 0; mi < 8; ++mi) {
#pragma unroll
      for (int ni = 0; ni < 4; ++ni) {
        float bv = bias[n0 + wc * 64 + ni * 16 + fr];
#pragma unroll
        for (int r = 0; r < 4; ++r)
          bw[(fo * 4 + r) * 64 + ni * 16 + fr] = f2bf(acc[mi][ni][r] + bv);
      }
      int lane = tid & 63;
      int ro = lane >> 2, ch = lane & 3;
      int m = m0 + wr * 128 + mi * 16 + ro;
      bf16x8 v0 = *(const bf16x8*)&bw[ro * 64 + ch * 16];
      bf16x8 v1 = *(const bf16x8*)&bw[ro * 64 + ch * 16 + 8];
      if (m < Mloc) {
        u16* dst = (u16*)Cout + (crowbase + m) * 1024 + n0 + wc * 64 + ch * 16;
        *(bf16x8*)dst = v0;
        *(bf16x8*)(dst + 8) = v1;
      }
    }
  } else {
    float* fw = (float*)&AS[0] + wave * 1024;
#pragma unroll
    for (int mi = 0; mi < 8; ++mi) {
#pragma unroll
      for (int ni = 0; ni < 4; ++ni) {
        float bv = bias[n0 + wc * 64 + ni * 16 + fr];
#pragma unroll
        for (int r = 0; r < 4; ++r)
          fw[(fo * 4 + r) * 64 + ni * 16 + fr] = acc[mi][ni][r] + bv;
      }
      int lane = tid & 63;
      int ro = lane >> 2, ch = lane & 3;
      int m = m0 + wr * 128 + mi * 16 + ro;
      f32x4 v0 = *(const f32x4*)&fw[ro * 64 + ch * 16];
      f32x4 v1 = *(const f32x4*)&fw[ro * 64 + ch * 16 + 4];
      f32x4 v2 = *(const f32x4*)&fw[ro * 64 + ch * 16 + 8];
      f32x4 v3 = *(const f32x4*)&fw[ro * 64 + ch * 16 + 12];
      if (m < Mloc) {
        float* dst = (float*)Cout + (size_t)m * 1024 + n0 + wc * 64 + ch * 16;
        *(f32x4*)dst = v0;
        *(f32x4*)(dst + 4) = v1;
        *(f32x4*)(dst + 8) = v2;
        *(f32x4*)(dst + 12) = v3;
      }
    }
  }
}

// ---------------- K: rope + compact-source gather -> pre-swizzled tiles [bh][tile][64][128B] ---
__global__ __launch_bounds__(256) void gather_k(const u16* __restrict__ PkC,
                                                const float* __restrict__ tab,
                                                const u16* __restrict__ karr,
                                                const int* __restrict__ kept,
                                                u16* __restrict__ Ktg) {
  const int tile = blockIdx.x;
  const int bh = blockIdx.y;
  const int h = bh & 15, b = bh >> 4;
  if (tile * 64 >= kept[b]) return;
  char* out = (char*)(Ktg + ((size_t)bh * 8 + tile) * 4096);
  const int tid = threadIdx.x;
#pragma unroll
  for (int i = 0; i < 8; ++i) {
    int item = i * 256 + tid;            // 2048 = 64 rows * 32 j
    int row = item >> 5, j = item & 31;
    int rk = tile * 64 + row;
    int tok = karr[b * 512 + rk];
    int sw = (row & 7) << 4;
    u16 o0 = 0, o1 = 0;
    if (tok != 0xFFFF) {
      const u16* src = PkC + ((size_t)b * 512 + rk) * 1024 + h * 64;   // compact rank row
      float x0 = bf2f(src[j]);
      float x1 = bf2f(src[32 + j]);
      float xe = bf2f(src[2 * j]);
      float xo = bf2f(src[2 * j + 1]);
      f32x2 cn = *(const f32x2*)(tab + (tok * 32 + j) * 2);
      o0 = f2bf(x0 * cn[0] - xo * cn[1]);
      o1 = f2bf(x1 * cn[0] + xe * cn[1]);
    }
    *(u16*)(out + row * 128 + ((2 * j) ^ sw)) = o0;
    *(u16*)(out + row * 128 + ((64 + 2 * j) ^ sw)) = o1;
  }
}

// ---------------- V: compact-source gather + transpose -> pre-swizzled V^T tiles --------------
__global__ __launch_bounds__(256) void gather_v(const u16* __restrict__ PvC,
                                                const u16* __restrict__ karr,
                                                const int* __restrict__ kept,
                                                u16* __restrict__ Vtg) {
  const int tile = blockIdx.x;
  const int bh = blockIdx.y;
  const int h = bh & 15, b = bh >> 4;
  if (tile * 64 >= kept[b]) return;
  const int tid = threadIdx.x;
  __shared__ __attribute__((aligned(16))) u16 Vl[64 * 64];
#pragma unroll
  for (int i = 0; i < 2; ++i) {
    int chunk = i * 256 + tid;           // 512: slot(64) x seg(8)
    int slot = chunk >> 3, seg = chunk & 7;
    int rk = tile * 64 + slot;
    int tok = karr[b * 512 + rk];
    bf16x8 v;
#pragma unroll
    for (int p = 0; p < 8; ++p) v[p] = 0;
    if (tok != 0xFFFF)
      v = *(const bf16x8*)(PvC + ((size_t)b * 512 + rk) * 1024 + h * 64 + seg * 8);
    *(bf16x8*)&Vl[slot * 64 + seg * 8] = v;
  }
  __syncthreads();
  u16* out = Vtg + ((size_t)bh * 8 + tile) * 4096;
#pragma unroll
  for (int i = 0; i < 2; ++i) {
    int chunk = i * 256 + tid;           // d(64) x c16(8)
    int d = chunk >> 3, c16 = chunk & 7;
    int k0 = ((c16 * 16) ^ ((d & 7) << 4)) >> 1;
    bf16x8 v;
#pragma unroll
    for (int p = 0; p < 8; ++p) v[p] = (short)Vl[(k0 + p) * 64 + d];
    *(bf16x8*)(out + chunk * 8) = v;
  }
}

// ---------------- flash attention: compressed k, swapped QK^T, in-reg softmax ----------------
__global__ __launch_bounds__(512) void attn_kernel(const u16* __restrict__ Qr,
                                                   const u16* __restrict__ Ktg,
                                                   const u16* __restrict__ Vtg,
                                                   const float* __restrict__ rel_emb,
                                                   const u16* __restrict__ karr,
                                                   const int* __restrict__ kept,
                                                   u16* __restrict__ AO) {
  const int bid = blockIdx.x;
  const int bh = ((bid >> 5) << 3) | (bid & 7);
  const int qb = (bid >> 3) & 3;
  const int h = bh & 15, b = bh >> 4;
  const int q0 = qb * 128;
  const int tid = threadIdx.x;
  const int wave = tid >> 6;
  const int fr = tid & 15, fo = (tid >> 4) & 3;

  __shared__ __attribute__((aligned(16))) u16 Ks[2][4096];
  __shared__ __attribute__((aligned(16))) u16 Vs[2][4096];
  __shared__ __attribute__((aligned(16))) u16 Pl[8][1024];
  __shared__ float rel2[640];
  __shared__ u16 okk[512];

  const int nt = (kept[b] + 63) >> 6;
  const float LOG2E = 1.44269504f;
  for (int i = tid; i < 640; i += 512) {
    int g = min(max(q0 - 12 + i, 0), 998);
    rel2[i] = (i == 0) ? -1e30f : rel_emb[g * 16 + h] * LOG2E;   // rel2[0] = pad sentinel
  }
  okk[tid] = karr[b * 512 + tid];

  const int qloc = wave * 16 + fr;
  const int qc = qloc + 511;             // pad slot (ok=0xFFFF) -> idx<0 -> clamp 0 -> -1e30
  const u16* Qb = Qr + ((size_t)bh * 500 + min(q0 + qloc, 499)) * 64;
  bf16x8 qf0 = *(const bf16x8*)(Qb + fo * 8);
  bf16x8 qf1 = *(const bf16x8*)(Qb + 32 + fo * 8);

  f32x4 o[4];
#pragma unroll
  for (int nf = 0; nf < 4; ++nf)
#pragma unroll
    for (int j = 0; j < 4; ++j) o[nf][j] = 0.f;
  float mrun = -1e30f, lrun = 0.f;

  const u16* Kb = Ktg + (size_t)bh * 32768;
  const u16* Vb = Vtg + (size_t)bh * 32768;
  const int sw = (fr & 7) << 4;
  const float SC = 0.18033688f;          // 0.125 * log2(e)

  if (nt > 0) {
    async16(&Ks[0][tid * 8], Kb + tid * 8);
    async16(&Vs[0][tid * 8], Vb + tid * 8);
  }
  __syncthreads();

  for (int t = 0; t < nt; ++t) {
    const int cur = t & 1;
    if (t + 1 < nt) {
      async16(&Ks[cur ^ 1][tid * 8], Kb + (t + 1) * 4096 + tid * 8);
      async16(&Vs[cur ^ 1][tid * 8], Vb + (t + 1) * 4096 + tid * 8);
    }
    const char* Kt = (const char*)(cur ? &Ks[1][0] : &Ks[0][0]);
    const char* Vt = (const char*)(cur ? &Vs[1][0] : &Vs[0][0]);

    f32x4 sacc[4];
    __builtin_amdgcn_s_setprio(1);
#pragma unroll
    for (int nf = 0; nf < 4; ++nf) {
#pragma unroll
      for (int jj = 0; jj < 4; ++jj) sacc[nf][jj] = 0.f;
      int rb = (nf * 16 + fr) * 128;
      bf16x8 kb0 = *(const bf16x8*)(Kt + rb + ((fo * 16) ^ sw));
      bf16x8 kb1 = *(const bf16x8*)(Kt + rb + ((64 + fo * 16) ^ sw));
      sacc[nf] = __builtin_amdgcn_mfma_f32_16x16x32_bf16(kb0, qf0, sacc[nf], 0, 0, 0);
      sacc[nf] = __builtin_amdgcn_mfma_f32_16x16x32_bf16(kb1, qf1, sacc[nf], 0, 0, 0);
    }
    __builtin_amdgcn_s_setprio(0);

    float p2[4][4];
    float pmax = -3e30f;
#pragma unroll
    for (int nf = 0; nf < 4; ++nf) {
      u16x4 ok4 = *(const u16x4*)&okk[t * 64 + nf * 16 + fo * 4];
#pragma unroll
      for (int r = 0; r < 4; ++r) {
        int idx2 = max(qc - (int)ok4[r], 0);
        float s2 = fmaf(sacc[nf][r], SC, rel2[idx2]);
        p2[nf][r] = s2;
        pmax = fmaxf(pmax, s2);
      }
    }
    pmax = fmaxf(pmax, __shfl_xor(pmax, 16, 64));
    pmax = fmaxf(pmax, __shfl_xor(pmax, 32, 64));

    if (!__all(pmax <= mrun + 8.0f)) {   // defer-max (T13)
      float mnew = fmaxf(mrun, pmax);
      float scl = EXP2(mrun - mnew);
      lrun *= scl;
#pragma unroll
      for (int nf = 0; nf < 4; ++nf)
#pragma unroll
        for (int r = 0; r < 4; ++r) o[nf][r] *= scl;
      mrun = mnew;
    }

    float lsum = 0.f;
#pragma unroll
    for (int nf = 0; nf < 4; ++nf) {
      float e0 = EXP2(p2[nf][0] - mrun);
      float e1 = EXP2(p2[nf][1] - mrun);
      float e2 = EXP2(p2[nf][2] - mrun);
      float e3 = EXP2(p2[nf][3] - mrun);
      lsum += (e0 + e1) + (e2 + e3);
      uint2 w; w.x = cvtpk(e0, e1); w.y = cvtpk(e2, e3);
      *(uint2*)((char*)&Pl[wave][0] + fr * 128 + ((nf * 32 + fo * 8) ^ sw)) = w;
    }
    lsum += __shfl_xor(lsum, 16, 64);
    lsum += __shfl_xor(lsum, 32, 64);
    lrun += lsum;

    bf16x8 pa0 = *(const bf16x8*)((char*)&Pl[wave][0] + fr * 128 + ((fo * 16) ^ sw));
    bf16x8 pa1 = *(const bf16x8*)((char*)&Pl[wave][0] + fr * 128 + ((64 + fo * 16) ^ sw));
    __builtin_amdgcn_s_setprio(1);
#pragma unroll
    for (int nf = 0; nf < 4; ++nf) {
      int rb = (nf * 16 + fr) * 128;
      bf16x8 vb0 = *(const bf16x8*)(Vt + rb + ((fo * 16) ^ sw));
      bf16x8 vb1 = *(const bf16x8*)(Vt + rb + ((64 + fo * 16) ^ sw));
      o[nf] = __builtin_amdgcn_mfma_f32_16x16x32_bf16(vb0, pa0, o[nf], 0, 0, 0);
      o[nf] = __builtin_amdgcn_mfma_f32_16x16x32_bf16(vb1, pa1, o[nf], 0, 0, 0);
    }
    __builtin_amdgcn_s_setprio(0);
    __syncthreads();
  }

  float inv = (lrun > 0.f) ? 1.f / lrun : 0.f;
#pragma unroll
  for (int nf = 0; nf < 4; ++nf) {
    float v0 = fminf(fmaxf(o[nf][0] * inv, -30.f), 30.f);
    float v1 = fminf(fmaxf(o[nf][1] * inv, -30.f), 30.f);
    float v2 = fminf(fmaxf(o[nf][2] * inv, -30.f), 30.f);
    float v3 = fminf(fmaxf(o[nf][3] * inv, -30.f), 30.f);
    uint2 w; w.x = cvtpk(v0, v1); w.y = cvtpk(v2, v3);
    *(uint2*)((char*)&Pl[wave][0] + fr * 128 + ((nf * 32 + fo * 8) ^ sw)) = w;
  }
  {
    int lane = tid & 63;
    int ro = lane >> 2, c = lane & 3;
    int swr = (ro & 7) << 4;
    const char* Pw = (const char*)&Pl[wave][0];
    bf16x8 v0 = *(const bf16x8*)(Pw + ro * 128 + ((c * 32) ^ swr));
    bf16x8 v1 = *(const bf16x8*)(Pw + ro * 128 + ((c * 32 + 16) ^ swr));
    int token = q0 + wave * 16 + ro;
    if (token < 500) {
      u16* dst = AO + (size_t)(b * 500 + token) * 1024 + h * 64 + c * 16;
      *(bf16x8*)dst = v0;
      *(bf16x8*)(dst + 8) = v1;
    }
  }
}

// ---------------- launch ----------------
extern "C" void kernel_launch(void* const* d_in, const int* in_sizes, int n_in,
                              void* d_out, int out_size, void* d_ws, size_t ws_size,
                              hipStream_t stream) {
  const float* query = (const float*)d_in[0];
  const float* key_  = (const float*)d_in[1];
  const float* value = (const float*)d_in[2];
  const void*  mask  = d_in[3];
  const float* Wq = (const float*)d_in[4];
  const float* bq = (const float*)d_in[5];
  const float* Wk = (const float*)d_in[6];
  const float* bk = (const float*)d_in[7];
  const float* Wv = (const float*)d_in[8];
  const float* bv = (const float*)d_in[9];
  const float* Wo = (const float*)d_in[10];
  const float* bo = (const float*)d_in[11];
  const float* rel = (const float*)d_in[12];

  // ws map: Wb 8.39MB | 4 slots x 32MiB | misc ~0.26MB
  // slot liveness: A: Xq(full)->PkC->Vtg | B: XkC->Ktg | C: XvC->Qro | D: PvC->AO
  char* ws = (char*)d_ws;
  const size_t SLOT = 33554432;
  u16* Wb = (u16*)ws;
  char* Aq = ws + 8388608;
  char* Bq = Aq + SLOT;
  char* Cq = Bq + SLOT;
  char* Dq = Cq + SLOT;
  char* MISC = Dq + SLOT;
  u16* karr  = (u16*)(MISC + 65536);
  int* kept  = (int*)(MISC + 131072);
  float* tab = (float*)(MISC + 131584);

  build_gather<<<32, 512, 0, stream>>>(mask, karr, kept);
  rope_table<<<63, 256, 0, stream>>>(tab);
  cvt_w4<<<dim3(1024, 4), 256, 0, stream>>>(Wq, Wk, Wv, Wo, Wb);
  cvt_f32_bf16<<<2048, 256, 0, stream>>>(query, (u16*)Aq, 4096000);                 // Xq full
  gathercvt2<<<dim3(256, 32, 2), 256, 0, stream>>>(key_, value, karr, kept,
                                                   (u16*)Bq, (u16*)Cq);             // XkC, XvC

  gemm_bt<3><<<256, 512, 0, stream>>>((u16*)Cq, Wb + 2 * 1048576, bv, Dq, 0, tab, kept);   // PvC=D
  gemm_bt<2><<<252, 512, 0, stream>>>((u16*)Aq, Wb + 0 * 1048576, bq, Cq, 16000, tab, nullptr); // Qro=C
  gemm_bt<3><<<256, 512, 0, stream>>>((u16*)Bq, Wb + 1 * 1048576, bk, Aq, 0, tab, kept);   // PkC=A

  gather_k<<<dim3(8, 512), 256, 0, stream>>>((u16*)Aq, tab, karr, kept, (u16*)Bq);  // Ktg=B
  gather_v<<<dim3(8, 512), 256, 0, stream>>>((u16*)Dq, karr, kept, (u16*)Aq);       // Vtg=A

  attn_kernel<<<2048, 512, 0, stream>>>((u16*)Cq, (u16*)Bq, (u16*)Aq, rel,
                                        karr, kept, (u16*)Dq);                  // AO=D

  gemm_bt<0><<<252, 512, 0, stream>>>((u16*)Dq, Wb + 3 * 1048576, bo, (float*)d_out, 16000, tab, nullptr);
}

// Round 14
// 291.997 us; speedup vs baseline: 1.2842x; 1.0181x over previous
//
#include <hip/hip_runtime.h>
#include <math.h>

// FlashMultiHeadAttention: B=32 S=500 H=1024 NH=16 HD=64, rope + rel-pos-bias + key-pad mask.
// Pipeline: [gather-list scan w/ inline mask-mode detect] [rope table] [cvt W x4 fused]
//           [cvt Q] [gather+cvt K/V kept rows fused] [K/V proj GEMM COMPACT]
//           [Q proj GEMM fusing rope+transpose] [rope+gather+swizzle K tiles]
//           [gather+transpose+swizzle V tiles] [flash attn] [out proj GEMM]
// GEMM core: 256x128 tile, BK=32, 2 LDS buffers (48KB -> 3 blocks/CU), grid 504/512,
//            T3-minimum loop; co-resident blocks hide the stage drain (m114 TLP).

typedef unsigned short u16;
typedef unsigned int   u32;
typedef unsigned char  u8;
using bf16x8 = __attribute__((ext_vector_type(8))) short;
using f32x4  = __attribute__((ext_vector_type(4))) float;
using f32x2  = __attribute__((ext_vector_type(2))) float;
using u16x4  = __attribute__((ext_vector_type(4))) unsigned short;

#define DEV __device__ __forceinline__

#if __has_builtin(__builtin_amdgcn_exp2f)
#define EXP2(x) __builtin_amdgcn_exp2f(x)
#else
#define EXP2(x) exp2f(x)
#endif

DEV u16 f2bf(float f) {                 // RNE f32 -> bf16
  union { float f; u32 u; } c; c.f = f;
  u32 u = c.u;
  return (u16)((u + 0x7FFFu + ((u >> 16) & 1u)) >> 16);
}
DEV float bf2f(u16 h) {
  union { u32 u; float f; } c; c.u = ((u32)h) << 16;
  return c.f;
}
DEV u32 cvtpk(float a, float b) {       // packed pair via HW cvt (T12)
  u32 r;
  asm("v_cvt_pk_bf16_f32 %0, %1, %2" : "=v"(r) : "v"(a), "v"(b));
  return r;
}

// async global->LDS, 16B/lane; LDS dest = wave-uniform base + lane*16 (linear).
DEV void async16(void* l, const void* g) {
  __builtin_amdgcn_global_load_lds(
      (__attribute__((address_space(1))) unsigned int*)g,
      (__attribute__((address_space(3))) unsigned int*)l, 16, 0, 0);
}

// ---------------- gather list + inline mask-mode detection ----------------
__global__ __launch_bounds__(512) void build_gather(const void* __restrict__ mraw,
                                                    u16* __restrict__ karr,
                                                    int* __restrict__ kept) {
  const int b = blockIdx.x;
  const int t = threadIdx.x;
  const int lane = t & 63, wave = t >> 6;
  __shared__ int s_li, s_lf;
  __shared__ int wbase[8];
  __shared__ int wpop[8];
  if (t == 0) { s_li = 0; s_lf = 0; }
  __syncthreads();
  const u32* w = (const u32*)mraw;
  int li = 0, lf = 0;
  for (int g = t; g < 4000; g += 512) {      // same 4000 words in every block -> same mode
    u32 v = w[g];
    li |= !(v == 0u || v == 1u);
    lf |= !(v == 0u || v == 0x3F800000u);
  }
  if (li) atomicOr(&s_li, 1);
  if (lf) atomicOr(&s_lf, 1);
  __syncthreads();
  const int mode = (!s_li) ? 0 : ((!s_lf) ? 1 : 2);   // 0=int32, 1=float32, 2=uint8
  int v = 0;
  if (t < 500) {
    if (mode == 0)      v = ((const int*)mraw)[b * 500 + t] != 0;
    else if (mode == 1) v = (((const float*)mraw)[b * 500 + t] != 0.0f);
    else                v = ((const u8*)mraw)[b * 500 + t] != 0;
  }
  unsigned long long bal = __ballot(v != 0);
  karr[b * 512 + t] = 0xFFFF;
  if (lane == 0) wpop[wave] = __popcll(bal);
  __syncthreads();
  if (t == 0) {
    int s = 0;
    for (int ww = 0; ww < 8; ++ww) { wbase[ww] = s; s += wpop[ww]; }
    kept[b] = s;
  }
  __syncthreads();
  if (v) {
    int rank = wbase[wave] + __popcll(bal & ((1ull << lane) - 1ull));
    karr[b * 512 + rank] = (u16)t;
  }
}

// ---------------- rope cos/sin table: tab[(s*32+j)*2] = cos, +1 = sin ----------------
__global__ __launch_bounds__(256) void rope_table(float* __restrict__ tab) {
  int idx = blockIdx.x * 256 + threadIdx.x;
  if (idx >= 16000) return;
  int s = idx >> 5, j = idx & 31;
  float ang = (float)s * exp2f(-(float)j * 0.41524100f);  // 10000^(-j/32)
  float sn, cs;
  sincosf(ang, &sn, &cs);
  tab[idx * 2] = cs;
  tab[idx * 2 + 1] = sn;
}

// ---------------- weights f32 -> bf16, 4 matrices in one launch ----------------
__global__ __launch_bounds__(256) void cvt_w4(const float* __restrict__ w0,
                                              const float* __restrict__ w1,
                                              const float* __restrict__ w2,
                                              const float* __restrict__ w3,
                                              u16* __restrict__ dst) {
  const float* src = (blockIdx.y == 0) ? w0 : (blockIdx.y == 1) ? w1
                    : (blockIdx.y == 2) ? w2 : w3;
  int i = blockIdx.x * 256 + threadIdx.x;            // 262144 groups of 4
  f32x4 f = *(const f32x4*)(src + (size_t)i * 4);
  u16x4 o;
  o[0] = f2bf(f[0]); o[1] = f2bf(f[1]); o[2] = f2bf(f[2]); o[3] = f2bf(f[3]);
  *(u16x4*)(dst + (size_t)blockIdx.y * 1048576 + (size_t)i * 4) = o;
}

// ---------------- f32 -> bf16 convert (vectorized) ----------------
__global__ __launch_bounds__(256) void cvt_f32_bf16(const float* __restrict__ src,
                                                    u16* __restrict__ dst, int n4) {
  int i = blockIdx.x * 256 + threadIdx.x;
  int stride = gridDim.x * 256;
  for (; i < n4; i += stride) {
    f32x4 f = *(const f32x4*)(src + (size_t)i * 4);
    u16x4 o;
    o[0] = f2bf(f[0]); o[1] = f2bf(f[1]); o[2] = f2bf(f[2]); o[3] = f2bf(f[3]);
    *(u16x4*)(dst + (size_t)i * 4) = o;
  }
}

// ---------------- gather kept rows + cvt for K and V in one launch ----------------
__global__ __launch_bounds__(256) void gathercvt2(const float* __restrict__ srcK,
                                                  const float* __restrict__ srcV,
                                                  const u16* __restrict__ karr,
                                                  const int* __restrict__ kept,
                                                  u16* __restrict__ dstK,
                                                  u16* __restrict__ dstV) {
  const int b = blockIdx.y;
  const int r = blockIdx.x * 2 + (threadIdx.x >> 7);   // 512 rows/batch
  if (r >= kept[b]) return;
  const float* src = blockIdx.z ? srcV : srcK;
  u16* dst = blockIdx.z ? dstV : dstK;
  const int c = (threadIdx.x & 127) * 8;
  const int tok = karr[b * 512 + r];
  const float* s = src + ((size_t)b * 500 + tok) * 1024 + c;
  f32x4 f0 = *(const f32x4*)s;
  f32x4 f1 = *(const f32x4*)(s + 4);
  u16 o[8];
  o[0] = f2bf(f0[0]); o[1] = f2bf(f0[1]); o[2] = f2bf(f0[2]); o[3] = f2bf(f0[3]);
  o[4] = f2bf(f1[0]); o[5] = f2bf(f1[1]); o[6] = f2bf(f1[2]); o[7] = f2bf(f1[3]);
  *(bf16x8*)(dst + ((size_t)b * 512 + r) * 1024 + c) = *(bf16x8*)o;
}

// ---------------- GEMM: C[m][n] = sum_k A[m][k]*Bw[n][k] + bias[n] ----------------
// 256x128 tile, BK=32, 512 thr / 8 waves (4Mx2N), per-wave 64x64 (4x4 frags).
// LDS: 2 buffers x (A 16KB + B 8KB) = 48KB -> 3 blocks/CU; grid 504 (full) ~2/CU.
// Row-pair packed 128B LDS rows, XOR slot swizzle (round-10 proven, conflict-free).
// T3-minimum loop: STAGE(t+1,buf^1) -> ds_read frags -> lgkm(0) -> 16 MFMA ->
//                  vmcnt(0) -> barrier. Co-resident blocks hide the drain.
// MODE: 0 f32 out; 1 bf16 out; 2 bf16+rope+transpose (Q); 3 compact kept-rank rows.
template <int MODE>
__global__ __launch_bounds__(512, 4) void gemm_bt(const u16* __restrict__ A,
                                                  const u16* __restrict__ Bw,
                                                  const float* __restrict__ bias,
                                                  void* __restrict__ Cout, int M,
                                                  const float* __restrict__ tabg,
                                                  const int* __restrict__ keptp) {
  const int bid = blockIdx.x;
  int m0, n0, Mloc;
  size_t abase, crowbase;
  if (MODE == 3) {
    const int swz = (bid & 7) * 64 + (bid >> 3);      // bijective: 512 = 8*64
    const int mb = swz >> 3;                          // 0..63
    n0 = (swz & 7) * 128;
    const int b = mb >> 1, rb = mb & 1;
    const int kb = keptp[b];
    if (rb * 256 >= kb) return;
    m0 = rb * 256;
    Mloc = kb;
    abase = (size_t)b * 512 * 1024;
    crowbase = (size_t)b * 512;
  } else {
    const int swz = (bid & 7) * 63 + (bid >> 3);      // bijective: 504 = 8*63
    m0 = (swz >> 3) * 256;
    n0 = (swz & 7) * 128;
    Mloc = M;
    abase = 0;
    crowbase = 0;
  }
  const int tid = threadIdx.x;
  const int wave = tid >> 6;
  const int wr = wave >> 1, wc = wave & 1;            // 4M x 2N
  const int fr = tid & 15, fo = (tid >> 4) & 3;
  const int fr2 = fr >> 1;
  const int aslot = ((4 * (fr & 1) + fo) ^ fr2) * 8;  // u16 offset within 64-u16 LDS row

  const int ATILE = 128 * 64;                         // 16KB (256 m-rows packed 2/row)
  const int BTILE = 64 * 64;                          // 8KB  (128 n-rows packed 2/row)
  __shared__ __attribute__((aligned(16))) u16 AS[2 * 128 * 64];   // 32KB
  __shared__ __attribute__((aligned(16))) u16 BS[2 * 64 * 64];    // 16KB

  f32x4 acc[4][4];
#pragma unroll
  for (int mi = 0; mi < 4; ++mi)
#pragma unroll
    for (int ni = 0; ni < 4; ++ni)
#pragma unroll
      for (int j = 0; j < 4; ++j) acc[mi][ni][j] = 0.f;

  // staging: LDS chunk c (16B) -> row r=c>>3, slot s=c&7; v = s ^ (r&7);
  // source row = 2r + (v>>2), k-chunk = v&3.
  auto STG = [&](int t, int buf) {
    u16* sA = &AS[buf * ATILE];
    u16* sB = &BS[buf * BTILE];
#pragma unroll
    for (int i = 0; i < 2; ++i) {                     // A: 1024 chunks
      int c = i * 512 + tid;
      int r = c >> 3, v = (c & 7) ^ (r & 7);
      int ar = min(m0 + 2 * r + (v >> 2), Mloc - 1);
      async16(&sA[c * 8], A + abase + (size_t)ar * 1024 + t * 32 + (v & 3) * 8);
    }
    {                                                 // B: 512 chunks
      int c = tid;
      int r = c >> 3, v = (c & 7) ^ (r & 7);
      int nr = n0 + 2 * r + (v >> 2);
      async16(&sB[c * 8], Bw + (size_t)nr * 1024 + t * 32 + (v & 3) * 8);
    }
  };

  STG(0, 0);
  asm volatile("s_waitcnt vmcnt(0)" ::: "memory");
  __builtin_amdgcn_sched_barrier(0);
  __builtin_amdgcn_s_barrier();

  int cur = 0;
  for (int t = 0; t < 32; ++t) {
    if (t + 1 < 32) STG(t + 1, cur ^ 1);
    const u16* a0 = &AS[cur * ATILE];
    const u16* b0 = &BS[cur * BTILE];
    bf16x8 a[4], b[4];
#pragma unroll
    for (int mi = 0; mi < 4; ++mi)
      a[mi] = *(const bf16x8*)&a0[(wr * 32 + mi * 8 + fr2) * 64 + aslot];
#pragma unroll
    for (int ni = 0; ni < 4; ++ni)
      b[ni] = *(const bf16x8*)&b0[(wc * 32 + ni * 8 + fr2) * 64 + aslot];
    asm volatile("s_waitcnt lgkmcnt(0)" ::: "memory");
    __builtin_amdgcn_sched_barrier(0);
    __builtin_amdgcn_s_setprio(1);
#pragma unroll
    for (int mi = 0; mi < 4; ++mi)
#pragma unroll
      for (int ni = 0; ni < 4; ++ni)
        acc[mi][ni] = __builtin_amdgcn_mfma_f32_16x16x32_bf16(a[mi], b[ni], acc[mi][ni], 0, 0, 0);
    __builtin_amdgcn_s_setprio(0);
    asm volatile("s_waitcnt vmcnt(0)" ::: "memory");
    __builtin_amdgcn_sched_barrier(0);
    __builtin_amdgcn_s_barrier();
    cur ^= 1;
  }

  // ---- epilogue ----
  __syncthreads();
  if (MODE == 2) {
    // rope + transpose: wave strip = head; bounce f32, rope from tab, write [bh][s][d]
    float* fw = (float*)&AS[0] + wave * 1024;         // 4KB per wave (32KB of AS)
    const int hh = (n0 >> 6) + wc;
    const int lane = tid & 63;
    const int row = lane >> 2;
    const int jb = (lane & 3) * 8;
    float bvv[4];
#pragma unroll
    for (int ni = 0; ni < 4; ++ni) bvv[ni] = bias[n0 + wc * 64 + ni * 16 + fr];
#pragma unroll
    for (int mi = 0; mi < 4; ++mi) {
#pragma unroll
      for (int ni = 0; ni < 4; ++ni)
#pragma unroll
        for (int r = 0; r < 4; ++r)
          fw[(fo * 4 + r) * 64 + ni * 16 + fr] = acc[mi][ni][r] + bvv[ni];
      int m = m0 + wr * 64 + mi * 16 + row;
      if (m < Mloc) {
        int bb = (u32)m / 500u;
        int ss = m - bb * 500;
        u16* dst = (u16*)Cout + (((size_t)(bb * 16 + hh)) * 500 + ss) * 64;
        bf16x8 va, vb;
#pragma unroll
        for (int p = 0; p < 8; ++p) {
          int j = jb + p;
          float x0 = fw[row * 64 + j];
          float x1 = fw[row * 64 + 32 + j];
          float xe = fw[row * 64 + 2 * j];
          float xo = fw[row * 64 + 2 * j + 1];
          f32x2 cn = *(const f32x2*)(tabg + (ss * 32 + j) * 2);
          va[p] = (short)f2bf(x0 * cn[0] - xo * cn[1]);
          vb[p] = (short)f2bf(x1 * cn[0] + xe * cn[1]);
        }
        *(bf16x8*)(dst + jb) = va;
        *(bf16x8*)(dst + 32 + jb) = vb;
      }
      __builtin_amdgcn_s_barrier();
    }
  } else if (MODE == 1 || MODE == 3) {
    u16* bw = (u16*)&AS[0] + wave * 2048;             // 4KB per wave
#pragma unroll
    for (int mi = 0; mi < 4; ++mi) {
#pragma unroll
      for (int ni = 0; ni < 4; ++ni) {
        float bv = bias[n0 + wc * 64 + ni * 16 + fr];
#pragma unroll
        for (int r = 0; r < 4; ++r)
          bw[(fo * 4 + r) * 64 + ni * 16 + fr] = f2bf(acc[mi][ni][r] + bv);
      }
      int lane = tid & 63;
      int ro = lane >> 2, ch = lane & 3;
      int m = m0 + wr * 64 + mi * 16 + ro;
      bf16x8 v0 = *(const bf16x8*)&bw[ro * 64 + ch * 16];
      bf16x8 v1 = *(const bf16x8*)&bw[ro * 64 + ch * 16 + 8];
      if (m < Mloc) {
        u16* dst = (u16*)Cout + (crowbase + m) * 1024 + n0 + wc * 64 + ch * 16;
        *(bf16x8*)dst = v0;
        *(bf16x8*)(dst + 8) = v1;
      }
    }
  } else {
    float* fw = (float*)&AS[0] + wave * 1024;         // 4KB per wave
#pragma unroll
    for (int mi = 0; mi < 4; ++mi) {
#pragma unroll
      for (int ni = 0; ni < 4; ++ni) {
        float bv = bias[n0 + wc * 64 + ni * 16 + fr];
#pragma unroll
        for (int r = 0; r < 4; ++r)
          fw[(fo * 4 + r) * 64 + ni * 16 + fr] = acc[mi][ni][r] + bv;
      }
      int lane = tid & 63;
      int ro = lane >> 2, ch = lane & 3;
      int m = m0 + wr * 64 + mi * 16 + ro;
      f32x4 v0 = *(const f32x4*)&fw[ro * 64 + ch * 16];
      f32x4 v1 = *(const f32x4*)&fw[ro * 64 + ch * 16 + 4];
      f32x4 v2 = *(const f32x4*)&fw[ro * 64 + ch * 16 + 8];
      f32x4 v3 = *(const f32x4*)&fw[ro * 64 + ch * 16 + 12];
      if (m < Mloc) {
        float* dst = (float*)Cout + (size_t)m * 1024 + n0 + wc * 64 + ch * 16;
        *(f32x4*)dst = v0;
        *(f32x4*)(dst + 4) = v1;
        *(f32x4*)(dst + 8) = v2;
        *(f32x4*)(dst + 12) = v3;
      }
    }
  }
}

// ---------------- K: rope + compact-source gather -> pre-swizzled tiles [bh][tile][64][128B] ---
__global__ __launch_bounds__(256) void gather_k(const u16* __restrict__ PkC,
                                                const float* __restrict__ tab,
                                                const u16* __restrict__ karr,
                                                const int* __restrict__ kept,
                                                u16* __restrict__ Ktg) {
  const int tile = blockIdx.x;
  const int bh = blockIdx.y;
  const int h = bh & 15, b = bh >> 4;
  if (tile * 64 >= kept[b]) return;
  char* out = (char*)(Ktg + ((size_t)bh * 8 + tile) * 4096);
  const int tid = threadIdx.x;
#pragma unroll
  for (int i = 0; i < 8; ++i) {
    int item = i * 256 + tid;            // 2048 = 64 rows * 32 j
    int row = item >> 5, j = item & 31;
    int rk = tile * 64 + row;
    int tok = karr[b * 512 + rk];
    int sw = (row & 7) << 4;
    u16 o0 = 0, o1 = 0;
    if (tok != 0xFFFF) {
      const u16* src = PkC + ((size_t)b * 512 + rk) * 1024 + h * 64;   // compact rank row
      float x0 = bf2f(src[j]);
      float x1 = bf2f(src[32 + j]);
      float xe = bf2f(src[2 * j]);
      float xo = bf2f(src[2 * j + 1]);
      f32x2 cn = *(const f32x2*)(tab + (tok * 32 + j) * 2);
      o0 = f2bf(x0 * cn[0] - xo * cn[1]);
      o1 = f2bf(x1 * cn[0] + xe * cn[1]);
    }
    *(u16*)(out + row * 128 + ((2 * j) ^ sw)) = o0;
    *(u16*)(out + row * 128 + ((64 + 2 * j) ^ sw)) = o1;
  }
}

// ---------------- V: compact-source gather + transpose -> pre-swizzled V^T tiles --------------
__global__ __launch_bounds__(256) void gather_v(const u16* __restrict__ PvC,
                                                const u16* __restrict__ karr,
                                                const int* __restrict__ kept,
                                                u16* __restrict__ Vtg) {
  const int tile = blockIdx.x;
  const int bh = blockIdx.y;
  const int h = bh & 15, b = bh >> 4;
  if (tile * 64 >= kept[b]) return;
  const int tid = threadIdx.x;
  __shared__ __attribute__((aligned(16))) u16 Vl[64 * 64];
#pragma unroll
  for (int i = 0; i < 2; ++i) {
    int chunk = i * 256 + tid;           // 512: slot(64) x seg(8)
    int slot = chunk >> 3, seg = chunk & 7;
    int rk = tile * 64 + slot;
    int tok = karr[b * 512 + rk];
    bf16x8 v;
#pragma unroll
    for (int p = 0; p < 8; ++p) v[p] = 0;
    if (tok != 0xFFFF)
      v = *(const bf16x8*)(PvC + ((size_t)b * 512 + rk) * 1024 + h * 64 + seg * 8);
    *(bf16x8*)&Vl[slot * 64 + seg * 8] = v;
  }
  __syncthreads();
  u16* out = Vtg + ((size_t)bh * 8 + tile) * 4096;
#pragma unroll
  for (int i = 0; i < 2; ++i) {
    int chunk = i * 256 + tid;           // d(64) x c16(8)
    int d = chunk >> 3, c16 = chunk & 7;
    int k0 = ((c16 * 16) ^ ((d & 7) << 4)) >> 1;
    bf16x8 v;
#pragma unroll
    for (int p = 0; p < 8; ++p) v[p] = (short)Vl[(k0 + p) * 64 + d];
    *(bf16x8*)(out + chunk * 8) = v;
  }
}

// ---------------- flash attention: compressed k, swapped QK^T, in-reg softmax ----------------
__global__ __launch_bounds__(512) void attn_kernel(const u16* __restrict__ Qr,
                                                   const u16* __restrict__ Ktg,
                                                   const u16* __restrict__ Vtg,
                                                   const float* __restrict__ rel_emb,
                                                   const u16* __restrict__ karr,
                                                   const int* __restrict__ kept,
                                                   u16* __restrict__ AO) {
  const int bid = blockIdx.x;
  const int bh = ((bid >> 5) << 3) | (bid & 7);
  const int qb = (bid >> 3) & 3;
  const int h = bh & 15, b = bh >> 4;
  const int q0 = qb * 128;
  const int tid = threadIdx.x;
  const int wave = tid >> 6;
  const int fr = tid & 15, fo = (tid >> 4) & 3;

  __shared__ __attribute__((aligned(16))) u16 Ks[2][4096];
  __shared__ __attribute__((aligned(16))) u16 Vs[2][4096];
  __shared__ __attribute__((aligned(16))) u16 Pl[8][1024];
  __shared__ float rel2[640];
  __shared__ u16 okk[512];

  const int nt = (kept[b] + 63) >> 6;
  const float LOG2E = 1.44269504f;
  for (int i = tid; i < 640; i += 512) {
    int g = min(max(q0 - 12 + i, 0), 998);
    rel2[i] = (i == 0) ? -1e30f : rel_emb[g * 16 + h] * LOG2E;   // rel2[0] = pad sentinel
  }
  okk[tid] = karr[b * 512 + tid];

  const int qloc = wave * 16 + fr;
  const int qc = qloc + 511;             // pad slot (ok=0xFFFF) -> idx<0 -> clamp 0 -> -1e30
  const u16* Qb = Qr + ((size_t)bh * 500 + min(q0 + qloc, 499)) * 64;
  bf16x8 qf0 = *(const bf16x8*)(Qb + fo * 8);
  bf16x8 qf1 = *(const bf16x8*)(Qb + 32 + fo * 8);

  f32x4 o[4];
#pragma unroll
  for (int nf = 0; nf < 4; ++nf)
#pragma unroll
    for (int j = 0; j < 4; ++j) o[nf][j] = 0.f;
  float mrun = -1e30f, lrun = 0.f;

  const u16* Kb = Ktg + (size_t)bh * 32768;
  const u16* Vb = Vtg + (size_t)bh * 32768;
  const int sw = (fr & 7) << 4;
  const float SC = 0.18033688f;          // 0.125 * log2(e)

  if (nt > 0) {
    async16(&Ks[0][tid * 8], Kb + tid * 8);
    async16(&Vs[0][tid * 8], Vb + tid * 8);
  }
  __syncthreads();

  for (int t = 0; t < nt; ++t) {
    const int cur = t & 1;
    if (t + 1 < nt) {
      async16(&Ks[cur ^ 1][tid * 8], Kb + (t + 1) * 4096 + tid * 8);
      async16(&Vs[cur ^ 1][tid * 8], Vb + (t + 1) * 4096 + tid * 8);
    }
    const char* Kt = (const char*)(cur ? &Ks[1][0] : &Ks[0][0]);
    const char* Vt = (const char*)(cur ? &Vs[1][0] : &Vs[0][0]);

    f32x4 sacc[4];
    __builtin_amdgcn_s_setprio(1);
#pragma unroll
    for (int nf = 0; nf < 4; ++nf) {
#pragma unroll
      for (int jj = 0; jj < 4; ++jj) sacc[nf][jj] = 0.f;
      int rb = (nf * 16 + fr) * 128;
      bf16x8 kb0 = *(const bf16x8*)(Kt + rb + ((fo * 16) ^ sw));
      bf16x8 kb1 = *(const bf16x8*)(Kt + rb + ((64 + fo * 16) ^ sw));
      sacc[nf] = __builtin_amdgcn_mfma_f32_16x16x32_bf16(kb0, qf0, sacc[nf], 0, 0, 0);
      sacc[nf] = __builtin_amdgcn_mfma_f32_16x16x32_bf16(kb1, qf1, sacc[nf], 0, 0, 0);
    }
    __builtin_amdgcn_s_setprio(0);

    float p2[4][4];
    float pmax = -3e30f;
#pragma unroll
    for (int nf = 0; nf < 4; ++nf) {
      u16x4 ok4 = *(const u16x4*)&okk[t * 64 + nf * 16 + fo * 4];
#pragma unroll
      for (int r = 0; r < 4; ++r) {
        int idx2 = max(qc - (int)ok4[r], 0);
        float s2 = fmaf(sacc[nf][r], SC, rel2[idx2]);
        p2[nf][r] = s2;
        pmax = fmaxf(pmax, s2);
      }
    }
    pmax = fmaxf(pmax, __shfl_xor(pmax, 16, 64));
    pmax = fmaxf(pmax, __shfl_xor(pmax, 32, 64));

    if (!__all(pmax <= mrun + 8.0f)) {   // defer-max (T13)
      float mnew = fmaxf(mrun, pmax);
      float scl = EXP2(mrun - mnew);
      lrun *= scl;
#pragma unroll
      for (int nf = 0; nf < 4; ++nf)
#pragma unroll
        for (int r = 0; r < 4; ++r) o[nf][r] *= scl;
      mrun = mnew;
    }

    float lsum = 0.f;
#pragma unroll
    for (int nf = 0; nf < 4; ++nf) {
      float e0 = EXP2(p2[nf][0] - mrun);
      float e1 = EXP2(p2[nf][1] - mrun);
      float e2 = EXP2(p2[nf][2] - mrun);
      float e3 = EXP2(p2[nf][3] - mrun);
      lsum += (e0 + e1) + (e2 + e3);
      uint2 w; w.x = cvtpk(e0, e1); w.y = cvtpk(e2, e3);
      *(uint2*)((char*)&Pl[wave][0] + fr * 128 + ((nf * 32 + fo * 8) ^ sw)) = w;
    }
    lsum += __shfl_xor(lsum, 16, 64);
    lsum += __shfl_xor(lsum, 32, 64);
    lrun += lsum;

    bf16x8 pa0 = *(const bf16x8*)((char*)&Pl[wave][0] + fr * 128 + ((fo * 16) ^ sw));
    bf16x8 pa1 = *(const bf16x8*)((char*)&Pl[wave][0] + fr * 128 + ((64 + fo * 16) ^ sw));
    __builtin_amdgcn_s_setprio(1);
#pragma unroll
    for (int nf = 0; nf < 4; ++nf) {
      int rb = (nf * 16 + fr) * 128;
      bf16x8 vb0 = *(const bf16x8*)(Vt + rb + ((fo * 16) ^ sw));
      bf16x8 vb1 = *(const bf16x8*)(Vt + rb + ((64 + fo * 16) ^ sw));
      o[nf] = __builtin_amdgcn_mfma_f32_16x16x32_bf16(vb0, pa0, o[nf], 0, 0, 0);
      o[nf] = __builtin_amdgcn_mfma_f32_16x16x32_bf16(vb1, pa1, o[nf], 0, 0, 0);
    }
    __builtin_amdgcn_s_setprio(0);
    __syncthreads();
  }

  float inv = (lrun > 0.f) ? 1.f / lrun : 0.f;
#pragma unroll
  for (int nf = 0; nf < 4; ++nf) {
    float v0 = fminf(fmaxf(o[nf][0] * inv, -30.f), 30.f);
    float v1 = fminf(fmaxf(o[nf][1] * inv, -30.f), 30.f);
    float v2 = fminf(fmaxf(o[nf][2] * inv, -30.f), 30.f);
    float v3 = fminf(fmaxf(o[nf][3] * inv, -30.f), 30.f);
    uint2 w; w.x = cvtpk(v0, v1); w.y = cvtpk(v2, v3);
    *(uint2*)((char*)&Pl[wave][0] + fr * 128 + ((nf * 32 + fo * 8) ^ sw)) = w;
  }
  {
    int lane = tid & 63;
    int ro = lane >> 2, c = lane & 3;
    int swr = (ro & 7) << 4;
    const char* Pw = (const char*)&Pl[wave][0];
    bf16x8 v0 = *(const bf16x8*)(Pw + ro * 128 + ((c * 32) ^ swr));
    bf16x8 v1 = *(const bf16x8*)(Pw + ro * 128 + ((c * 32 + 16) ^ swr));
    int token = q0 + wave * 16 + ro;
    if (token < 500) {
      u16* dst = AO + (size_t)(b * 500 + token) * 1024 + h * 64 + c * 16;
      *(bf16x8*)dst = v0;
      *(bf16x8*)(dst + 8) = v1;
    }
  }
}

// ---------------- launch ----------------
extern "C" void kernel_launch(void* const* d_in, const int* in_sizes, int n_in,
                              void* d_out, int out_size, void* d_ws, size_t ws_size,
                              hipStream_t stream) {
  const float* query = (const float*)d_in[0];
  const float* key_  = (const float*)d_in[1];
  const float* value = (const float*)d_in[2];
  const void*  mask  = d_in[3];
  const float* Wq = (const float*)d_in[4];
  const float* bq = (const float*)d_in[5];
  const float* Wk = (const float*)d_in[6];
  const float* bk = (const float*)d_in[7];
  const float* Wv = (const float*)d_in[8];
  const float* bv = (const float*)d_in[9];
  const float* Wo = (const float*)d_in[10];
  const float* bo = (const float*)d_in[11];
  const float* rel = (const float*)d_in[12];

  // ws map: Wb 8.39MB | 4 slots x 32MiB | misc ~0.26MB
  // slot liveness: A: Xq(full)->PkC->Vtg | B: XkC->Ktg | C: XvC->Qro | D: PvC->AO
  char* ws = (char*)d_ws;
  const size_t SLOT = 33554432;
  u16* Wb = (u16*)ws;
  char* Aq = ws + 8388608;
  char* Bq = Aq + SLOT;
  char* Cq = Bq + SLOT;
  char* Dq = Cq + SLOT;
  char* MISC = Dq + SLOT;
  u16* karr  = (u16*)(MISC + 65536);
  int* kept  = (int*)(MISC + 131072);
  float* tab = (float*)(MISC + 131584);

  build_gather<<<32, 512, 0, stream>>>(mask, karr, kept);
  rope_table<<<63, 256, 0, stream>>>(tab);
  cvt_w4<<<dim3(1024, 4), 256, 0, stream>>>(Wq, Wk, Wv, Wo, Wb);
  cvt_f32_bf16<<<2048, 256, 0, stream>>>(query, (u16*)Aq, 4096000);                 // Xq full
  gathercvt2<<<dim3(256, 32, 2), 256, 0, stream>>>(key_, value, karr, kept,
                                                   (u16*)Bq, (u16*)Cq);             // XkC, XvC

  gemm_bt<3><<<512, 512, 0, stream>>>((u16*)Cq, Wb + 2 * 1048576, bv, Dq, 0, tab, kept);   // PvC=D
  gemm_bt<2><<<504, 512, 0, stream>>>((u16*)Aq, Wb + 0 * 1048576, bq, Cq, 16000, tab, nullptr); // Qro=C
  gemm_bt<3><<<512, 512, 0, stream>>>((u16*)Bq, Wb + 1 * 1048576, bk, Aq, 0, tab, kept);   // PkC=A

  gather_k<<<dim3(8, 512), 256, 0, stream>>>((u16*)Aq, tab, karr, kept, (u16*)Bq);  // Ktg=B
  gather_v<<<dim3(8, 512), 256, 0, stream>>>((u16*)Dq, karr, kept, (u16*)Aq);       // Vtg=A

  attn_kernel<<<2048, 512, 0, stream>>>((u16*)Cq, (u16*)Bq, (u16*)Aq, rel,
                                        karr, kept, (u16*)Dq);                  // AO=D

  gemm_bt<0><<<504, 512, 0, stream>>>((u16*)Dq, Wb + 3 * 1048576, bo, (float*)d_out, 16000, tab, nullptr);
}

// Round 15
// 280.030 us; speedup vs baseline: 1.3391x; 1.0427x over previous
//
#include <hip/hip_runtime.h>
#include <math.h>

// FlashMultiHeadAttention: B=32 S=500 H=1024 NH=16 HD=64, rope + rel-pos-bias + key-pad mask.
// Pipeline: [gather-list scan w/ inline mask-mode detect] [rope table] [cvt W x4 fused]
//           [cvt Q] [gather+cvt K/V kept rows fused]
//           [FUSED proj GEMM: Q(full, rope+transpose) + K(compact) + V(compact) in ONE launch]
//           [rope+gather+swizzle K tiles] [gather+transpose+swizzle V tiles]
//           [flash attn] [out proj GEMM]
// GEMM core (round-14 proven): 256x128 tile, BK=32, 2 LDS buffers (48KB -> 3 blocks/CU),
// row-pair packed 128B LDS rows + XOR slot swizzle, T3-minimum single-barrier loop.
// Fusing the 3 independent projections gives ~1270 active blocks -> 3/CU co-residency
// so each block's vmcnt drain hides under the others' compute (m114 TLP).

typedef unsigned short u16;
typedef unsigned int   u32;
typedef unsigned char  u8;
using bf16x8 = __attribute__((ext_vector_type(8))) short;
using f32x4  = __attribute__((ext_vector_type(4))) float;
using f32x2  = __attribute__((ext_vector_type(2))) float;
using u16x4  = __attribute__((ext_vector_type(4))) unsigned short;

#define DEV __device__ __forceinline__

#if __has_builtin(__builtin_amdgcn_exp2f)
#define EXP2(x) __builtin_amdgcn_exp2f(x)
#else
#define EXP2(x) exp2f(x)
#endif

DEV u16 f2bf(float f) {                 // RNE f32 -> bf16
  union { float f; u32 u; } c; c.f = f;
  u32 u = c.u;
  return (u16)((u + 0x7FFFu + ((u >> 16) & 1u)) >> 16);
}
DEV float bf2f(u16 h) {
  union { u32 u; float f; } c; c.u = ((u32)h) << 16;
  return c.f;
}
DEV u32 cvtpk(float a, float b) {       // packed pair via HW cvt (T12)
  u32 r;
  asm("v_cvt_pk_bf16_f32 %0, %1, %2" : "=v"(r) : "v"(a), "v"(b));
  return r;
}

// async global->LDS, 16B/lane; LDS dest = wave-uniform base + lane*16 (linear).
DEV void async16(void* l, const void* g) {
  __builtin_amdgcn_global_load_lds(
      (__attribute__((address_space(1))) unsigned int*)g,
      (__attribute__((address_space(3))) unsigned int*)l, 16, 0, 0);
}

// ---------------- gather list + inline mask-mode detection ----------------
__global__ __launch_bounds__(512) void build_gather(const void* __restrict__ mraw,
                                                    u16* __restrict__ karr,
                                                    int* __restrict__ kept) {
  const int b = blockIdx.x;
  const int t = threadIdx.x;
  const int lane = t & 63, wave = t >> 6;
  __shared__ int s_li, s_lf;
  __shared__ int wbase[8];
  __shared__ int wpop[8];
  if (t == 0) { s_li = 0; s_lf = 0; }
  __syncthreads();
  const u32* w = (const u32*)mraw;
  int li = 0, lf = 0;
  for (int g = t; g < 4000; g += 512) {      // same 4000 words in every block -> same mode
    u32 v = w[g];
    li |= !(v == 0u || v == 1u);
    lf |= !(v == 0u || v == 0x3F800000u);
  }
  if (li) atomicOr(&s_li, 1);
  if (lf) atomicOr(&s_lf, 1);
  __syncthreads();
  const int mode = (!s_li) ? 0 : ((!s_lf) ? 1 : 2);   // 0=int32, 1=float32, 2=uint8
  int v = 0;
  if (t < 500) {
    if (mode == 0)      v = ((const int*)mraw)[b * 500 + t] != 0;
    else if (mode == 1) v = (((const float*)mraw)[b * 500 + t] != 0.0f);
    else                v = ((const u8*)mraw)[b * 500 + t] != 0;
  }
  unsigned long long bal = __ballot(v != 0);
  karr[b * 512 + t] = 0xFFFF;
  if (lane == 0) wpop[wave] = __popcll(bal);
  __syncthreads();
  if (t == 0) {
    int s = 0;
    for (int ww = 0; ww < 8; ++ww) { wbase[ww] = s; s += wpop[ww]; }
    kept[b] = s;
  }
  __syncthreads();
  if (v) {
    int rank = wbase[wave] + __popcll(bal & ((1ull << lane) - 1ull));
    karr[b * 512 + rank] = (u16)t;
  }
}

// ---------------- rope cos/sin table: tab[(s*32+j)*2] = cos, +1 = sin ----------------
__global__ __launch_bounds__(256) void rope_table(float* __restrict__ tab) {
  int idx = blockIdx.x * 256 + threadIdx.x;
  if (idx >= 16000) return;
  int s = idx >> 5, j = idx & 31;
  float ang = (float)s * exp2f(-(float)j * 0.41524100f);  // 10000^(-j/32)
  float sn, cs;
  sincosf(ang, &sn, &cs);
  tab[idx * 2] = cs;
  tab[idx * 2 + 1] = sn;
}

// ---------------- weights f32 -> bf16, 4 matrices in one launch ----------------
__global__ __launch_bounds__(256) void cvt_w4(const float* __restrict__ w0,
                                              const float* __restrict__ w1,
                                              const float* __restrict__ w2,
                                              const float* __restrict__ w3,
                                              u16* __restrict__ dst) {
  const float* src = (blockIdx.y == 0) ? w0 : (blockIdx.y == 1) ? w1
                    : (blockIdx.y == 2) ? w2 : w3;
  int i = blockIdx.x * 256 + threadIdx.x;            // 262144 groups of 4
  f32x4 f = *(const f32x4*)(src + (size_t)i * 4);
  u16x4 o;
  o[0] = f2bf(f[0]); o[1] = f2bf(f[1]); o[2] = f2bf(f[2]); o[3] = f2bf(f[3]);
  *(u16x4*)(dst + (size_t)blockIdx.y * 1048576 + (size_t)i * 4) = o;
}

// ---------------- f32 -> bf16 convert (vectorized) ----------------
__global__ __launch_bounds__(256) void cvt_f32_bf16(const float* __restrict__ src,
                                                    u16* __restrict__ dst, int n4) {
  int i = blockIdx.x * 256 + threadIdx.x;
  int stride = gridDim.x * 256;
  for (; i < n4; i += stride) {
    f32x4 f = *(const f32x4*)(src + (size_t)i * 4);
    u16x4 o;
    o[0] = f2bf(f[0]); o[1] = f2bf(f[1]); o[2] = f2bf(f[2]); o[3] = f2bf(f[3]);
    *(u16x4*)(dst + (size_t)i * 4) = o;
  }
}

// ---------------- gather kept rows + cvt for K and V in one launch ----------------
__global__ __launch_bounds__(256) void gathercvt2(const float* __restrict__ srcK,
                                                  const float* __restrict__ srcV,
                                                  const u16* __restrict__ karr,
                                                  const int* __restrict__ kept,
                                                  u16* __restrict__ dstK,
                                                  u16* __restrict__ dstV) {
  const int b = blockIdx.y;
  const int r = blockIdx.x * 2 + (threadIdx.x >> 7);   // 512 rows/batch
  if (r >= kept[b]) return;
  const float* src = blockIdx.z ? srcV : srcK;
  u16* dst = blockIdx.z ? dstV : dstK;
  const int c = (threadIdx.x & 127) * 8;
  const int tok = karr[b * 512 + r];
  const float* s = src + ((size_t)b * 500 + tok) * 1024 + c;
  f32x4 f0 = *(const f32x4*)s;
  f32x4 f1 = *(const f32x4*)(s + 4);
  u16 o[8];
  o[0] = f2bf(f0[0]); o[1] = f2bf(f0[1]); o[2] = f2bf(f0[2]); o[3] = f2bf(f0[3]);
  o[4] = f2bf(f1[0]); o[5] = f2bf(f1[1]); o[6] = f2bf(f1[2]); o[7] = f2bf(f1[3]);
  *(bf16x8*)(dst + ((size_t)b * 512 + r) * 1024 + c) = *(bf16x8*)o;
}

// ---------------- shared GEMM core (round-14 proven) ----------------
// 256x128 tile, BK=32, 512 thr / 8 waves (4Mx2N), per-wave 64x64 (4x4 frags).
// 2 LDS buffers (A 16KB + B 8KB each). Row-pair packed 128B rows, XOR slot swizzle.
// T3-minimum loop: STAGE(t+1,buf^1) -> ds_read -> lgkm(0) -> 16 MFMA -> vmcnt(0) -> barrier.
DEV void gemm_core(const u16* __restrict__ A, size_t abase,
                   const u16* __restrict__ W,
                   int m0, int n0, int Mloc,
                   u16* AS, u16* BS, f32x4 (&acc)[4][4], int tid) {
  const int wave = tid >> 6;
  const int wr = wave >> 1, wc = wave & 1;            // 4M x 2N
  const int fr = tid & 15, fo = (tid >> 4) & 3;
  const int fr2 = fr >> 1;
  const int aslot = ((4 * (fr & 1) + fo) ^ fr2) * 8;  // u16 offset within 64-u16 LDS row
  const int ATILE = 128 * 64;                         // 16KB
  const int BTILE = 64 * 64;                          // 8KB

#pragma unroll
  for (int mi = 0; mi < 4; ++mi)
#pragma unroll
    for (int ni = 0; ni < 4; ++ni)
#pragma unroll
      for (int j = 0; j < 4; ++j) acc[mi][ni][j] = 0.f;

  auto STG = [&](int t, int buf) {
    u16* sA = &AS[buf * ATILE];
    u16* sB = &BS[buf * BTILE];
#pragma unroll
    for (int i = 0; i < 2; ++i) {                     // A: 1024 chunks
      int c = i * 512 + tid;
      int r = c >> 3, v = (c & 7) ^ (r & 7);
      int ar = min(m0 + 2 * r + (v >> 2), Mloc - 1);
      async16(&sA[c * 8], A + abase + (size_t)ar * 1024 + t * 32 + (v & 3) * 8);
    }
    {                                                 // B: 512 chunks
      int c = tid;
      int r = c >> 3, v = (c & 7) ^ (r & 7);
      int nr = n0 + 2 * r + (v >> 2);
      async16(&sB[c * 8], W + (size_t)nr * 1024 + t * 32 + (v & 3) * 8);
    }
  };

  STG(0, 0);
  asm volatile("s_waitcnt vmcnt(0)" ::: "memory");
  __builtin_amdgcn_sched_barrier(0);
  __builtin_amdgcn_s_barrier();

  int cur = 0;
  for (int t = 0; t < 32; ++t) {
    if (t + 1 < 32) STG(t + 1, cur ^ 1);
    const u16* a0 = &AS[cur * ATILE];
    const u16* b0 = &BS[cur * BTILE];
    bf16x8 a[4], b[4];
#pragma unroll
    for (int mi = 0; mi < 4; ++mi)
      a[mi] = *(const bf16x8*)&a0[(wr * 32 + mi * 8 + fr2) * 64 + aslot];
#pragma unroll
    for (int ni = 0; ni < 4; ++ni)
      b[ni] = *(const bf16x8*)&b0[(wc * 32 + ni * 8 + fr2) * 64 + aslot];
    asm volatile("s_waitcnt lgkmcnt(0)" ::: "memory");
    __builtin_amdgcn_sched_barrier(0);
    __builtin_amdgcn_s_setprio(1);
#pragma unroll
    for (int mi = 0; mi < 4; ++mi)
#pragma unroll
      for (int ni = 0; ni < 4; ++ni)
        acc[mi][ni] = __builtin_amdgcn_mfma_f32_16x16x32_bf16(a[mi], b[ni], acc[mi][ni], 0, 0, 0);
    __builtin_amdgcn_s_setprio(0);
    asm volatile("s_waitcnt vmcnt(0)" ::: "memory");
    __builtin_amdgcn_sched_barrier(0);
    __builtin_amdgcn_s_barrier();
    cur ^= 1;
  }
  __syncthreads();
}

// ---------------- FUSED projection GEMM: Q(full+rope+tr) + K(compact) + V(compact) ------------
// grid 1528 = 504 (Q) + 512 (K) + 512 (V); bases are multiples of 8 so per-path
// XCD swizzle stays aligned with the dispatcher's bid%8 round-robin.
__global__ __launch_bounds__(512, 4) void gemm_fused(
    const u16* __restrict__ Xq, const u16* __restrict__ XkC, const u16* __restrict__ XvC,
    const u16* __restrict__ Wb,
    const float* __restrict__ bq, const float* __restrict__ bk, const float* __restrict__ bv,
    u16* __restrict__ Qro, u16* __restrict__ PkC, u16* __restrict__ PvC,
    const float* __restrict__ tabg, const int* __restrict__ keptp) {
  __shared__ __attribute__((aligned(16))) u16 AS[2 * 128 * 64];   // 32KB
  __shared__ __attribute__((aligned(16))) u16 BS[2 * 64 * 64];    // 16KB
  const int bid = blockIdx.x;
  const int tid = threadIdx.x;
  const int wave = tid >> 6;
  const int wr = wave >> 1, wc = wave & 1;
  const int fr = tid & 15, fo = (tid >> 4) & 3;

  f32x4 acc[4][4];

  if (bid < 504) {
    // ---- Q path: full M=16000, rope+transpose epilogue -> Qro [bh][s][64] ----
    const int swz = (bid & 7) * 63 + (bid >> 3);
    const int m0 = (swz >> 3) * 256;
    const int n0 = (swz & 7) * 128;
    gemm_core(Xq, 0, Wb, m0, n0, 16000, AS, BS, acc, tid);

    float* fw = (float*)&AS[0] + wave * 1024;         // 4KB per wave
    const int hh = (n0 >> 6) + wc;
    const int lane = tid & 63;
    const int row = lane >> 2;
    const int jb = (lane & 3) * 8;
    float bvv[4];
#pragma unroll
    for (int ni = 0; ni < 4; ++ni) bvv[ni] = bq[n0 + wc * 64 + ni * 16 + fr];
#pragma unroll
    for (int mi = 0; mi < 4; ++mi) {
#pragma unroll
      for (int ni = 0; ni < 4; ++ni)
#pragma unroll
        for (int r = 0; r < 4; ++r)
          fw[(fo * 4 + r) * 64 + ni * 16 + fr] = acc[mi][ni][r] + bvv[ni];
      int m = m0 + wr * 64 + mi * 16 + row;
      if (m < 16000) {
        int bb = (u32)m / 500u;
        int ss = m - bb * 500;
        u16* dst = Qro + (((size_t)(bb * 16 + hh)) * 500 + ss) * 64;
        bf16x8 va, vb;
#pragma unroll
        for (int p = 0; p < 8; ++p) {
          int j = jb + p;
          float x0 = fw[row * 64 + j];
          float x1 = fw[row * 64 + 32 + j];
          float xe = fw[row * 64 + 2 * j];
          float xo = fw[row * 64 + 2 * j + 1];
          f32x2 cn = *(const f32x2*)(tabg + (ss * 32 + j) * 2);
          va[p] = (short)f2bf(x0 * cn[0] - xo * cn[1]);
          vb[p] = (short)f2bf(x1 * cn[0] + xe * cn[1]);
        }
        *(bf16x8*)(dst + jb) = va;
        *(bf16x8*)(dst + 32 + jb) = vb;
      }
      __builtin_amdgcn_s_barrier();
    }
  } else {
    // ---- K/V compact paths: kept-rank rows, bf16 compact epilogue ----
    const bool isV = (bid >= 1016);
    const int local = isV ? (bid - 1016) : (bid - 504);
    const u16* A = isV ? XvC : XkC;
    const u16* W = Wb + (isV ? 2 : 1) * 1048576;
    const float* bias = isV ? bv : bk;
    u16* Cout = isV ? PvC : PkC;
    const int swz = (local & 7) * 64 + (local >> 3);  // bijective: 512 = 8*64
    const int mb = swz >> 3;
    const int n0 = (swz & 7) * 128;
    const int b = mb >> 1, rb = mb & 1;
    const int kb = keptp[b];
    if (rb * 256 >= kb) return;
    const int m0 = rb * 256;
    gemm_core(A, (size_t)b * 512 * 1024, W, m0, n0, kb, AS, BS, acc, tid);

    u16* bw = (u16*)&AS[0] + wave * 2048;             // 4KB per wave
#pragma unroll
    for (int mi = 0; mi < 4; ++mi) {
#pragma unroll
      for (int ni = 0; ni < 4; ++ni) {
        float bvs = bias[n0 + wc * 64 + ni * 16 + fr];
#pragma unroll
        for (int r = 0; r < 4; ++r)
          bw[(fo * 4 + r) * 64 + ni * 16 + fr] = f2bf(acc[mi][ni][r] + bvs);
      }
      int lane = tid & 63;
      int ro = lane >> 2, ch = lane & 3;
      int m = m0 + wr * 64 + mi * 16 + ro;
      bf16x8 v0 = *(const bf16x8*)&bw[ro * 64 + ch * 16];
      bf16x8 v1 = *(const bf16x8*)&bw[ro * 64 + ch * 16 + 8];
      if (m < kb) {
        u16* dst = Cout + ((size_t)b * 512 + m) * 1024 + n0 + wc * 64 + ch * 16;
        *(bf16x8*)dst = v0;
        *(bf16x8*)(dst + 8) = v1;
      }
    }
  }
}

// ---------------- out-projection GEMM: full, f32 out ----------------
__global__ __launch_bounds__(512, 4) void gemm_out(const u16* __restrict__ A,
                                                   const u16* __restrict__ W,
                                                   const float* __restrict__ bias,
                                                   float* __restrict__ Cout) {
  __shared__ __attribute__((aligned(16))) u16 AS[2 * 128 * 64];
  __shared__ __attribute__((aligned(16))) u16 BS[2 * 64 * 64];
  const int bid = blockIdx.x;
  const int tid = threadIdx.x;
  const int wave = tid >> 6;
  const int wr = wave >> 1, wc = wave & 1;
  const int fr = tid & 15, fo = (tid >> 4) & 3;
  const int swz = (bid & 7) * 63 + (bid >> 3);
  const int m0 = (swz >> 3) * 256;
  const int n0 = (swz & 7) * 128;

  f32x4 acc[4][4];
  gemm_core(A, 0, W, m0, n0, 16000, AS, BS, acc, tid);

  float* fw = (float*)&AS[0] + wave * 1024;           // 4KB per wave
#pragma unroll
  for (int mi = 0; mi < 4; ++mi) {
#pragma unroll
    for (int ni = 0; ni < 4; ++ni) {
      float bv = bias[n0 + wc * 64 + ni * 16 + fr];
#pragma unroll
      for (int r = 0; r < 4; ++r)
        fw[(fo * 4 + r) * 64 + ni * 16 + fr] = acc[mi][ni][r] + bv;
    }
    int lane = tid & 63;
    int ro = lane >> 2, ch = lane & 3;
    int m = m0 + wr * 64 + mi * 16 + ro;
    f32x4 v0 = *(const f32x4*)&fw[ro * 64 + ch * 16];
    f32x4 v1 = *(const f32x4*)&fw[ro * 64 + ch * 16 + 4];
    f32x4 v2 = *(const f32x4*)&fw[ro * 64 + ch * 16 + 8];
    f32x4 v3 = *(const f32x4*)&fw[ro * 64 + ch * 16 + 12];
    if (m < 16000) {
      float* dst = Cout + (size_t)m * 1024 + n0 + wc * 64 + ch * 16;
      *(f32x4*)dst = v0;
      *(f32x4*)(dst + 4) = v1;
      *(f32x4*)(dst + 8) = v2;
      *(f32x4*)(dst + 12) = v3;
    }
  }
}

// ---------------- K: rope + compact-source gather -> pre-swizzled tiles [bh][tile][64][128B] ---
__global__ __launch_bounds__(256) void gather_k(const u16* __restrict__ PkC,
                                                const float* __restrict__ tab,
                                                const u16* __restrict__ karr,
                                                const int* __restrict__ kept,
                                                u16* __restrict__ Ktg) {
  const int tile = blockIdx.x;
  const int bh = blockIdx.y;
  const int h = bh & 15, b = bh >> 4;
  if (tile * 64 >= kept[b]) return;
  char* out = (char*)(Ktg + ((size_t)bh * 8 + tile) * 4096);
  const int tid = threadIdx.x;
#pragma unroll
  for (int i = 0; i < 8; ++i) {
    int item = i * 256 + tid;            // 2048 = 64 rows * 32 j
    int row = item >> 5, j = item & 31;
    int rk = tile * 64 + row;
    int tok = karr[b * 512 + rk];
    int sw = (row & 7) << 4;
    u16 o0 = 0, o1 = 0;
    if (tok != 0xFFFF) {
      const u16* src = PkC + ((size_t)b * 512 + rk) * 1024 + h * 64;   // compact rank row
      float x0 = bf2f(src[j]);
      float x1 = bf2f(src[32 + j]);
      float xe = bf2f(src[2 * j]);
      float xo = bf2f(src[2 * j + 1]);
      f32x2 cn = *(const f32x2*)(tab + (tok * 32 + j) * 2);
      o0 = f2bf(x0 * cn[0] - xo * cn[1]);
      o1 = f2bf(x1 * cn[0] + xe * cn[1]);
    }
    *(u16*)(out + row * 128 + ((2 * j) ^ sw)) = o0;
    *(u16*)(out + row * 128 + ((64 + 2 * j) ^ sw)) = o1;
  }
}

// ---------------- V: compact-source gather + transpose -> pre-swizzled V^T tiles --------------
__global__ __launch_bounds__(256) void gather_v(const u16* __restrict__ PvC,
                                                const u16* __restrict__ karr,
                                                const int* __restrict__ kept,
                                                u16* __restrict__ Vtg) {
  const int tile = blockIdx.x;
  const int bh = blockIdx.y;
  const int h = bh & 15, b = bh >> 4;
  if (tile * 64 >= kept[b]) return;
  const int tid = threadIdx.x;
  __shared__ __attribute__((aligned(16))) u16 Vl[64 * 64];
#pragma unroll
  for (int i = 0; i < 2; ++i) {
    int chunk = i * 256 + tid;           // 512: slot(64) x seg(8)
    int slot = chunk >> 3, seg = chunk & 7;
    int rk = tile * 64 + slot;
    int tok = karr[b * 512 + rk];
    bf16x8 v;
#pragma unroll
    for (int p = 0; p < 8; ++p) v[p] = 0;
    if (tok != 0xFFFF)
      v = *(const bf16x8*)(PvC + ((size_t)b * 512 + rk) * 1024 + h * 64 + seg * 8);
    *(bf16x8*)&Vl[slot * 64 + seg * 8] = v;
  }
  __syncthreads();
  u16* out = Vtg + ((size_t)bh * 8 + tile) * 4096;
#pragma unroll
  for (int i = 0; i < 2; ++i) {
    int chunk = i * 256 + tid;           // d(64) x c16(8)
    int d = chunk >> 3, c16 = chunk & 7;
    int k0 = ((c16 * 16) ^ ((d & 7) << 4)) >> 1;
    bf16x8 v;
#pragma unroll
    for (int p = 0; p < 8; ++p) v[p] = (short)Vl[(k0 + p) * 64 + d];
    *(bf16x8*)(out + chunk * 8) = v;
  }
}

// ---------------- flash attention: compressed k, swapped QK^T, in-reg softmax ----------------
__global__ __launch_bounds__(512) void attn_kernel(const u16* __restrict__ Qr,
                                                   const u16* __restrict__ Ktg,
                                                   const u16* __restrict__ Vtg,
                                                   const float* __restrict__ rel_emb,
                                                   const u16* __restrict__ karr,
                                                   const int* __restrict__ kept,
                                                   u16* __restrict__ AO) {
  const int bid = blockIdx.x;
  const int bh = ((bid >> 5) << 3) | (bid & 7);
  const int qb = (bid >> 3) & 3;
  const int h = bh & 15, b = bh >> 4;
  const int q0 = qb * 128;
  const int tid = threadIdx.x;
  const int wave = tid >> 6;
  const int fr = tid & 15, fo = (tid >> 4) & 3;

  __shared__ __attribute__((aligned(16))) u16 Ks[2][4096];
  __shared__ __attribute__((aligned(16))) u16 Vs[2][4096];
  __shared__ __attribute__((aligned(16))) u16 Pl[8][1024];
  __shared__ float rel2[640];
  __shared__ u16 okk[512];

  const int nt = (kept[b] + 63) >> 6;
  const float LOG2E = 1.44269504f;
  for (int i = tid; i < 640; i += 512) {
    int g = min(max(q0 - 12 + i, 0), 998);
    rel2[i] = (i == 0) ? -1e30f : rel_emb[g * 16 + h] * LOG2E;   // rel2[0] = pad sentinel
  }
  okk[tid] = karr[b * 512 + tid];

  const int qloc = wave * 16 + fr;
  const int qc = qloc + 511;             // pad slot (ok=0xFFFF) -> idx<0 -> clamp 0 -> -1e30
  const u16* Qb = Qr + ((size_t)bh * 500 + min(q0 + qloc, 499)) * 64;
  bf16x8 qf0 = *(const bf16x8*)(Qb + fo * 8);
  bf16x8 qf1 = *(const bf16x8*)(Qb + 32 + fo * 8);

  f32x4 o[4];
#pragma unroll
  for (int nf = 0; nf < 4; ++nf)
#pragma unroll
    for (int j = 0; j < 4; ++j) o[nf][j] = 0.f;
  float mrun = -1e30f, lrun = 0.f;

  const u16* Kb = Ktg + (size_t)bh * 32768;
  const u16* Vb = Vtg + (size_t)bh * 32768;
  const int sw = (fr & 7) << 4;
  const float SC = 0.18033688f;          // 0.125 * log2(e)

  if (nt > 0) {
    async16(&Ks[0][tid * 8], Kb + tid * 8);
    async16(&Vs[0][tid * 8], Vb + tid * 8);
  }
  __syncthreads();

  for (int t = 0; t < nt; ++t) {
    const int cur = t & 1;
    if (t + 1 < nt) {
      async16(&Ks[cur ^ 1][tid * 8], Kb + (t + 1) * 4096 + tid * 8);
      async16(&Vs[cur ^ 1][tid * 8], Vb + (t + 1) * 4096 + tid * 8);
    }
    const char* Kt = (const char*)(cur ? &Ks[1][0] : &Ks[0][0]);
    const char* Vt = (const char*)(cur ? &Vs[1][0] : &Vs[0][0]);

    f32x4 sacc[4];
    __builtin_amdgcn_s_setprio(1);
#pragma unroll
    for (int nf = 0; nf < 4; ++nf) {
#pragma unroll
      for (int jj = 0; jj < 4; ++jj) sacc[nf][jj] = 0.f;
      int rb = (nf * 16 + fr) * 128;
      bf16x8 kb0 = *(const bf16x8*)(Kt + rb + ((fo * 16) ^ sw));
      bf16x8 kb1 = *(const bf16x8*)(Kt + rb + ((64 + fo * 16) ^ sw));
      sacc[nf] = __builtin_amdgcn_mfma_f32_16x16x32_bf16(kb0, qf0, sacc[nf], 0, 0, 0);
      sacc[nf] = __builtin_amdgcn_mfma_f32_16x16x32_bf16(kb1, qf1, sacc[nf], 0, 0, 0);
    }
    __builtin_amdgcn_s_setprio(0);

    float p2[4][4];
    float pmax = -3e30f;
#pragma unroll
    for (int nf = 0; nf < 4; ++nf) {
      u16x4 ok4 = *(const u16x4*)&okk[t * 64 + nf * 16 + fo * 4];
#pragma unroll
      for (int r = 0; r < 4; ++r) {
        int idx2 = max(qc - (int)ok4[r], 0);
        float s2 = fmaf(sacc[nf][r], SC, rel2[idx2]);
        p2[nf][r] = s2;
        pmax = fmaxf(pmax, s2);
      }
    }
    pmax = fmaxf(pmax, __shfl_xor(pmax, 16, 64));
    pmax = fmaxf(pmax, __shfl_xor(pmax, 32, 64));

    if (!__all(pmax <= mrun + 8.0f)) {   // defer-max (T13)
      float mnew = fmaxf(mrun, pmax);
      float scl = EXP2(mrun - mnew);
      lrun *= scl;
#pragma unroll
      for (int nf = 0; nf < 4; ++nf)
#pragma unroll
        for (int r = 0; r < 4; ++r) o[nf][r] *= scl;
      mrun = mnew;
    }

    float lsum = 0.f;
#pragma unroll
    for (int nf = 0; nf < 4; ++nf) {
      float e0 = EXP2(p2[nf][0] - mrun);
      float e1 = EXP2(p2[nf][1] - mrun);
      float e2 = EXP2(p2[nf][2] - mrun);
      float e3 = EXP2(p2[nf][3] - mrun);
      lsum += (e0 + e1) + (e2 + e3);
      uint2 w; w.x = cvtpk(e0, e1); w.y = cvtpk(e2, e3);
      *(uint2*)((char*)&Pl[wave][0] + fr * 128 + ((nf * 32 + fo * 8) ^ sw)) = w;
    }
    lsum += __shfl_xor(lsum, 16, 64);
    lsum += __shfl_xor(lsum, 32, 64);
    lrun += lsum;

    bf16x8 pa0 = *(const bf16x8*)((char*)&Pl[wave][0] + fr * 128 + ((fo * 16) ^ sw));
    bf16x8 pa1 = *(const bf16x8*)((char*)&Pl[wave][0] + fr * 128 + ((64 + fo * 16) ^ sw));
    __builtin_amdgcn_s_setprio(1);
#pragma unroll
    for (int nf = 0; nf < 4; ++nf) {
      int rb = (nf * 16 + fr) * 128;
      bf16x8 vb0 = *(const bf16x8*)(Vt + rb + ((fo * 16) ^ sw));
      bf16x8 vb1 = *(const bf16x8*)(Vt + rb + ((64 + fo * 16) ^ sw));
      o[nf] = __builtin_amdgcn_mfma_f32_16x16x32_bf16(vb0, pa0, o[nf], 0, 0, 0);
      o[nf] = __builtin_amdgcn_mfma_f32_16x16x32_bf16(vb1, pa1, o[nf], 0, 0, 0);
    }
    __builtin_amdgcn_s_setprio(0);
    __syncthreads();
  }

  float inv = (lrun > 0.f) ? 1.f / lrun : 0.f;
#pragma unroll
  for (int nf = 0; nf < 4; ++nf) {
    float v0 = fminf(fmaxf(o[nf][0] * inv, -30.f), 30.f);
    float v1 = fminf(fmaxf(o[nf][1] * inv, -30.f), 30.f);
    float v2 = fminf(fmaxf(o[nf][2] * inv, -30.f), 30.f);
    float v3 = fminf(fmaxf(o[nf][3] * inv, -30.f), 30.f);
    uint2 w; w.x = cvtpk(v0, v1); w.y = cvtpk(v2, v3);
    *(uint2*)((char*)&Pl[wave][0] + fr * 128 + ((nf * 32 + fo * 8) ^ sw)) = w;
  }
  {
    int lane = tid & 63;
    int ro = lane >> 2, c = lane & 3;
    int swr = (ro & 7) << 4;
    const char* Pw = (const char*)&Pl[wave][0];
    bf16x8 v0 = *(const bf16x8*)(Pw + ro * 128 + ((c * 32) ^ swr));
    bf16x8 v1 = *(const bf16x8*)(Pw + ro * 128 + ((c * 32 + 16) ^ swr));
    int token = q0 + wave * 16 + ro;
    if (token < 500) {
      u16* dst = AO + (size_t)(b * 500 + token) * 1024 + h * 64 + c * 16;
      *(bf16x8*)dst = v0;
      *(bf16x8*)(dst + 8) = v1;
    }
  }
}

// ---------------- launch ----------------
extern "C" void kernel_launch(void* const* d_in, const int* in_sizes, int n_in,
                              void* d_out, int out_size, void* d_ws, size_t ws_size,
                              hipStream_t stream) {
  const float* query = (const float*)d_in[0];
  const float* key_  = (const float*)d_in[1];
  const float* value = (const float*)d_in[2];
  const void*  mask  = d_in[3];
  const float* Wq = (const float*)d_in[4];
  const float* bq = (const float*)d_in[5];
  const float* Wk = (const float*)d_in[6];
  const float* bk = (const float*)d_in[7];
  const float* Wv = (const float*)d_in[8];
  const float* bv = (const float*)d_in[9];
  const float* Wo = (const float*)d_in[10];
  const float* bo = (const float*)d_in[11];
  const float* rel = (const float*)d_in[12];

  // ws map: Wb 8.39MB | 5 slots x 32MiB | misc ~0.26MB (~176.4MB total)
  // A: Xq -> Vtg | B: XkC -> AO | C: XvC -> Ktg | D: PvC | E: PkC
  // Qro lives in d_out (65.5MB f32 >= 32.8MB bf16 scratch; overwritten by out-proj).
  char* ws = (char*)d_ws;
  const size_t SLOT = 33554432;
  u16* Wb = (u16*)ws;
  char* Aq = ws + 8388608;
  char* Bq = Aq + SLOT;
  char* Cq = Bq + SLOT;
  char* Dq = Cq + SLOT;
  char* Eq = Dq + SLOT;
  char* MISC = Eq + SLOT;
  u16* karr  = (u16*)(MISC + 65536);
  int* kept  = (int*)(MISC + 131072);
  float* tab = (float*)(MISC + 131584);
  u16* Qro = (u16*)d_out;

  build_gather<<<32, 512, 0, stream>>>(mask, karr, kept);
  rope_table<<<63, 256, 0, stream>>>(tab);
  cvt_w4<<<dim3(1024, 4), 256, 0, stream>>>(Wq, Wk, Wv, Wo, Wb);
  cvt_f32_bf16<<<2048, 256, 0, stream>>>(query, (u16*)Aq, 4096000);                 // Xq=A
  gathercvt2<<<dim3(256, 32, 2), 256, 0, stream>>>(key_, value, karr, kept,
                                                   (u16*)Bq, (u16*)Cq);             // XkC=B, XvC=C

  // fused Q+K+V projections (independent): 504 Q + 512 K + 512 V blocks, 3/CU co-resident
  gemm_fused<<<1528, 512, 0, stream>>>((u16*)Aq, (u16*)Bq, (u16*)Cq, Wb,
                                       bq, bk, bv,
                                       Qro, (u16*)Eq, (u16*)Dq, tab, kept);

  gather_k<<<dim3(8, 512), 256, 0, stream>>>((u16*)Eq, tab, karr, kept, (u16*)Cq);  // Ktg=C
  gather_v<<<dim3(8, 512), 256, 0, stream>>>((u16*)Dq, karr, kept, (u16*)Aq);       // Vtg=A

  attn_kernel<<<2048, 512, 0, stream>>>(Qro, (u16*)Cq, (u16*)Aq, rel,
                                        karr, kept, (u16*)Bq);                  // AO=B

  gemm_out<<<504, 512, 0, stream>>>((u16*)Bq, Wb + 3 * 1048576, bo, (float*)d_out);
}

// Round 17
// 252.164 us; speedup vs baseline: 1.4870x; 1.1105x over previous
//
#include <hip/hip_runtime.h>
#include <math.h>

// FlashMultiHeadAttention: B=32 S=500 H=1024 NH=16 HD=64, rope + rel-pos-bias + key-pad mask.
// Pipeline: [gather-list scan w/ inline mask-mode detect] [rope table] [cvt W x4]
//           [cvt Q] [gather+cvt K/V kept rows]
//           [FUSED proj GEMM: Q(full, rope+transpose) + K(compact -> roped swizzled Ktg tiles)
//            + V(compact -> transposed swizzled Vtg tiles), ONE launch]
//           [flash attn] [out proj GEMM]
// GEMM core: 256x128 tile, BK=32, 2 LDS buffers (48KB -> 3 blocks/CU co-resident),
// row-pair packed 128B LDS rows + XOR slot swizzle, T3-minimum single-barrier loop.

typedef unsigned short u16;
typedef unsigned int   u32;
typedef unsigned char  u8;
using bf16x8 = __attribute__((ext_vector_type(8))) short;
using f32x4  = __attribute__((ext_vector_type(4))) float;
using f32x2  = __attribute__((ext_vector_type(2))) float;
using u16x4  = __attribute__((ext_vector_type(4))) unsigned short;

#define DEV __device__ __forceinline__

#if __has_builtin(__builtin_amdgcn_exp2f)
#define EXP2(x) __builtin_amdgcn_exp2f(x)
#else
#define EXP2(x) exp2f(x)
#endif

DEV u16 f2bf(float f) {                 // RNE f32 -> bf16
  union { float f; u32 u; } c; c.f = f;
  u32 u = c.u;
  return (u16)((u + 0x7FFFu + ((u >> 16) & 1u)) >> 16);
}
DEV float bf2f(u16 h) {
  union { u32 u; float f; } c; c.u = ((u32)h) << 16;
  return c.f;
}
DEV u32 cvtpk(float a, float b) {       // packed pair via HW cvt (T12)
  u32 r;
  asm("v_cvt_pk_bf16_f32 %0, %1, %2" : "=v"(r) : "v"(a), "v"(b));
  return r;
}

// async global->LDS, 16B/lane; LDS dest = wave-uniform base + lane*16 (linear).
DEV void async16(void* l, const void* g) {
  __builtin_amdgcn_global_load_lds(
      (__attribute__((address_space(1))) unsigned int*)g,
      (__attribute__((address_space(3))) unsigned int*)l, 16, 0, 0);
}

// ---------------- gather list + inline mask-mode detection ----------------
__global__ __launch_bounds__(512) void build_gather(const void* __restrict__ mraw,
                                                    u16* __restrict__ karr,
                                                    int* __restrict__ kept) {
  const int b = blockIdx.x;
  const int t = threadIdx.x;
  const int lane = t & 63, wave = t >> 6;
  __shared__ int s_li, s_lf;
  __shared__ int wbase[8];
  __shared__ int wpop[8];
  if (t == 0) { s_li = 0; s_lf = 0; }
  __syncthreads();
  const u32* w = (const u32*)mraw;
  int li = 0, lf = 0;
  for (int g = t; g < 4000; g += 512) {      // same 4000 words in every block -> same mode
    u32 v = w[g];
    li |= !(v == 0u || v == 1u);
    lf |= !(v == 0u || v == 0x3F800000u);
  }
  if (li) atomicOr(&s_li, 1);
  if (lf) atomicOr(&s_lf, 1);
  __syncthreads();
  const int mode = (!s_li) ? 0 : ((!s_lf) ? 1 : 2);   // 0=int32, 1=float32, 2=uint8
  int v = 0;
  if (t < 500) {
    if (mode == 0)      v = ((const int*)mraw)[b * 500 + t] != 0;
    else if (mode == 1) v = (((const float*)mraw)[b * 500 + t] != 0.0f);
    else                v = ((const u8*)mraw)[b * 500 + t] != 0;
  }
  unsigned long long bal = __ballot(v != 0);
  karr[b * 512 + t] = 0xFFFF;
  if (lane == 0) wpop[wave] = __popcll(bal);
  __syncthreads();
  if (t == 0) {
    int s = 0;
    for (int ww = 0; ww < 8; ++ww) { wbase[ww] = s; s += wpop[ww]; }
    kept[b] = s;
  }
  __syncthreads();
  if (v) {
    int rank = wbase[wave] + __popcll(bal & ((1ull << lane) - 1ull));
    karr[b * 512 + rank] = (u16)t;
  }
}

// ---------------- rope cos/sin table: tab[(s*32+j)*2] = cos, +1 = sin ----------------
__global__ __launch_bounds__(256) void rope_table(float* __restrict__ tab) {
  int idx = blockIdx.x * 256 + threadIdx.x;
  if (idx >= 16000) return;
  int s = idx >> 5, j = idx & 31;
  float ang = (float)s * exp2f(-(float)j * 0.41524100f);  // 10000^(-j/32)
  float sn, cs;
  sincosf(ang, &sn, &cs);
  tab[idx * 2] = cs;
  tab[idx * 2 + 1] = sn;
}

// ---------------- weights f32 -> bf16, 4 matrices in one launch ----------------
__global__ __launch_bounds__(256) void cvt_w4(const float* __restrict__ w0,
                                              const float* __restrict__ w1,
                                              const float* __restrict__ w2,
                                              const float* __restrict__ w3,
                                              u16* __restrict__ dst) {
  const float* src = (blockIdx.y == 0) ? w0 : (blockIdx.y == 1) ? w1
                    : (blockIdx.y == 2) ? w2 : w3;
  int i = blockIdx.x * 256 + threadIdx.x;            // 262144 groups of 4
  f32x4 f = *(const f32x4*)(src + (size_t)i * 4);
  u16x4 o;
  o[0] = f2bf(f[0]); o[1] = f2bf(f[1]); o[2] = f2bf(f[2]); o[3] = f2bf(f[3]);
  *(u16x4*)(dst + (size_t)blockIdx.y * 1048576 + (size_t)i * 4) = o;
}

// ---------------- f32 -> bf16 convert (vectorized) ----------------
__global__ __launch_bounds__(256) void cvt_f32_bf16(const float* __restrict__ src,
                                                    u16* __restrict__ dst, int n4) {
  int i = blockIdx.x * 256 + threadIdx.x;
  int stride = gridDim.x * 256;
  for (; i < n4; i += stride) {
    f32x4 f = *(const f32x4*)(src + (size_t)i * 4);
    u16x4 o;
    o[0] = f2bf(f[0]); o[1] = f2bf(f[1]); o[2] = f2bf(f[2]); o[3] = f2bf(f[3]);
    *(u16x4*)(dst + (size_t)i * 4) = o;
  }
}

// ---------------- gather kept rows + cvt for K and V in one launch ----------------
__global__ __launch_bounds__(256) void gathercvt2(const float* __restrict__ srcK,
                                                  const float* __restrict__ srcV,
                                                  const u16* __restrict__ karr,
                                                  const int* __restrict__ kept,
                                                  u16* __restrict__ dstK,
                                                  u16* __restrict__ dstV) {
  const int b = blockIdx.y;
  const int r = blockIdx.x * 2 + (threadIdx.x >> 7);   // 512 rows/batch
  if (r >= kept[b]) return;
  const float* src = blockIdx.z ? srcV : srcK;
  u16* dst = blockIdx.z ? dstV : dstK;
  const int c = (threadIdx.x & 127) * 8;
  const int tok = karr[b * 512 + r];
  const float* s = src + ((size_t)b * 500 + tok) * 1024 + c;
  f32x4 f0 = *(const f32x4*)s;
  f32x4 f1 = *(const f32x4*)(s + 4);
  u16 o[8];
  o[0] = f2bf(f0[0]); o[1] = f2bf(f0[1]); o[2] = f2bf(f0[2]); o[3] = f2bf(f0[3]);
  o[4] = f2bf(f1[0]); o[5] = f2bf(f1[1]); o[6] = f2bf(f1[2]); o[7] = f2bf(f1[3]);
  *(bf16x8*)(dst + ((size_t)b * 512 + r) * 1024 + c) = *(bf16x8*)o;
}

// ---------------- shared GEMM core (round-14 proven) ----------------
// 256x128 tile, BK=32, 512 thr / 8 waves (4Mx2N), per-wave 64x64 (4x4 frags).
// 2 LDS buffers (A 16KB + B 8KB each). Row-pair packed 128B rows, XOR slot swizzle.
// T3-minimum loop: STAGE(t+1,buf^1) -> ds_read -> lgkm(0) -> 16 MFMA -> vmcnt(0) -> barrier.
DEV void gemm_core(const u16* __restrict__ A, size_t abase,
                   const u16* __restrict__ W,
                   int m0, int n0, int Mloc,
                   u16* AS, u16* BS, f32x4 (&acc)[4][4], int tid) {
  const int wave = tid >> 6;
  const int wr = wave >> 1, wc = wave & 1;            // 4M x 2N
  const int fr = tid & 15, fo = (tid >> 4) & 3;
  const int fr2 = fr >> 1;
  const int aslot = ((4 * (fr & 1) + fo) ^ fr2) * 8;  // u16 offset within 64-u16 LDS row
  const int ATILE = 128 * 64;                         // 16KB
  const int BTILE = 64 * 64;                          // 8KB

#pragma unroll
  for (int mi = 0; mi < 4; ++mi)
#pragma unroll
    for (int ni = 0; ni < 4; ++ni)
#pragma unroll
      for (int j = 0; j < 4; ++j) acc[mi][ni][j] = 0.f;

  auto STG = [&](int t, int buf) {
    u16* sA = &AS[buf * ATILE];
    u16* sB = &BS[buf * BTILE];
#pragma unroll
    for (int i = 0; i < 2; ++i) {                     // A: 1024 chunks
      int c = i * 512 + tid;
      int r = c >> 3, v = (c & 7) ^ (r & 7);
      int ar = min(m0 + 2 * r + (v >> 2), Mloc - 1);
      async16(&sA[c * 8], A + abase + (size_t)ar * 1024 + t * 32 + (v & 3) * 8);
    }
    {                                                 // B: 512 chunks
      int c = tid;
      int r = c >> 3, v = (c & 7) ^ (r & 7);
      int nr = n0 + 2 * r + (v >> 2);
      async16(&sB[c * 8], W + (size_t)nr * 1024 + t * 32 + (v & 3) * 8);
    }
  };

  STG(0, 0);
  asm volatile("s_waitcnt vmcnt(0)" ::: "memory");
  __builtin_amdgcn_sched_barrier(0);
  __builtin_amdgcn_s_barrier();

  int cur = 0;
  for (int t = 0; t < 32; ++t) {
    if (t + 1 < 32) STG(t + 1, cur ^ 1);
    const u16* a0 = &AS[cur * ATILE];
    const u16* b0 = &BS[cur * BTILE];
    bf16x8 a[4], b[4];
#pragma unroll
    for (int mi = 0; mi < 4; ++mi)
      a[mi] = *(const bf16x8*)&a0[(wr * 32 + mi * 8 + fr2) * 64 + aslot];
#pragma unroll
    for (int ni = 0; ni < 4; ++ni)
      b[ni] = *(const bf16x8*)&b0[(wc * 32 + ni * 8 + fr2) * 64 + aslot];
    asm volatile("s_waitcnt lgkmcnt(0)" ::: "memory");
    __builtin_amdgcn_sched_barrier(0);
    __builtin_amdgcn_s_setprio(1);
#pragma unroll
    for (int mi = 0; mi < 4; ++mi)
#pragma unroll
      for (int ni = 0; ni < 4; ++ni)
        acc[mi][ni] = __builtin_amdgcn_mfma_f32_16x16x32_bf16(a[mi], b[ni], acc[mi][ni], 0, 0, 0);
    __builtin_amdgcn_s_setprio(0);
    asm volatile("s_waitcnt vmcnt(0)" ::: "memory");
    __builtin_amdgcn_sched_barrier(0);
    __builtin_amdgcn_s_barrier();
    cur ^= 1;
  }
  __syncthreads();
}

// ---------------- FUSED projection GEMM ----------------
// grid 1528 = 504 (Q full: rope+transpose -> Qro) + 512 (K compact: rope -> swizzled Ktg
// tiles) + 512 (V compact: transpose -> swizzled Vtg tiles). Bases multiples of 8 keep
// per-path XCD swizzle aligned with the dispatcher's bid%8 round-robin.
__global__ __launch_bounds__(512, 4) void gemm_fused(
    const u16* __restrict__ Xq, const u16* __restrict__ XkC, const u16* __restrict__ XvC,
    const u16* __restrict__ Wb,
    const float* __restrict__ bq, const float* __restrict__ bk, const float* __restrict__ bv,
    u16* __restrict__ Qro, u16* __restrict__ Ktg, u16* __restrict__ Vtg,
    const float* __restrict__ tabg, const u16* __restrict__ karr,
    const int* __restrict__ keptp) {
  __shared__ __attribute__((aligned(16))) u16 SH[2 * 128 * 64 + 2 * 64 * 64];  // 48KB
  u16* AS = &SH[0];
  u16* BS = &SH[2 * 128 * 64];
  const int bid = blockIdx.x;
  const int tid = threadIdx.x;
  const int wave = tid >> 6;
  const int wr = wave >> 1, wc = wave & 1;
  const int fr = tid & 15, fo = (tid >> 4) & 3;
  const int lane = tid & 63;

  f32x4 acc[4][4];

  if (bid < 504) {
    // ---- Q path: full M=16000, rope+transpose epilogue -> Qro [bh][s][64] ----
    const int swz = (bid & 7) * 63 + (bid >> 3);
    const int m0 = (swz >> 3) * 256;
    const int n0 = (swz & 7) * 128;
    gemm_core(Xq, 0, Wb, m0, n0, 16000, AS, BS, acc, tid);

    float* fw = (float*)&SH[0] + wave * 1024;         // 4KB per wave (stride-64 rows)
    const int hh = (n0 >> 6) + wc;
    const int row = lane >> 2;
    const int jb = (lane & 3) * 8;
    float bvv[4];
#pragma unroll
    for (int ni = 0; ni < 4; ++ni) bvv[ni] = bq[n0 + wc * 64 + ni * 16 + fr];
#pragma unroll
    for (int mi = 0; mi < 4; ++mi) {
#pragma unroll
      for (int ni = 0; ni < 4; ++ni)
#pragma unroll
        for (int r = 0; r < 4; ++r)
          fw[(fo * 4 + r) * 64 + ni * 16 + fr] = acc[mi][ni][r] + bvv[ni];
      int m = m0 + wr * 64 + mi * 16 + row;
      if (m < 16000) {
        int bb = (u32)m / 500u;
        int ss = m - bb * 500;
        u16* dst = Qro + (((size_t)(bb * 16 + hh)) * 500 + ss) * 64;
        bf16x8 va, vb;
#pragma unroll
        for (int p = 0; p < 8; ++p) {
          int j = jb + p;
          float x0 = fw[row * 64 + j];
          float x1 = fw[row * 64 + 32 + j];
          float xe = fw[row * 64 + 2 * j];
          float xo = fw[row * 64 + 2 * j + 1];
          f32x2 cn = *(const f32x2*)(tabg + (ss * 32 + j) * 2);
          va[p] = (short)f2bf(x0 * cn[0] - xo * cn[1]);
          vb[p] = (short)f2bf(x1 * cn[0] + xe * cn[1]);
        }
        *(bf16x8*)(dst + jb) = va;
        *(bf16x8*)(dst + 32 + jb) = vb;
      }
      __builtin_amdgcn_s_barrier();
    }
  } else {
    // ---- K/V compact paths ----
    const bool isV = (bid >= 1016);
    const int local = isV ? (bid - 1016) : (bid - 504);
    const u16* A = isV ? XvC : XkC;
    const u16* W = Wb + (isV ? 2 : 1) * 1048576;
    const float* bias = isV ? bv : bk;
    const int swz = (local & 7) * 64 + (local >> 3);  // bijective: 512 = 8*64
    const int mb = swz >> 3;
    const int n0 = (swz & 7) * 128;
    const int b = mb >> 1, rb = mb & 1;
    const int kb = keptp[b];
    if (rb * 256 >= kb) return;
    const int m0 = rb * 256;
    gemm_core(A, (size_t)b * 512 * 1024, W, m0, n0, kb, AS, BS, acc, tid);

    // f32 bounce with stride-66 rows (conflict-free strided column reads for V)
    float* fw = (float*)&SH[0] + wave * 1056;         // 16 x 66 f32 = 4224B per wave
    const int hh = (n0 >> 6) + wc;
    float bvv[4];
#pragma unroll
    for (int ni = 0; ni < 4; ++ni) bvv[ni] = bias[n0 + wc * 64 + ni * 16 + fr];

    if (!isV) {
      // K: rope per rank, write pre-swizzled Ktg tiles [bh][tile][rin][128B]
      const int row = lane >> 2;
      const int jb = (lane & 3) * 8;
#pragma unroll
      for (int mi = 0; mi < 4; ++mi) {
#pragma unroll
        for (int ni = 0; ni < 4; ++ni)
#pragma unroll
          for (int r = 0; r < 4; ++r)
            fw[(fo * 4 + r) * 66 + ni * 16 + fr] = acc[mi][ni][r] + bvv[ni];
        int rk = m0 + wr * 64 + mi * 16 + row;
        int tile = rk >> 6, rin = rk & 63;
        int swk = (rin & 7) << 4;
        if (tile * 64 < kb) {
          // FIX (round 16 bug): + rin*128 row offset within the tile
          char* outp = (char*)(Ktg + (((size_t)(b * 16 + hh)) * 8 + tile) * 4096) + rin * 128;
          bf16x8 va, vb;
          if (rk < kb) {
            int tok = karr[b * 512 + rk];
#pragma unroll
            for (int p = 0; p < 8; ++p) {
              int j = jb + p;
              float x0 = fw[row * 66 + j];
              float x1 = fw[row * 66 + 32 + j];
              float xe = fw[row * 66 + 2 * j];
              float xo = fw[row * 66 + 2 * j + 1];
              f32x2 cn = *(const f32x2*)(tabg + (tok * 32 + j) * 2);
              va[p] = (short)f2bf(x0 * cn[0] - xo * cn[1]);
              vb[p] = (short)f2bf(x1 * cn[0] + xe * cn[1]);
            }
          } else {
#pragma unroll
            for (int p = 0; p < 8; ++p) { va[p] = 0; vb[p] = 0; }
          }
          *(bf16x8*)(outp + ((2 * jb) ^ swk)) = va;
          *(bf16x8*)(outp + ((64 + 2 * jb) ^ swk)) = vb;
        }
        __builtin_amdgcn_s_barrier();
      }
    } else {
      // V: transpose in bounce (lane = d), write pre-swizzled Vtg tiles [bh][tile][d][128B]
      const int d = lane;
      const int swv = (d & 7) << 4;
#pragma unroll
      for (int mi = 0; mi < 4; ++mi) {
#pragma unroll
        for (int ni = 0; ni < 4; ++ni)
#pragma unroll
          for (int r = 0; r < 4; ++r)
            fw[(fo * 4 + r) * 66 + ni * 16 + fr] = acc[mi][ni][r] + bvv[ni];
        int rk0 = m0 + wr * 64 + mi * 16;
        int tile = rk0 >> 6, rin0 = rk0 & 63;
        if (tile * 64 < kb) {
          char* rowp = (char*)(Vtg + (((size_t)(b * 16 + hh)) * 8 + tile) * 4096) + d * 128;
          bf16x8 va, vb;
#pragma unroll
          for (int t2 = 0; t2 < 8; ++t2)
            va[t2] = (rk0 + t2 < kb) ? (short)f2bf(fw[t2 * 66 + d]) : (short)0;
#pragma unroll
          for (int t2 = 0; t2 < 8; ++t2)
            vb[t2] = (rk0 + 8 + t2 < kb) ? (short)f2bf(fw[(8 + t2) * 66 + d]) : (short)0;
          *(bf16x8*)(rowp + ((2 * rin0) ^ swv)) = va;
          *(bf16x8*)(rowp + ((2 * rin0 + 16) ^ swv)) = vb;
        }
        __builtin_amdgcn_s_barrier();
      }
    }
  }
}

// ---------------- out-projection GEMM: full, f32 out ----------------
__global__ __launch_bounds__(512, 4) void gemm_out(const u16* __restrict__ A,
                                                   const u16* __restrict__ W,
                                                   const float* __restrict__ bias,
                                                   float* __restrict__ Cout) {
  __shared__ __attribute__((aligned(16))) u16 SH[2 * 128 * 64 + 2 * 64 * 64];
  u16* AS = &SH[0];
  u16* BS = &SH[2 * 128 * 64];
  const int bid = blockIdx.x;
  const int tid = threadIdx.x;
  const int wave = tid >> 6;
  const int wr = wave >> 1, wc = wave & 1;
  const int fr = tid & 15, fo = (tid >> 4) & 3;
  const int swz = (bid & 7) * 63 + (bid >> 3);
  const int m0 = (swz >> 3) * 256;
  const int n0 = (swz & 7) * 128;

  f32x4 acc[4][4];
  gemm_core(A, 0, W, m0, n0, 16000, AS, BS, acc, tid);

  float* fw = (float*)&SH[0] + wave * 1024;           // 4KB per wave
#pragma unroll
  for (int mi = 0; mi < 4; ++mi) {
#pragma unroll
    for (int ni = 0; ni < 4; ++ni) {
      float bv = bias[n0 + wc * 64 + ni * 16 + fr];
#pragma unroll
      for (int r = 0; r < 4; ++r)
        fw[(fo * 4 + r) * 64 + ni * 16 + fr] = acc[mi][ni][r] + bv;
    }
    int lane = tid & 63;
    int ro = lane >> 2, ch = lane & 3;
    int m = m0 + wr * 64 + mi * 16 + ro;
    f32x4 v0 = *(const f32x4*)&fw[ro * 64 + ch * 16];
    f32x4 v1 = *(const f32x4*)&fw[ro * 64 + ch * 16 + 4];
    f32x4 v2 = *(const f32x4*)&fw[ro * 64 + ch * 16 + 8];
    f32x4 v3 = *(const f32x4*)&fw[ro * 64 + ch * 16 + 12];
    if (m < 16000) {
      float* dst = Cout + (size_t)m * 1024 + n0 + wc * 64 + ch * 16;
      *(f32x4*)dst = v0;
      *(f32x4*)(dst + 4) = v1;
      *(f32x4*)(dst + 8) = v2;
      *(f32x4*)(dst + 12) = v3;
    }
    __builtin_amdgcn_s_barrier();
  }
}

// ---------------- flash attention: compressed k, swapped QK^T, in-reg softmax ----------------
__global__ __launch_bounds__(512) void attn_kernel(const u16* __restrict__ Qr,
                                                   const u16* __restrict__ Ktg,
                                                   const u16* __restrict__ Vtg,
                                                   const float* __restrict__ rel_emb,
                                                   const u16* __restrict__ karr,
                                                   const int* __restrict__ kept,
                                                   u16* __restrict__ AO) {
  const int bid = blockIdx.x;
  const int bh = ((bid >> 5) << 3) | (bid & 7);
  const int qb = (bid >> 3) & 3;
  const int h = bh & 15, b = bh >> 4;
  const int q0 = qb * 128;
  const int tid = threadIdx.x;
  const int wave = tid >> 6;
  const int fr = tid & 15, fo = (tid >> 4) & 3;

  __shared__ __attribute__((aligned(16))) u16 Ks[2][4096];
  __shared__ __attribute__((aligned(16))) u16 Vs[2][4096];
  __shared__ __attribute__((aligned(16))) u16 Pl[8][1024];
  __shared__ float rel2[640];
  __shared__ u16 okk[512];

  const int nt = (kept[b] + 63) >> 6;
  const float LOG2E = 1.44269504f;
  for (int i = tid; i < 640; i += 512) {
    int g = min(max(q0 - 12 + i, 0), 998);
    rel2[i] = (i == 0) ? -1e30f : rel_emb[g * 16 + h] * LOG2E;   // rel2[0] = pad sentinel
  }
  okk[tid] = karr[b * 512 + tid];

  const int qloc = wave * 16 + fr;
  const int qc = qloc + 511;             // pad slot (ok=0xFFFF) -> idx<0 -> clamp 0 -> -1e30
  const u16* Qb = Qr + ((size_t)bh * 500 + min(q0 + qloc, 499)) * 64;
  bf16x8 qf0 = *(const bf16x8*)(Qb + fo * 8);
  bf16x8 qf1 = *(const bf16x8*)(Qb + 32 + fo * 8);

  f32x4 o[4];
#pragma unroll
  for (int nf = 0; nf < 4; ++nf)
#pragma unroll
    for (int j = 0; j < 4; ++j) o[nf][j] = 0.f;
  float mrun = -1e30f, lrun = 0.f;

  const u16* Kb = Ktg + (size_t)bh * 32768;
  const u16* Vb = Vtg + (size_t)bh * 32768;
  const int sw = (fr & 7) << 4;
  const float SC = 0.18033688f;          // 0.125 * log2(e)

  if (nt > 0) {
    async16(&Ks[0][tid * 8], Kb + tid * 8);
    async16(&Vs[0][tid * 8], Vb + tid * 8);
  }
  __syncthreads();

  for (int t = 0; t < nt; ++t) {
    const int cur = t & 1;
    if (t + 1 < nt) {
      async16(&Ks[cur ^ 1][tid * 8], Kb + (t + 1) * 4096 + tid * 8);
      async16(&Vs[cur ^ 1][tid * 8], Vb + (t + 1) * 4096 + tid * 8);
    }
    const char* Kt = (const char*)(cur ? &Ks[1][0] : &Ks[0][0]);
    const char* Vt = (const char*)(cur ? &Vs[1][0] : &Vs[0][0]);

    f32x4 sacc[4];
    __builtin_amdgcn_s_setprio(1);
#pragma unroll
    for (int nf = 0; nf < 4; ++nf) {
#pragma unroll
      for (int jj = 0; jj < 4; ++jj) sacc[nf][jj] = 0.f;
      int rb = (nf * 16 + fr) * 128;
      bf16x8 kb0 = *(const bf16x8*)(Kt + rb + ((fo * 16) ^ sw));
      bf16x8 kb1 = *(const bf16x8*)(Kt + rb + ((64 + fo * 16) ^ sw));
      sacc[nf] = __builtin_amdgcn_mfma_f32_16x16x32_bf16(kb0, qf0, sacc[nf], 0, 0, 0);
      sacc[nf] = __builtin_amdgcn_mfma_f32_16x16x32_bf16(kb1, qf1, sacc[nf], 0, 0, 0);
    }
    __builtin_amdgcn_s_setprio(0);

    float p2[4][4];
    float pmax = -3e30f;
#pragma unroll
    for (int nf = 0; nf < 4; ++nf) {
      u16x4 ok4 = *(const u16x4*)&okk[t * 64 + nf * 16 + fo * 4];
#pragma unroll
      for (int r = 0; r < 4; ++r) {
        int idx2 = max(qc - (int)ok4[r], 0);
        float s2 = fmaf(sacc[nf][r], SC, rel2[idx2]);
        p2[nf][r] = s2;
        pmax = fmaxf(pmax, s2);
      }
    }
    pmax = fmaxf(pmax, __shfl_xor(pmax, 16, 64));
    pmax = fmaxf(pmax, __shfl_xor(pmax, 32, 64));

    if (!__all(pmax <= mrun + 8.0f)) {   // defer-max (T13)
      float mnew = fmaxf(mrun, pmax);
      float scl = EXP2(mrun - mnew);
      lrun *= scl;
#pragma unroll
      for (int nf = 0; nf < 4; ++nf)
#pragma unroll
        for (int r = 0; r < 4; ++r) o[nf][r] *= scl;
      mrun = mnew;
    }

    float lsum = 0.f;
#pragma unroll
    for (int nf = 0; nf < 4; ++nf) {
      float e0 = EXP2(p2[nf][0] - mrun);
      float e1 = EXP2(p2[nf][1] - mrun);
      float e2 = EXP2(p2[nf][2] - mrun);
      float e3 = EXP2(p2[nf][3] - mrun);
      lsum += (e0 + e1) + (e2 + e3);
      uint2 w; w.x = cvtpk(e0, e1); w.y = cvtpk(e2, e3);
      *(uint2*)((char*)&Pl[wave][0] + fr * 128 + ((nf * 32 + fo * 8) ^ sw)) = w;
    }
    lsum += __shfl_xor(lsum, 16, 64);
    lsum += __shfl_xor(lsum, 32, 64);
    lrun += lsum;

    bf16x8 pa0 = *(const bf16x8*)((char*)&Pl[wave][0] + fr * 128 + ((fo * 16) ^ sw));
    bf16x8 pa1 = *(const bf16x8*)((char*)&Pl[wave][0] + fr * 128 + ((64 + fo * 16) ^ sw));
    __builtin_amdgcn_s_setprio(1);
#pragma unroll
    for (int nf = 0; nf < 4; ++nf) {
      int rb = (nf * 16 + fr) * 128;
      bf16x8 vb0 = *(const bf16x8*)(Vt + rb + ((fo * 16) ^ sw));
      bf16x8 vb1 = *(const bf16x8*)(Vt + rb + ((64 + fo * 16) ^ sw));
      o[nf] = __builtin_amdgcn_mfma_f32_16x16x32_bf16(vb0, pa0, o[nf], 0, 0, 0);
      o[nf] = __builtin_amdgcn_mfma_f32_16x16x32_bf16(vb1, pa1, o[nf], 0, 0, 0);
    }
    __builtin_amdgcn_s_setprio(0);
    __syncthreads();
  }

  float inv = (lrun > 0.f) ? 1.f / lrun : 0.f;
#pragma unroll
  for (int nf = 0; nf < 4; ++nf) {
    float v0 = fminf(fmaxf(o[nf][0] * inv, -30.f), 30.f);
    float v1 = fminf(fmaxf(o[nf][1] * inv, -30.f), 30.f);
    float v2 = fminf(fmaxf(o[nf][2] * inv, -30.f), 30.f);
    float v3 = fminf(fmaxf(o[nf][3] * inv, -30.f), 30.f);
    uint2 w; w.x = cvtpk(v0, v1); w.y = cvtpk(v2, v3);
    *(uint2*)((char*)&Pl[wave][0] + fr * 128 + ((nf * 32 + fo * 8) ^ sw)) = w;
  }
  {
    int lane = tid & 63;
    int ro = lane >> 2, c = lane & 3;
    int swr = (ro & 7) << 4;
    const char* Pw = (const char*)&Pl[wave][0];
    bf16x8 v0 = *(const bf16x8*)(Pw + ro * 128 + ((c * 32) ^ swr));
    bf16x8 v1 = *(const bf16x8*)(Pw + ro * 128 + ((c * 32 + 16) ^ swr));
    int token = q0 + wave * 16 + ro;
    if (token < 500) {
      u16* dst = AO + (size_t)(b * 500 + token) * 1024 + h * 64 + c * 16;
      *(bf16x8*)dst = v0;
      *(bf16x8*)(dst + 8) = v1;
    }
  }
}

// ---------------- launch ----------------
extern "C" void kernel_launch(void* const* d_in, const int* in_sizes, int n_in,
                              void* d_out, int out_size, void* d_ws, size_t ws_size,
                              hipStream_t stream) {
  const float* query = (const float*)d_in[0];
  const float* key_  = (const float*)d_in[1];
  const float* value = (const float*)d_in[2];
  const void*  mask  = d_in[3];
  const float* Wq = (const float*)d_in[4];
  const float* bq = (const float*)d_in[5];
  const float* Wk = (const float*)d_in[6];
  const float* bk = (const float*)d_in[7];
  const float* Wv = (const float*)d_in[8];
  const float* bv = (const float*)d_in[9];
  const float* Wo = (const float*)d_in[10];
  const float* bo = (const float*)d_in[11];
  const float* rel = (const float*)d_in[12];

  // ws map: Wb 8.39MB | 5 slots x 32MiB | misc ~0.26MB
  // A: Xq | B: XkC -> AO | C: XvC | D: Ktg | E: Vtg
  // Qro lives in d_out (f32 65.5MB >= 32.8MB bf16 scratch; overwritten by out-proj).
  char* ws = (char*)d_ws;
  const size_t SLOT = 33554432;
  u16* Wb = (u16*)ws;
  char* Aq = ws + 8388608;
  char* Bq = Aq + SLOT;
  char* Cq = Bq + SLOT;
  char* Dq = Cq + SLOT;
  char* Eq = Dq + SLOT;
  char* MISC = Eq + SLOT;
  u16* karr  = (u16*)(MISC + 65536);
  int* kept  = (int*)(MISC + 131072);
  float* tab = (float*)(MISC + 131584);
  u16* Qro = (u16*)d_out;

  build_gather<<<32, 512, 0, stream>>>(mask, karr, kept);
  rope_table<<<63, 256, 0, stream>>>(tab);
  cvt_w4<<<dim3(1024, 4), 256, 0, stream>>>(Wq, Wk, Wv, Wo, Wb);
  cvt_f32_bf16<<<2048, 256, 0, stream>>>(query, (u16*)Aq, 4096000);                 // Xq=A
  gathercvt2<<<dim3(256, 32, 2), 256, 0, stream>>>(key_, value, karr, kept,
                                                   (u16*)Bq, (u16*)Cq);             // XkC=B, XvC=C

  // fused Q+K+V projections; K/V epilogues emit swizzled Ktg/Vtg tiles directly
  gemm_fused<<<1528, 512, 0, stream>>>((u16*)Aq, (u16*)Bq, (u16*)Cq, Wb,
                                       bq, bk, bv,
                                       Qro, (u16*)Dq, (u16*)Eq, tab, karr, kept);

  attn_kernel<<<2048, 512, 0, stream>>>(Qro, (u16*)Dq, (u16*)Eq, rel,
                                        karr, kept, (u16*)Bq);                  // AO=B

  gemm_out<<<504, 512, 0, stream>>>((u16*)Bq, Wb + 3 * 1048576, bo, (float*)d_out);
}